// Round 7
// baseline (537.032 us; speedup 1.0000x reference)
//
#include <hip/hip_runtime.h>
#include <hip/hip_bf16.h>
#include <math.h>

// Problem constants
constexpr int B  = 16;
constexpr int N  = 8192;     // 2^13
constexpr int E  = 131072;   // 2^17
constexpr int H  = 128;
constexpr int K1 = 4096;
constexpr int K2 = 2048;

constexpr int CHUNKS = 16;         // edge chunks per graph (8192 edges each)
constexpr int NBK    = 16;         // dst buckets (dst>>9, 512 nodes each)
constexpr int FCAP   = 12288;      // final_scatter LDS capacity

typedef __attribute__((ext_vector_type(8))) short short8;
typedef __attribute__((ext_vector_type(4))) float floatx4;

__device__ __forceinline__ unsigned short f2bf(float f) {
  unsigned u = __float_as_uint(f);
  return (unsigned short)((u + 0x7FFFu + ((u >> 16) & 1u)) >> 16);  // RNE
}
__device__ __forceinline__ float bf2f(unsigned short s) {
  return __uint_as_float(((unsigned)s) << 16);
}
__device__ __forceinline__ float rdlane_f(float v, int l) {
  return __uint_as_float((unsigned)__builtin_amdgcn_readlane((int)__float_as_uint(v), l));
}
__device__ __forceinline__ unsigned cvt_pk_bf16(float a, float b) {
  unsigned r;
  asm("v_cvt_pk_bf16_f32 %0, %1, %2" : "=v"(r) : "v"(a), "v"(b));
  return r;
}

// ---------------------------------------------------------------------------
// CSR build (streaming counting sort) — unchanged from R5
// ---------------------------------------------------------------------------
__global__ __launch_bounds__(256) void hist_pass(const int* __restrict__ ei,
                                                 int* __restrict__ bchist) {
  int blk = blockIdx.x;                 // B*CHUNKS = 256
  int b = blk >> 4, c = blk & 15;
  __shared__ int h16[NBK];
  if (threadIdx.x < NBK) h16[threadIdx.x] = 0;
  __syncthreads();
  const int* dstp = ei + (size_t)b * 2 * E + E + c * 8192;
  for (int i = 0; i < 32; ++i) {
    int dst = dstp[i * 256 + threadIdx.x];
    atomicAdd(&h16[dst >> 9], 1);
  }
  __syncthreads();
  if (threadIdx.x < NBK) bchist[(blk << 4) + threadIdx.x] = h16[threadIdx.x];
}

__global__ __launch_bounds__(256) void bucket_scan(const int* __restrict__ bchist,
                                                   int* __restrict__ cursor,
                                                   int* __restrict__ bbase) {
  int b = blockIdx.x;                   // B = 16
  int tid = threadIdx.x;                // 256 = CHUNKS*NBK
  int c = tid >> 4, k = tid & 15;
  __shared__ int arr[CHUNKS][NBK];
  __shared__ int base[NBK + 1];
  arr[c][k] = bchist[((b * CHUNKS + c) << 4) + k];
  __syncthreads();
  if (tid == 0) {
    int run = 0;
    for (int kk = 0; kk < NBK; ++kk) {
      base[kk] = run;
      int t = 0;
      for (int cc = 0; cc < CHUNKS; ++cc) t += arr[cc][kk];
      run += t;
    }
    base[NBK] = run;
  }
  __syncthreads();
  int pre = 0;
  for (int cc = 0; cc < c; ++cc) pre += arr[cc][k];
  cursor[((b * CHUNKS + c) << 4) + k] = base[k] + pre;
  if (tid < NBK + 1) bbase[b * (NBK + 1) + tid] = base[tid];
}

__global__ __launch_bounds__(256) void bin_scatter(const int* __restrict__ ei,
                                                   const int* __restrict__ cursor,
                                                   unsigned* __restrict__ pbuf) {
  int blk = blockIdx.x;
  int b = blk >> 4, c = blk & 15;
  __shared__ int gcur[NBK], lcnt[NBK], lfill[NBK];
  __shared__ int lbase[NBK + 1];
  __shared__ unsigned sbuf[2048];
  int tid = threadIdx.x;
  if (tid < NBK) gcur[tid] = cursor[(blk << 4) + tid];
  const int* srcp = ei + (size_t)b * 2 * E + c * 8192;
  const int* dstp = srcp + E;
  unsigned* pb = pbuf + (size_t)b * E;

  for (int sc = 0; sc < 4; ++sc) {
    if (tid < NBK) { lcnt[tid] = 0; lfill[tid] = 0; }
    __syncthreads();
    int s8[8], d8[8];
#pragma unroll
    for (int q = 0; q < 8; ++q) {
      int i = sc * 2048 + q * 256 + tid;
      s8[q] = srcp[i]; d8[q] = dstp[i];
      atomicAdd(&lcnt[d8[q] >> 9], 1);
    }
    __syncthreads();
    if (tid == 0) {
      int run = 0;
      for (int k = 0; k < NBK; ++k) { lbase[k] = run; run += lcnt[k]; }
      lbase[NBK] = run;
    }
    __syncthreads();
#pragma unroll
    for (int q = 0; q < 8; ++q) {
      int k = d8[q] >> 9;
      int idx = atomicAdd(&lfill[k], 1);
      sbuf[lbase[k] + idx] = ((unsigned)(d8[q] & 511) << 13) | (unsigned)s8[q];
    }
    __syncthreads();
    for (int i = tid; i < 2048; i += 256) {
      int k = 0;
      while (lbase[k + 1] <= i) ++k;
      pb[gcur[k] + (i - lbase[k])] = sbuf[i];
    }
    __syncthreads();
    if (tid < NBK) gcur[tid] += lcnt[tid];
    __syncthreads();
  }
}

__global__ __launch_bounds__(256) void final_scatter(const unsigned* __restrict__ pbuf,
                                                     const int* __restrict__ bbase,
                                                     int* __restrict__ csr,
                                                     int* __restrict__ offs,
                                                     float* __restrict__ dinv1) {
  int blk = blockIdx.x;
  int b = blk >> 4, k = blk & 15;
  __shared__ int ncnt[512], nbase[512], nfill[512];
  __shared__ int sred[256];
  __shared__ unsigned sbuf[FCAP];
  int tid = threadIdx.x;
  int gbase = bbase[b * (NBK + 1) + k];
  int gend  = bbase[b * (NBK + 1) + k + 1];
  int cnt = gend - gbase;
  const unsigned* pb = pbuf + (size_t)b * E + gbase;

  for (int i = tid; i < 512; i += 256) { ncnt[i] = 0; nfill[i] = 0; }
  __syncthreads();
  for (int i = tid; i < cnt; i += 256) atomicAdd(&ncnt[pb[i] >> 13], 1);
  __syncthreads();
  int v0 = ncnt[2 * tid], v1 = ncnt[2 * tid + 1];
  int s = v0 + v1;
  sred[tid] = s;
  __syncthreads();
  for (int off = 1; off < 256; off <<= 1) {
    int x = (tid >= off) ? sred[tid - off] : 0;
    __syncthreads();
    sred[tid] += x;
    __syncthreads();
  }
  int ex = sred[tid] - s;
  nbase[2 * tid] = ex;
  nbase[2 * tid + 1] = ex + v0;
  __syncthreads();
  for (int i = tid; i < 512; i += 256) {
    int node = k * 512 + i;
    offs[b * (N + 1) + node] = gbase + nbase[i];
    dinv1[b * N + node] = rsqrtf((float)ncnt[i] + 1.0f);
  }
  if (k == 15 && tid == 0) offs[b * (N + 1) + N] = E;
  __syncthreads();
  for (int i = tid; i < cnt; i += 256) {
    unsigned pk = pb[i];
    int node = pk >> 13;
    int idx = atomicAdd(&nfill[node], 1);
    sbuf[nbase[node] + idx] = pk & 8191u;
  }
  __syncthreads();
  int* co = csr + (size_t)b * E + gbase;
  for (int i = tid; i < cnt; i += 256) co[i] = (int)sbuf[i];
}

// ---------------------------------------------------------------------------
// W[128][128] fp32 -> Wt[128][128] bf16 transposed, 3 weights in one launch
// ---------------------------------------------------------------------------
__global__ __launch_bounds__(256) void prep_wt3(const float* __restrict__ W1,
                                                const float* __restrict__ W2,
                                                const float* __restrict__ W3,
                                                unsigned short* __restrict__ Wt) {
  const float* W = (blockIdx.x == 0) ? W1 : (blockIdx.x == 1) ? W2 : W3;
  unsigned short* o = Wt + blockIdx.x * 128 * 128;
  for (int i = threadIdx.x; i < 128 * 128; i += 256) {
    int k = i >> 7, n = i & 127;
    o[n * 128 + k] = f2bf(W[i]);
  }
}

// ---------------------------------------------------------------------------
// MFMA GEMM: C[M,128](bf16) = diag(fscale) @ A[M,128] @ W (fscale in epilogue)
// ---------------------------------------------------------------------------
template <bool ABF16>
__global__ __launch_bounds__(256) void gemm_mfma(const void* __restrict__ Ap,
                                                 const unsigned short* __restrict__ Wt,
                                                 unsigned short* __restrict__ Cb,
                                                 const float* __restrict__ fscale) {
  int wv   = threadIdx.x >> 6;
  int lane = threadIdx.x & 63;
  int l15  = lane & 15, lg = lane >> 4;
  size_t rowbase = (size_t)blockIdx.x * 128 + wv * 32;

  short8 afrag[2][4];
#pragma unroll
  for (int rg = 0; rg < 2; ++rg) {
    size_t row = rowbase + rg * 16 + l15;
#pragma unroll
    for (int c = 0; c < 4; ++c) {
      int k0 = c * 32 + lg * 8;
      if (ABF16) {
        afrag[rg][c] = *(const short8*)((const unsigned short*)Ap + row * 128 + k0);
      } else {
        const float* p = (const float*)Ap + row * 128 + k0;
        float4 v0 = *(const float4*)p;
        float4 v1 = *(const float4*)(p + 4);
        short8 a;
        a[0] = (short)f2bf(v0.x); a[1] = (short)f2bf(v0.y);
        a[2] = (short)f2bf(v0.z); a[3] = (short)f2bf(v0.w);
        a[4] = (short)f2bf(v1.x); a[5] = (short)f2bf(v1.y);
        a[6] = (short)f2bf(v1.z); a[7] = (short)f2bf(v1.w);
        afrag[rg][c] = a;
      }
    }
  }

  float fsr0[4] = {1.f, 1.f, 1.f, 1.f}, fsr1[4] = {1.f, 1.f, 1.f, 1.f};
  if (fscale != nullptr) {
    float4 t0 = *(const float4*)(fscale + rowbase + lg * 4);
    float4 t1 = *(const float4*)(fscale + rowbase + 16 + lg * 4);
    fsr0[0] = t0.x; fsr0[1] = t0.y; fsr0[2] = t0.z; fsr0[3] = t0.w;
    fsr1[0] = t1.x; fsr1[1] = t1.y; fsr1[2] = t1.z; fsr1[3] = t1.w;
  }

#pragma unroll
  for (int t = 0; t < 8; ++t) {
    int col = t * 16 + l15;
    short8 bfrag[4];
#pragma unroll
    for (int c = 0; c < 4; ++c)
      bfrag[c] = *(const short8*)(Wt + col * 128 + c * 32 + lg * 8);

    floatx4 acc0 = {0.f, 0.f, 0.f, 0.f};
    floatx4 acc1 = {0.f, 0.f, 0.f, 0.f};
#pragma unroll
    for (int c = 0; c < 4; ++c) {
      acc0 = __builtin_amdgcn_mfma_f32_16x16x32_bf16(afrag[0][c], bfrag[c], acc0, 0, 0, 0);
      acc1 = __builtin_amdgcn_mfma_f32_16x16x32_bf16(afrag[1][c], bfrag[c], acc1, 0, 0, 0);
    }
#pragma unroll
    for (int r = 0; r < 4; ++r) {
      size_t row0 = rowbase + lg * 4 + r;
      size_t row1 = rowbase + 16 + lg * 4 + r;
      Cb[row0 * 128 + col] = f2bf(acc0[r] * fsr0[r]);
      Cb[row1 * 128 + col] = f2bf(acc1[r] * fsr1[r]);
    }
  }
}

// ---------------------------------------------------------------------------
// GCN aggregation v5: 2 nodes per wave, first 32 edges of both nodes
// prefetched via quarter-broadcast metadata loads (lane quarter g owns edges
// e ≡ g mod 4) — NO bpermute, no wave-wide dependency; 32 independent loads
// in flight per wave. ecnt==null -> degree from offs (layer 1, all live).
// ---------------------------------------------------------------------------
template <bool ALL_LIVE>
__global__ __launch_bounds__(256) void gcn_agg5(
    const unsigned* __restrict__ tmp, const float* __restrict__ dinv,
    const int* __restrict__ offs, const int* __restrict__ ecnt,
    const int* __restrict__ csr, const float* __restrict__ bias,
    unsigned* __restrict__ hout,
    const float* __restrict__ wrel, const float* __restrict__ wroot,
    float* __restrict__ rr, float* __restrict__ tt) {
  int blk = blockIdx.x;                // B*N/8 = 16384
  int xcd = blk & 7;
  int j   = blk >> 3;                  // 0..2047
  int b   = xcd * 2 + (j >> 10);       // 2 graphs per XCD
  int ng  = j & 1023;                  // 8 nodes per block
  int wv   = threadIdx.x >> 6;
  int lane = threadIdx.x & 63;
  int g  = lane >> 4;
  int fo = (lane & 15) << 4;           // byte offset within a 256 B row
  int n0 = ng * 8 + wv * 2;
  int wid0 = b * N + n0;

  const unsigned* tmpb = tmp + (((size_t)b << 13) << 6);
  const float* dvb = dinv + (b << 13);
  const int*   cs  = csr + (size_t)b * E;

  // uniform node meta
  int o0[2], d[2]; float dv[2];
#pragma unroll
  for (int i = 0; i < 2; ++i) {
    int nb = b * (N + 1) + n0 + i;
    o0[i] = __builtin_amdgcn_readfirstlane(offs[nb]);
    if (ecnt != nullptr)
      d[i] = __builtin_amdgcn_readfirstlane(ecnt[wid0 + i]);
    else
      d[i] = __builtin_amdgcn_readfirstlane(offs[nb + 1]) - o0[i];
    dv[i] = rdlane_f(dinv[wid0 + i], 0);
    if (d[i] == 0) o0[i] = 0;          // safe clamp target
  }

  // phase 1: metadata for first 32 edges of both nodes (quarter-broadcast)
  int sw[2][8];
#pragma unroll
  for (int i = 0; i < 2; ++i) {
    if (ALL_LIVE || dv[i] > 0.0f) {
      int dm = d[i] - 1; if (dm < 0) dm = 0;
#pragma unroll
      for (int t = 0; t < 8; ++t) {
        int e = t * 4 + g;
        sw[i][t] = cs[o0[i] + (e < d[i] ? e : dm)];
      }
    } else {
#pragma unroll
      for (int t = 0; t < 8; ++t) sw[i][t] = 0;
    }
  }
  // self rows (issue early)
  uint4 su[2];
#pragma unroll
  for (int i = 0; i < 2; ++i)
    su[i] = *(const uint4*)((const char*)tmpb + (((unsigned)(n0 + i) << 8) + fo));
  // phase 2: weight gathers (16 independent)
  float wq[2][8];
#pragma unroll
  for (int i = 0; i < 2; ++i)
#pragma unroll
    for (int t = 0; t < 8; ++t) {
      float w = dvb[sw[i][t]];
      wq[i][t] = (t * 4 + g < d[i]) ? w : 0.0f;
    }

  // phase 3: per-node row gathers + FMA + epilogue
#pragma unroll
  for (int i = 0; i < 2; ++i) {
    int wid = wid0 + i;
    uint4* hrow4 = (uint4*)(hout + (size_t)wid * 64);
    if (!ALL_LIVE && dv[i] <= 0.0f) {
      if (lane < 16) hrow4[lane] = make_uint4(0u, 0u, 0u, 0u);
      continue;
    }
    float acc[8] = {};
    int nblk = (d[i] + 15) >> 4; if (nblk > 2) nblk = 2;
    for (int b16 = 0; b16 < nblk; ++b16) {
#pragma unroll
      for (int q = 0; q < 4; ++q) {
        int t = b16 * 4 + q;
        uint4 u = *(const uint4*)((const char*)tmpb + (((unsigned)sw[i][t] << 8) + fo));
        float w = wq[i][t];
        acc[0] += w * __uint_as_float(u.x << 16);
        acc[1] += w * __uint_as_float(u.x & 0xFFFF0000u);
        acc[2] += w * __uint_as_float(u.y << 16);
        acc[3] += w * __uint_as_float(u.y & 0xFFFF0000u);
        acc[4] += w * __uint_as_float(u.z << 16);
        acc[5] += w * __uint_as_float(u.z & 0xFFFF0000u);
        acc[6] += w * __uint_as_float(u.w << 16);
        acc[7] += w * __uint_as_float(u.w & 0xFFFF0000u);
      }
    }
    // residual (deg > 32) — astronomically rare, correctness only
    for (int base = 32; base < d[i]; base += 16) {
#pragma unroll
      for (int q = 0; q < 4; ++q) {
        int e = base + q * 4 + g;
        int a = o0[i] + (e < d[i] ? e : d[i] - 1);
        int s = cs[a];
        float w = (e < d[i]) ? dvb[s] : 0.0f;
        uint4 u = *(const uint4*)((const char*)tmpb + (((unsigned)s << 8) + fo));
        acc[0] += w * __uint_as_float(u.x << 16);
        acc[1] += w * __uint_as_float(u.x & 0xFFFF0000u);
        acc[2] += w * __uint_as_float(u.y << 16);
        acc[3] += w * __uint_as_float(u.y & 0xFFFF0000u);
        acc[4] += w * __uint_as_float(u.z << 16);
        acc[5] += w * __uint_as_float(u.z & 0xFFFF0000u);
        acc[6] += w * __uint_as_float(u.w << 16);
        acc[7] += w * __uint_as_float(u.w & 0xFFFF0000u);
      }
    }
    // reduce the 4 lane quarters
#pragma unroll
    for (int q = 0; q < 8; ++q) {
      acc[q] += __shfl_xor(acc[q], 16);
      acc[q] += __shfl_xor(acc[q], 32);
    }
    // self term + bias + relu
    float dvi = dv[i];
    float sv[8];
    sv[0] = __uint_as_float(su[i].x << 16); sv[1] = __uint_as_float(su[i].x & 0xFFFF0000u);
    sv[2] = __uint_as_float(su[i].y << 16); sv[3] = __uint_as_float(su[i].y & 0xFFFF0000u);
    sv[4] = __uint_as_float(su[i].z << 16); sv[5] = __uint_as_float(su[i].z & 0xFFFF0000u);
    sv[6] = __uint_as_float(su[i].w << 16); sv[7] = __uint_as_float(su[i].w & 0xFFFF0000u);
    const float4 b0 = *(const float4*)(bias + (fo >> 1));
    const float4 b1 = *(const float4*)(bias + (fo >> 1) + 4);
    float outv[8];
    outv[0] = fmaxf(dvi * (acc[0] + dvi * sv[0]) + b0.x, 0.f);
    outv[1] = fmaxf(dvi * (acc[1] + dvi * sv[1]) + b0.y, 0.f);
    outv[2] = fmaxf(dvi * (acc[2] + dvi * sv[2]) + b0.z, 0.f);
    outv[3] = fmaxf(dvi * (acc[3] + dvi * sv[3]) + b0.w, 0.f);
    outv[4] = fmaxf(dvi * (acc[4] + dvi * sv[4]) + b1.x, 0.f);
    outv[5] = fmaxf(dvi * (acc[5] + dvi * sv[5]) + b1.y, 0.f);
    outv[6] = fmaxf(dvi * (acc[6] + dvi * sv[6]) + b1.z, 0.f);
    outv[7] = fmaxf(dvi * (acc[7] + dvi * sv[7]) + b1.w, 0.f);

    uint4 po;
    po.x = cvt_pk_bf16(outv[0], outv[1]);
    po.y = cvt_pk_bf16(outv[2], outv[3]);
    po.z = cvt_pk_bf16(outv[4], outv[5]);
    po.w = cvt_pk_bf16(outv[6], outv[7]);
    if (lane < 16) hrow4[lane] = po;

    if (rr != nullptr) {                      // fused pool dots
      const float4 wr0 = *(const float4*)(wrel + (fo >> 1));
      const float4 wr1 = *(const float4*)(wrel + (fo >> 1) + 4);
      const float4 wo0 = *(const float4*)(wroot + (fo >> 1));
      const float4 wo1 = *(const float4*)(wroot + (fo >> 1) + 4);
      float pr = outv[0] * wr0.x + outv[1] * wr0.y + outv[2] * wr0.z + outv[3] * wr0.w
               + outv[4] * wr1.x + outv[5] * wr1.y + outv[6] * wr1.z + outv[7] * wr1.w;
      float pt = outv[0] * wo0.x + outv[1] * wo0.y + outv[2] * wo0.z + outv[3] * wo0.w
               + outv[4] * wo1.x + outv[5] * wo1.y + outv[6] * wo1.z + outv[7] * wo1.w;
#pragma unroll
      for (int dd = 1; dd < 16; dd <<= 1) {
        pr += __shfl_xor(pr, dd);
        pt += __shfl_xor(pt, dd);
      }
      if (lane == 0) { rr[wid] = pr; tt[wid] = pt; }
    }
  }
}

// ---------------------------------------------------------------------------
// compact_pool: ONE fused pass per pool. Wave per node: gather mask[src],
// ballot-compact live srcs IN PLACE (per-node range, write never passes the
// read cursor), emit live count + new dinv. csr is rebuilt every launch by
// final_scatter, so in-place mutation is replay-deterministic.
// ---------------------------------------------------------------------------
__global__ __launch_bounds__(256) void compact_pool(
    const float* __restrict__ mask, const int* __restrict__ offs,
    const int* __restrict__ ecnt_in, int* __restrict__ csr,
    int* __restrict__ ecnt_out, float* __restrict__ dinv_out) {
  int wid = blockIdx.x * 4 + (threadIdx.x >> 6);
  int lane = threadIdx.x & 63;
  int b = wid >> 13, n = wid & (N - 1);
  float m = rdlane_f(mask[wid], 0);
  if (m <= 0.0f) {
    if (lane == 0) { ecnt_out[wid] = 0; dinv_out[wid] = 0.0f; }
    return;
  }
  int nb = b * (N + 1) + n;
  int o0 = __builtin_amdgcn_readfirstlane(offs[nb]);
  int din = (ecnt_in != nullptr)
                ? __builtin_amdgcn_readfirstlane(ecnt_in[wid])
                : __builtin_amdgcn_readfirstlane(offs[nb + 1]) - o0;
  int* cs = csr + (size_t)b * E;
  const float* mb = mask + b * N;
  int wpos = o0;
  for (int base = 0; base < din; base += 64) {
    int nv = din - base; if (nv > 64) nv = 64;
    int s = (lane < nv) ? cs[o0 + base + lane] : 0;
    bool alive = (lane < nv) && (mb[s] > 0.0f);
    unsigned long long bal = __ballot(alive);
    int idx = __popcll(bal & ((1ull << lane) - 1ull));
    if (alive) cs[wpos + idx] = s;
    wpos += __popcll(bal);
  }
  if (lane == 0) {
    int total = wpos - o0;
    ecnt_out[wid] = total;
    dinv_out[wid] = rsqrtf((float)total + 1.0f);
  }
}

// ---------------------------------------------------------------------------
// pool score: score[n] = live*(sum_in r[src] + t[n] + b); 16 lanes/node.
// ---------------------------------------------------------------------------
__global__ __launch_bounds__(256) void score_agg(const float* __restrict__ r,
                                                 const float* __restrict__ t,
                                                 const float* __restrict__ pb,
                                                 const float* __restrict__ livep,
                                                 const int* __restrict__ offs,
                                                 const int* __restrict__ ecnt,
                                                 const int* __restrict__ csr,
                                                 float* __restrict__ score) {
  int grp = threadIdx.x >> 4;
  int gl  = threadIdx.x & 15;
  int nid = blockIdx.x * 16 + grp;
  int b = nid >> 13, n = nid & (N - 1);
  bool live = (livep == nullptr) || (livep[nid] > 0.0f);
  float s = 0.0f;
  if (live) {
    int o0 = offs[b * (N + 1) + n];
    int d = (ecnt != nullptr) ? ecnt[nid] : offs[b * (N + 1) + n + 1] - o0;
    const int* cs = csr + (size_t)b * E;
    const float* rb = r + b * N;
    for (int base = 0; base < d; base += 16)
      if (base + gl < d) s += rb[cs[o0 + base + gl]];
  }
#pragma unroll
  for (int dd = 8; dd > 0; dd >>= 1) s += __shfl_xor(s, dd, 16);
  if (gl == 0) score[nid] = live ? (s + t[nid] + pb[0]) : 0.0f;
}

// ---------------------------------------------------------------------------
// top-k via radix select (unchanged)
// ---------------------------------------------------------------------------
__device__ __forceinline__ unsigned fkey(float s, float m) {
  if (m <= 0.0f) return 0u;
  unsigned u = __float_as_uint(s);
  return (u & 0x80000000u) ? ~u : (u | 0x80000000u);
}

__global__ __launch_bounds__(1024) void topk_kernel(const float* __restrict__ score,
                                                    const float* __restrict__ mkin,
                                                    float* __restrict__ mkout,
                                                    float* __restrict__ fscale,
                                                    int k) {
  int b = blockIdx.x, tid = threadIdx.x;
  const float* sc = score + b * N;
  float* mk = mkout + b * N;
  float* fs = fscale + b * N;
  __shared__ unsigned keyb[N];
  __shared__ int hist[256];
  __shared__ int sbuf[1024];
  __shared__ unsigned sh_prefix;
  __shared__ int sh_kneed;

  for (int i = tid; i < N; i += 1024) {
    float m = (mkin == nullptr) ? 1.0f : mkin[b * N + i];
    keyb[i] = fkey(sc[i], m);
  }
  __syncthreads();

  unsigned prefix = 0, hm = 0;
  int kneed = k;
  for (int shift = 24; shift >= 0; shift -= 8) {
    if (tid < 256) hist[tid] = 0;
    __syncthreads();
    for (int i = tid; i < N; i += 1024) {
      unsigned key = keyb[i];
      if ((key & hm) == prefix) atomicAdd(&hist[(key >> shift) & 255], 1);
    }
    __syncthreads();
    if (tid < 256) sbuf[tid] = hist[tid];
    __syncthreads();
    for (int off = 1; off < 256; off <<= 1) {
      int v = (tid < 256 && tid + off < 256) ? sbuf[tid + off] : 0;
      __syncthreads();
      if (tid < 256) sbuf[tid] += v;
      __syncthreads();
    }
    if (tid < 256) {
      int ge = sbuf[tid];
      int gt = (tid < 255) ? sbuf[tid + 1] : 0;
      if (ge >= kneed && gt < kneed) {
        sh_prefix = prefix | ((unsigned)tid << shift);
        sh_kneed = kneed - gt;
      }
    }
    __syncthreads();
    prefix = sh_prefix;
    kneed = sh_kneed;
    hm |= (0xFFu << shift);
    __syncthreads();
  }

  unsigned T = prefix;
  int base = tid * 8;
  unsigned keys[8];
  int eqf[8];
  int cnt = 0;
#pragma unroll
  for (int q = 0; q < 8; ++q) {
    keys[q] = keyb[base + q];
    eqf[q] = (keys[q] == T) ? 1 : 0;
    cnt += eqf[q];
  }
  sbuf[tid] = cnt; __syncthreads();
  for (int off = 1; off < 1024; off <<= 1) {
    int x = (tid >= off) ? sbuf[tid - off] : 0;
    __syncthreads();
    sbuf[tid] += x;
    __syncthreads();
  }
  int ex = sbuf[tid] - cnt;
#pragma unroll
  for (int q = 0; q < 8; ++q) {
    bool sel = (keys[q] > T) || (eqf[q] && (ex < kneed));
    ex += eqf[q];
    mk[base + q] = sel ? 1.0f : 0.0f;
    fs[base + q] = sel ? tanhf(sc[base + q]) : 0.0f;
  }
}

// ---------------------------------------------------------------------------
// readout partials (bf16 h) + head MLP + log_softmax
// ---------------------------------------------------------------------------
__global__ __launch_bounds__(256) void readout(const unsigned short* __restrict__ h,
                                               float* __restrict__ part) {
  int b = blockIdx.x, c = blockIdx.y;
  int tid = threadIdx.x;
  int f = tid & 127, half = tid >> 7;
  float acc = 0.0f;
  for (int n = c * 256 + half; n < (c + 1) * 256; n += 2)
    acc += bf2f(h[((size_t)b * N + n) * 128 + f]);
  __shared__ float red[256];
  red[tid] = acc; __syncthreads();
  if (half == 0) part[((size_t)b * 32 + c) * 128 + f] = red[f] + red[f + 128];
}

__global__ __launch_bounds__(128) void head(const float* __restrict__ part,
                                            const float* __restrict__ l1w,
                                            const float* __restrict__ l1b,
                                            const float* __restrict__ l2w,
                                            const float* __restrict__ l2b,
                                            float* __restrict__ out) {
  int b = blockIdx.x, f = threadIdx.x;
  float g = 0.0f;
  for (int c = 0; c < 32; ++c) g += part[((size_t)b * 32 + c) * 128 + f];
  g *= (1.0f / (float)K2);
  __shared__ float gs[128], hh[128], lg[10];
  gs[f] = g; __syncthreads();
  float a = l1b[f];
  for (int kk = 0; kk < 128; ++kk) a += gs[kk] * l1w[kk * 128 + f];
  hh[f] = fmaxf(a, 0.0f); __syncthreads();
  if (f < 10) {
    float l = l2b[f];
    for (int j = 0; j < 128; ++j) l += hh[j] * l2w[j * 10 + f];
    lg[f] = l;
  }
  __syncthreads();
  if (f == 0) {
    float m = lg[0];
    for (int c = 1; c < 10; ++c) m = fmaxf(m, lg[c]);
    float s = 0.0f;
    for (int c = 0; c < 10; ++c) s += expf(lg[c] - m);
    float lse = m + logf(s);
    for (int c = 0; c < 10; ++c) out[b * 10 + c] = lg[c] - lse;
  }
}

// ---------------------------------------------------------------------------
extern "C" void kernel_launch(void* const* d_in, const int* in_sizes, int n_in,
                              void* d_out, int out_size, void* d_ws, size_t ws_size,
                              hipStream_t stream) {
  (void)in_sizes; (void)n_in; (void)out_size; (void)ws_size;
  const float* x       = (const float*)d_in[0];
  const int*   ei      = (const int*)d_in[1];
  const float* W1      = (const float*)d_in[2];
  const float* b1      = (const float*)d_in[3];
  const float* p1_wrel = (const float*)d_in[4];
  const float* p1_wroot= (const float*)d_in[5];
  const float* p1_b    = (const float*)d_in[6];
  const float* W2      = (const float*)d_in[7];
  const float* b2      = (const float*)d_in[8];
  const float* p2_wrel = (const float*)d_in[9];
  const float* p2_wroot= (const float*)d_in[10];
  const float* p2_b    = (const float*)d_in[11];
  const float* W3      = (const float*)d_in[12];
  const float* b3      = (const float*)d_in[13];
  const float* l1w     = (const float*)d_in[14];
  const float* l1b     = (const float*)d_in[15];
  const float* l2w     = (const float*)d_in[16];
  const float* l2b     = (const float*)d_in[17];
  float* out = (float*)d_out;

  char* p = (char*)d_ws;
  auto alloc = [&](size_t bytes) {
    char* r = p;
    p += ((bytes + 255) & ~(size_t)255);
    return r;
  };
  unsigned short* h   = (unsigned short*)alloc((size_t)B * N * H * 2);   // bf16
  unsigned short* tmp = (unsigned short*)alloc((size_t)B * N * H * 2);   // bf16
  int*      offs   = (int*)alloc((size_t)B * (N + 1) * 4);
  int*      csr    = (int*)alloc((size_t)B * E * 4);
  unsigned* pbuf   = (unsigned*)alloc((size_t)B * E * 4);
  int*      bchist = (int*)alloc((size_t)B * CHUNKS * NBK * 4);
  int*      cursor = (int*)alloc((size_t)B * CHUNKS * NBK * 4);
  int*      bbase  = (int*)alloc((size_t)B * (NBK + 1) * 4);
  int*      ecnt   = (int*)alloc((size_t)B * N * 4);
  float* dinv   = (float*)alloc((size_t)B * N * 4);
  float* mask   = (float*)alloc((size_t)B * N * 4);
  float* rr     = (float*)alloc((size_t)B * N * 4);
  float* tt     = (float*)alloc((size_t)B * N * 4);
  float* score  = (float*)alloc((size_t)B * N * 4);
  float* fscale = (float*)alloc((size_t)B * N * 4);
  float* part   = (float*)alloc((size_t)B * 32 * H * 4);
  unsigned short* Wts = (unsigned short*)alloc(3 * 128 * 128 * 2);

  // CSR build (streaming counting sort) + weight prep
  hist_pass<<<B * CHUNKS, 256, 0, stream>>>(ei, bchist);
  bucket_scan<<<B, 256, 0, stream>>>(bchist, cursor, bbase);
  bin_scatter<<<B * CHUNKS, 256, 0, stream>>>(ei, cursor, pbuf);
  final_scatter<<<B * NBK, 256, 0, stream>>>(pbuf, bbase, csr, offs, dinv);
  prep_wt3<<<3, 256, 0, stream>>>(W1, W2, W3, Wts);

  // ---- layer 1 + pool 1 (all nodes live)
  gemm_mfma<false><<<(B * N) / 128, 256, 0, stream>>>(x, Wts, tmp, nullptr);
  gcn_agg5<true><<<B * N / 8, 256, 0, stream>>>((const unsigned*)tmp, dinv, offs,
                                                nullptr, csr, b1, (unsigned*)h,
                                                p1_wrel, p1_wroot, rr, tt);
  score_agg<<<B * N / 16, 256, 0, stream>>>(rr, tt, p1_b, nullptr, offs, nullptr,
                                            csr, score);
  topk_kernel<<<B, 1024, 0, stream>>>(score, nullptr, mask, fscale, K1);
  compact_pool<<<B * N / 4, 256, 0, stream>>>(mask, offs, nullptr, csr, ecnt, dinv);

  // ---- layer 2 + pool 2
  gemm_mfma<true><<<(B * N) / 128, 256, 0, stream>>>(h, Wts + 128 * 128, tmp, fscale);
  gcn_agg5<false><<<B * N / 8, 256, 0, stream>>>((const unsigned*)tmp, dinv, offs,
                                                 ecnt, csr, b2, (unsigned*)h,
                                                 p2_wrel, p2_wroot, rr, tt);
  score_agg<<<B * N / 16, 256, 0, stream>>>(rr, tt, p2_b, dinv, offs, ecnt, csr, score);
  topk_kernel<<<B, 1024, 0, stream>>>(score, mask, mask, fscale, K2);
  compact_pool<<<B * N / 4, 256, 0, stream>>>(mask, offs, ecnt, csr, ecnt, dinv);

  // ---- layer 3
  gemm_mfma<true><<<(B * N) / 128, 256, 0, stream>>>(h, Wts + 2 * 128 * 128, tmp, fscale);
  gcn_agg5<false><<<B * N / 8, 256, 0, stream>>>((const unsigned*)tmp, dinv, offs,
                                                 ecnt, csr, b3, (unsigned*)h,
                                                 nullptr, nullptr, nullptr, nullptr);

  // ---- readout + head
  readout<<<dim3(B, 32), 256, 0, stream>>>(h, part);
  head<<<B, 128, 0, stream>>>(part, l1w, l1b, l2w, l2b, out);
}

// Round 8
// 450.124 us; speedup vs baseline: 1.1931x; 1.1931x over previous
//
#include <hip/hip_runtime.h>
#include <hip/hip_bf16.h>
#include <math.h>

// Problem constants
constexpr int B  = 16;
constexpr int N  = 8192;     // 2^13
constexpr int E  = 131072;   // 2^17
constexpr int H  = 128;
constexpr int K1 = 4096;
constexpr int K2 = 2048;

constexpr int CHUNKS = 16;         // edge chunks per graph (8192 edges each)
constexpr int NBK    = 16;         // dst buckets (dst>>9, 512 nodes each)
constexpr int FCAP   = 12288;      // final_scatter LDS capacity

typedef __attribute__((ext_vector_type(8))) short short8;
typedef __attribute__((ext_vector_type(4))) float floatx4;

__device__ __forceinline__ unsigned short f2bf(float f) {
  unsigned u = __float_as_uint(f);
  return (unsigned short)((u + 0x7FFFu + ((u >> 16) & 1u)) >> 16);  // RNE
}
__device__ __forceinline__ float bf2f(unsigned short s) {
  return __uint_as_float(((unsigned)s) << 16);
}
__device__ __forceinline__ int rdlane_i(int v, int l) {
  return __builtin_amdgcn_readlane(v, l);
}
__device__ __forceinline__ float rdlane_f(float v, int l) {
  return __uint_as_float((unsigned)__builtin_amdgcn_readlane((int)__float_as_uint(v), l));
}
__device__ __forceinline__ unsigned cvt_pk_bf16(float a, float b) {
  unsigned r;
  asm("v_cvt_pk_bf16_f32 %0, %1, %2" : "=v"(r) : "v"(a), "v"(b));
  return r;
}

// ---------------------------------------------------------------------------
// CSR build (streaming counting sort) — unchanged from R5
// ---------------------------------------------------------------------------
__global__ __launch_bounds__(256) void hist_pass(const int* __restrict__ ei,
                                                 int* __restrict__ bchist) {
  int blk = blockIdx.x;                 // B*CHUNKS = 256
  int b = blk >> 4, c = blk & 15;
  __shared__ int h16[NBK];
  if (threadIdx.x < NBK) h16[threadIdx.x] = 0;
  __syncthreads();
  const int* dstp = ei + (size_t)b * 2 * E + E + c * 8192;
  for (int i = 0; i < 32; ++i) {
    int dst = dstp[i * 256 + threadIdx.x];
    atomicAdd(&h16[dst >> 9], 1);
  }
  __syncthreads();
  if (threadIdx.x < NBK) bchist[(blk << 4) + threadIdx.x] = h16[threadIdx.x];
}

__global__ __launch_bounds__(256) void bucket_scan(const int* __restrict__ bchist,
                                                   int* __restrict__ cursor,
                                                   int* __restrict__ bbase) {
  int b = blockIdx.x;                   // B = 16
  int tid = threadIdx.x;                // 256 = CHUNKS*NBK
  int c = tid >> 4, k = tid & 15;
  __shared__ int arr[CHUNKS][NBK];
  __shared__ int base[NBK + 1];
  arr[c][k] = bchist[((b * CHUNKS + c) << 4) + k];
  __syncthreads();
  if (tid == 0) {
    int run = 0;
    for (int kk = 0; kk < NBK; ++kk) {
      base[kk] = run;
      int t = 0;
      for (int cc = 0; cc < CHUNKS; ++cc) t += arr[cc][kk];
      run += t;
    }
    base[NBK] = run;
  }
  __syncthreads();
  int pre = 0;
  for (int cc = 0; cc < c; ++cc) pre += arr[cc][k];
  cursor[((b * CHUNKS + c) << 4) + k] = base[k] + pre;
  if (tid < NBK + 1) bbase[b * (NBK + 1) + tid] = base[tid];
}

__global__ __launch_bounds__(256) void bin_scatter(const int* __restrict__ ei,
                                                   const int* __restrict__ cursor,
                                                   unsigned* __restrict__ pbuf) {
  int blk = blockIdx.x;
  int b = blk >> 4, c = blk & 15;
  __shared__ int gcur[NBK], lcnt[NBK], lfill[NBK];
  __shared__ int lbase[NBK + 1];
  __shared__ unsigned sbuf[2048];
  int tid = threadIdx.x;
  if (tid < NBK) gcur[tid] = cursor[(blk << 4) + tid];
  const int* srcp = ei + (size_t)b * 2 * E + c * 8192;
  const int* dstp = srcp + E;
  unsigned* pb = pbuf + (size_t)b * E;

  for (int sc = 0; sc < 4; ++sc) {
    if (tid < NBK) { lcnt[tid] = 0; lfill[tid] = 0; }
    __syncthreads();
    int s8[8], d8[8];
#pragma unroll
    for (int q = 0; q < 8; ++q) {
      int i = sc * 2048 + q * 256 + tid;
      s8[q] = srcp[i]; d8[q] = dstp[i];
      atomicAdd(&lcnt[d8[q] >> 9], 1);
    }
    __syncthreads();
    if (tid == 0) {
      int run = 0;
      for (int k = 0; k < NBK; ++k) { lbase[k] = run; run += lcnt[k]; }
      lbase[NBK] = run;
    }
    __syncthreads();
#pragma unroll
    for (int q = 0; q < 8; ++q) {
      int k = d8[q] >> 9;
      int idx = atomicAdd(&lfill[k], 1);
      sbuf[lbase[k] + idx] = ((unsigned)(d8[q] & 511) << 13) | (unsigned)s8[q];
    }
    __syncthreads();
    for (int i = tid; i < 2048; i += 256) {
      int k = 0;
      while (lbase[k + 1] <= i) ++k;
      pb[gcur[k] + (i - lbase[k])] = sbuf[i];
    }
    __syncthreads();
    if (tid < NBK) gcur[tid] += lcnt[tid];
    __syncthreads();
  }
}

__global__ __launch_bounds__(256) void final_scatter(const unsigned* __restrict__ pbuf,
                                                     const int* __restrict__ bbase,
                                                     int* __restrict__ csr,
                                                     int* __restrict__ offs,
                                                     float* __restrict__ dinv1) {
  int blk = blockIdx.x;
  int b = blk >> 4, k = blk & 15;
  __shared__ int ncnt[512], nbase[512], nfill[512];
  __shared__ int sred[256];
  __shared__ unsigned sbuf[FCAP];
  int tid = threadIdx.x;
  int gbase = bbase[b * (NBK + 1) + k];
  int gend  = bbase[b * (NBK + 1) + k + 1];
  int cnt = gend - gbase;
  const unsigned* pb = pbuf + (size_t)b * E + gbase;

  for (int i = tid; i < 512; i += 256) { ncnt[i] = 0; nfill[i] = 0; }
  __syncthreads();
  for (int i = tid; i < cnt; i += 256) atomicAdd(&ncnt[pb[i] >> 13], 1);
  __syncthreads();
  int v0 = ncnt[2 * tid], v1 = ncnt[2 * tid + 1];
  int s = v0 + v1;
  sred[tid] = s;
  __syncthreads();
  for (int off = 1; off < 256; off <<= 1) {
    int x = (tid >= off) ? sred[tid - off] : 0;
    __syncthreads();
    sred[tid] += x;
    __syncthreads();
  }
  int ex = sred[tid] - s;
  nbase[2 * tid] = ex;
  nbase[2 * tid + 1] = ex + v0;
  __syncthreads();
  for (int i = tid; i < 512; i += 256) {
    int node = k * 512 + i;
    offs[b * (N + 1) + node] = gbase + nbase[i];
    dinv1[b * N + node] = rsqrtf((float)ncnt[i] + 1.0f);
  }
  if (k == 15 && tid == 0) offs[b * (N + 1) + N] = E;
  __syncthreads();
  for (int i = tid; i < cnt; i += 256) {
    unsigned pk = pb[i];
    int node = pk >> 13;
    int idx = atomicAdd(&nfill[node], 1);
    sbuf[nbase[node] + idx] = pk & 8191u;
  }
  __syncthreads();
  int* co = csr + (size_t)b * E + gbase;
  for (int i = tid; i < cnt; i += 256) co[i] = (int)sbuf[i];
}

// ---------------------------------------------------------------------------
// W[128][128] fp32 -> Wt[128][128] bf16 transposed, 3 weights in one launch
// ---------------------------------------------------------------------------
__global__ __launch_bounds__(256) void prep_wt3(const float* __restrict__ W1,
                                                const float* __restrict__ W2,
                                                const float* __restrict__ W3,
                                                unsigned short* __restrict__ Wt) {
  const float* W = (blockIdx.x == 0) ? W1 : (blockIdx.x == 1) ? W2 : W3;
  unsigned short* o = Wt + blockIdx.x * 128 * 128;
  for (int i = threadIdx.x; i < 128 * 128; i += 256) {
    int k = i >> 7, n = i & 127;
    o[n * 128 + k] = f2bf(W[i]);
  }
}

// ---------------------------------------------------------------------------
// MFMA GEMM: C[M,128](bf16) = diag(fscale) @ A[M,128] @ W (fscale in epilogue)
// ---------------------------------------------------------------------------
template <bool ABF16>
__global__ __launch_bounds__(256) void gemm_mfma(const void* __restrict__ Ap,
                                                 const unsigned short* __restrict__ Wt,
                                                 unsigned short* __restrict__ Cb,
                                                 const float* __restrict__ fscale) {
  int wv   = threadIdx.x >> 6;
  int lane = threadIdx.x & 63;
  int l15  = lane & 15, lg = lane >> 4;
  size_t rowbase = (size_t)blockIdx.x * 128 + wv * 32;

  short8 afrag[2][4];
#pragma unroll
  for (int rg = 0; rg < 2; ++rg) {
    size_t row = rowbase + rg * 16 + l15;
#pragma unroll
    for (int c = 0; c < 4; ++c) {
      int k0 = c * 32 + lg * 8;
      if (ABF16) {
        afrag[rg][c] = *(const short8*)((const unsigned short*)Ap + row * 128 + k0);
      } else {
        const float* p = (const float*)Ap + row * 128 + k0;
        float4 v0 = *(const float4*)p;
        float4 v1 = *(const float4*)(p + 4);
        short8 a;
        a[0] = (short)f2bf(v0.x); a[1] = (short)f2bf(v0.y);
        a[2] = (short)f2bf(v0.z); a[3] = (short)f2bf(v0.w);
        a[4] = (short)f2bf(v1.x); a[5] = (short)f2bf(v1.y);
        a[6] = (short)f2bf(v1.z); a[7] = (short)f2bf(v1.w);
        afrag[rg][c] = a;
      }
    }
  }

  float fsr0[4] = {1.f, 1.f, 1.f, 1.f}, fsr1[4] = {1.f, 1.f, 1.f, 1.f};
  if (fscale != nullptr) {
    float4 t0 = *(const float4*)(fscale + rowbase + lg * 4);
    float4 t1 = *(const float4*)(fscale + rowbase + 16 + lg * 4);
    fsr0[0] = t0.x; fsr0[1] = t0.y; fsr0[2] = t0.z; fsr0[3] = t0.w;
    fsr1[0] = t1.x; fsr1[1] = t1.y; fsr1[2] = t1.z; fsr1[3] = t1.w;
  }

#pragma unroll
  for (int t = 0; t < 8; ++t) {
    int col = t * 16 + l15;
    short8 bfrag[4];
#pragma unroll
    for (int c = 0; c < 4; ++c)
      bfrag[c] = *(const short8*)(Wt + col * 128 + c * 32 + lg * 8);

    floatx4 acc0 = {0.f, 0.f, 0.f, 0.f};
    floatx4 acc1 = {0.f, 0.f, 0.f, 0.f};
#pragma unroll
    for (int c = 0; c < 4; ++c) {
      acc0 = __builtin_amdgcn_mfma_f32_16x16x32_bf16(afrag[0][c], bfrag[c], acc0, 0, 0, 0);
      acc1 = __builtin_amdgcn_mfma_f32_16x16x32_bf16(afrag[1][c], bfrag[c], acc1, 0, 0, 0);
    }
#pragma unroll
    for (int r = 0; r < 4; ++r) {
      size_t row0 = rowbase + lg * 4 + r;
      size_t row1 = rowbase + 16 + lg * 4 + r;
      Cb[row0 * 128 + col] = f2bf(acc0[r] * fsr0[r]);
      Cb[row1 * 128 + col] = f2bf(acc1[r] * fsr1[r]);
    }
  }
}

// ---------------------------------------------------------------------------
// GCN aggregation v6 == R5's proven v3 structure (wave per node, coalesced
// metadata load, readlane->SGPR broadcast, saddr row gathers, 16-deep
// batches, dual accumulators, low VGPR / high occupancy), extended with an
// optional compacted-degree array ecnt. For !ALL_LIVE, the edge list has
// been compacted to live->live edges, so no per-src masking is needed.
// ---------------------------------------------------------------------------
template <bool ALL_LIVE>
__global__ __launch_bounds__(256) void gcn_agg6(
    const unsigned* __restrict__ tmp, const float* __restrict__ dinv,
    const int* __restrict__ offs, const int* __restrict__ ecnt,
    const int* __restrict__ csr, const float* __restrict__ bias,
    unsigned* __restrict__ hout,
    const float* __restrict__ wrel, const float* __restrict__ wroot,
    float* __restrict__ rr, float* __restrict__ tt) {
  int blk = blockIdx.x;
  int xcd = blk & 7;
  int j   = blk >> 3;                      // 0..4095
  int b   = xcd * 2 + (j >> 11);           // 2 graphs per XCD
  int n   = (j & 2047) * 4 + (threadIdx.x >> 6);
  int wid = b * N + n;
  int lane = threadIdx.x & 63;

  float dv = rdlane_f(dinv[wid], 0);       // wave-uniform -> SGPR
  unsigned* hrow = hout + (size_t)wid * 64;

  if (!ALL_LIVE && dv <= 0.0f) {           // dead destination: zeros only
    hrow[lane] = 0u;
    if (rr != nullptr && lane == 0) { rr[wid] = 0.0f; tt[wid] = 0.0f; }
    return;
  }

  const unsigned* tmpb = tmp + (((size_t)b << 13) << 6);
  const float* dvb = dinv + (b << 13);
  const int*   cs  = csr + (size_t)b * E;

  float2 accA, accB;
  {
    const unsigned* selfp = tmpb + ((unsigned)n << 6);
    unsigned u = selfp[lane];
    accA.x = dv * __uint_as_float(u << 16);
    accA.y = dv * __uint_as_float(u & 0xFFFF0000u);
    accB.x = 0.0f; accB.y = 0.0f;
  }

  int nbase = b * (N + 1) + n;
  int o0 = __builtin_amdgcn_readfirstlane(offs[nbase]);
  int d;
  if (ALL_LIVE) d = __builtin_amdgcn_readfirstlane(offs[nbase + 1]) - o0;
  else          d = __builtin_amdgcn_readfirstlane(ecnt[wid]);

  for (int base = 0; base < d; base += 64) {
    int nv = d - base; if (nv > 64) nv = 64;
    int sl = 0; float wl = 0.0f;
    if (lane < nv) {
      sl = cs[o0 + base + lane];     // compacted lists: all srcs live
      wl = dvb[sl];
    }

    for (int i0 = 0; i0 < nv; i0 += 16) {
      unsigned uu[16]; float wq[16];
#pragma unroll
      for (int q = 0; q < 16; ++q) {
        int idx = i0 + q;                    // < 64 always; pads have w=0,s=0
        int   sq = rdlane_i(sl, idx);        // SGPR
        wq[q]    = rdlane_f(wl, idx);        // SGPR
        const unsigned* rowp = tmpb + ((unsigned)sq << 6);  // uniform base
        uu[q] = rowp[lane];                  // saddr + lane*4 voffset
      }
#pragma unroll
      for (int q = 0; q < 16; ++q) {
        float lo = __uint_as_float(uu[q] << 16);
        float hi = __uint_as_float(uu[q] & 0xFFFF0000u);
        if (q & 1) { accB.x += wq[q] * lo; accB.y += wq[q] * hi; }
        else       { accA.x += wq[q] * lo; accA.y += wq[q] * hi; }
      }
    }
  }

  float2 acc = {accA.x + accB.x, accA.y + accB.y};
  const float2 bb = *(const float2*)(bias + lane * 2);
  float2 outv;
  outv.x = fmaxf(dv * acc.x + bb.x, 0.0f);
  outv.y = fmaxf(dv * acc.y + bb.y, 0.0f);
  hrow[lane] = cvt_pk_bf16(outv.x, outv.y);

  if (rr != nullptr) {                        // fused pool dots r=h.wrel t=h.wroot
    const float2 wr = *(const float2*)(wrel + lane * 2);
    const float2 wo = *(const float2*)(wroot + lane * 2);
    float pr = outv.x * wr.x + outv.y * wr.y;
    float pt = outv.x * wo.x + outv.y * wo.y;
#pragma unroll
    for (int dd = 32; dd > 0; dd >>= 1) {
      pr += __shfl_down(pr, dd);
      pt += __shfl_down(pt, dd);
    }
    if (lane == 0) { rr[wid] = pr; tt[wid] = pt; }
  }
}

// ---------------------------------------------------------------------------
// compact_pool: ONE fused pass per pool. Wave per node: gather mask[src],
// ballot-compact live srcs IN PLACE (write cursor never passes read cursor),
// emit live count + new dinv. csr is rebuilt every launch -> deterministic.
// ---------------------------------------------------------------------------
__global__ __launch_bounds__(256) void compact_pool(
    const float* __restrict__ mask, const int* __restrict__ offs,
    const int* __restrict__ ecnt_in, int* __restrict__ csr,
    int* __restrict__ ecnt_out, float* __restrict__ dinv_out) {
  int wid = blockIdx.x * 4 + (threadIdx.x >> 6);
  int lane = threadIdx.x & 63;
  int b = wid >> 13, n = wid & (N - 1);
  float m = rdlane_f(mask[wid], 0);
  if (m <= 0.0f) {
    if (lane == 0) { ecnt_out[wid] = 0; dinv_out[wid] = 0.0f; }
    return;
  }
  int nb = b * (N + 1) + n;
  int o0 = __builtin_amdgcn_readfirstlane(offs[nb]);
  int din = (ecnt_in != nullptr)
                ? __builtin_amdgcn_readfirstlane(ecnt_in[wid])
                : __builtin_amdgcn_readfirstlane(offs[nb + 1]) - o0;
  int* cs = csr + (size_t)b * E;
  const float* mb = mask + b * N;
  int wpos = o0;
  for (int base = 0; base < din; base += 64) {
    int nv = din - base; if (nv > 64) nv = 64;
    int s = (lane < nv) ? cs[o0 + base + lane] : 0;
    bool alive = (lane < nv) && (mb[s] > 0.0f);
    unsigned long long bal = __ballot(alive);
    int idx = __popcll(bal & ((1ull << lane) - 1ull));
    if (alive) cs[wpos + idx] = s;
    wpos += __popcll(bal);
  }
  if (lane == 0) {
    int total = wpos - o0;
    ecnt_out[wid] = total;
    dinv_out[wid] = rsqrtf((float)total + 1.0f);
  }
}

// ---------------------------------------------------------------------------
// pool score: score[n] = live*(sum_in r[src] + t[n] + b); 16 lanes/node.
// ---------------------------------------------------------------------------
__global__ __launch_bounds__(256) void score_agg(const float* __restrict__ r,
                                                 const float* __restrict__ t,
                                                 const float* __restrict__ pb,
                                                 const float* __restrict__ livep,
                                                 const int* __restrict__ offs,
                                                 const int* __restrict__ ecnt,
                                                 const int* __restrict__ csr,
                                                 float* __restrict__ score) {
  int grp = threadIdx.x >> 4;
  int gl  = threadIdx.x & 15;
  int nid = blockIdx.x * 16 + grp;
  int b = nid >> 13, n = nid & (N - 1);
  bool live = (livep == nullptr) || (livep[nid] > 0.0f);
  float s = 0.0f;
  if (live) {
    int o0 = offs[b * (N + 1) + n];
    int d = (ecnt != nullptr) ? ecnt[nid] : offs[b * (N + 1) + n + 1] - o0;
    const int* cs = csr + (size_t)b * E;
    const float* rb = r + b * N;
    for (int base = 0; base < d; base += 16)
      if (base + gl < d) s += rb[cs[o0 + base + gl]];
  }
#pragma unroll
  for (int dd = 8; dd > 0; dd >>= 1) s += __shfl_xor(s, dd, 16);
  if (gl == 0) score[nid] = live ? (s + t[nid] + pb[0]) : 0.0f;
}

// ---------------------------------------------------------------------------
// top-k via radix select (unchanged)
// ---------------------------------------------------------------------------
__device__ __forceinline__ unsigned fkey(float s, float m) {
  if (m <= 0.0f) return 0u;
  unsigned u = __float_as_uint(s);
  return (u & 0x80000000u) ? ~u : (u | 0x80000000u);
}

__global__ __launch_bounds__(1024) void topk_kernel(const float* __restrict__ score,
                                                    const float* __restrict__ mkin,
                                                    float* __restrict__ mkout,
                                                    float* __restrict__ fscale,
                                                    int k) {
  int b = blockIdx.x, tid = threadIdx.x;
  const float* sc = score + b * N;
  float* mk = mkout + b * N;
  float* fs = fscale + b * N;
  __shared__ unsigned keyb[N];
  __shared__ int hist[256];
  __shared__ int sbuf[1024];
  __shared__ unsigned sh_prefix;
  __shared__ int sh_kneed;

  for (int i = tid; i < N; i += 1024) {
    float m = (mkin == nullptr) ? 1.0f : mkin[b * N + i];
    keyb[i] = fkey(sc[i], m);
  }
  __syncthreads();

  unsigned prefix = 0, hm = 0;
  int kneed = k;
  for (int shift = 24; shift >= 0; shift -= 8) {
    if (tid < 256) hist[tid] = 0;
    __syncthreads();
    for (int i = tid; i < N; i += 1024) {
      unsigned key = keyb[i];
      if ((key & hm) == prefix) atomicAdd(&hist[(key >> shift) & 255], 1);
    }
    __syncthreads();
    if (tid < 256) sbuf[tid] = hist[tid];
    __syncthreads();
    for (int off = 1; off < 256; off <<= 1) {
      int v = (tid < 256 && tid + off < 256) ? sbuf[tid + off] : 0;
      __syncthreads();
      if (tid < 256) sbuf[tid] += v;
      __syncthreads();
    }
    if (tid < 256) {
      int ge = sbuf[tid];
      int gt = (tid < 255) ? sbuf[tid + 1] : 0;
      if (ge >= kneed && gt < kneed) {
        sh_prefix = prefix | ((unsigned)tid << shift);
        sh_kneed = kneed - gt;
      }
    }
    __syncthreads();
    prefix = sh_prefix;
    kneed = sh_kneed;
    hm |= (0xFFu << shift);
    __syncthreads();
  }

  unsigned T = prefix;
  int base = tid * 8;
  unsigned keys[8];
  int eqf[8];
  int cnt = 0;
#pragma unroll
  for (int q = 0; q < 8; ++q) {
    keys[q] = keyb[base + q];
    eqf[q] = (keys[q] == T) ? 1 : 0;
    cnt += eqf[q];
  }
  sbuf[tid] = cnt; __syncthreads();
  for (int off = 1; off < 1024; off <<= 1) {
    int x = (tid >= off) ? sbuf[tid - off] : 0;
    __syncthreads();
    sbuf[tid] += x;
    __syncthreads();
  }
  int ex = sbuf[tid] - cnt;
#pragma unroll
  for (int q = 0; q < 8; ++q) {
    bool sel = (keys[q] > T) || (eqf[q] && (ex < kneed));
    ex += eqf[q];
    mk[base + q] = sel ? 1.0f : 0.0f;
    fs[base + q] = sel ? tanhf(sc[base + q]) : 0.0f;
  }
}

// ---------------------------------------------------------------------------
// readout partials (bf16 h) + head MLP + log_softmax
// ---------------------------------------------------------------------------
__global__ __launch_bounds__(256) void readout(const unsigned short* __restrict__ h,
                                               float* __restrict__ part) {
  int b = blockIdx.x, c = blockIdx.y;
  int tid = threadIdx.x;
  int f = tid & 127, half = tid >> 7;
  float acc = 0.0f;
  for (int n = c * 256 + half; n < (c + 1) * 256; n += 2)
    acc += bf2f(h[((size_t)b * N + n) * 128 + f]);
  __shared__ float red[256];
  red[tid] = acc; __syncthreads();
  if (half == 0) part[((size_t)b * 32 + c) * 128 + f] = red[f] + red[f + 128];
}

__global__ __launch_bounds__(128) void head(const float* __restrict__ part,
                                            const float* __restrict__ l1w,
                                            const float* __restrict__ l1b,
                                            const float* __restrict__ l2w,
                                            const float* __restrict__ l2b,
                                            float* __restrict__ out) {
  int b = blockIdx.x, f = threadIdx.x;
  float g = 0.0f;
  for (int c = 0; c < 32; ++c) g += part[((size_t)b * 32 + c) * 128 + f];
  g *= (1.0f / (float)K2);
  __shared__ float gs[128], hh[128], lg[10];
  gs[f] = g; __syncthreads();
  float a = l1b[f];
  for (int kk = 0; kk < 128; ++kk) a += gs[kk] * l1w[kk * 128 + f];
  hh[f] = fmaxf(a, 0.0f); __syncthreads();
  if (f < 10) {
    float l = l2b[f];
    for (int j = 0; j < 128; ++j) l += hh[j] * l2w[j * 10 + f];
    lg[f] = l;
  }
  __syncthreads();
  if (f == 0) {
    float m = lg[0];
    for (int c = 1; c < 10; ++c) m = fmaxf(m, lg[c]);
    float s = 0.0f;
    for (int c = 0; c < 10; ++c) s += expf(lg[c] - m);
    float lse = m + logf(s);
    for (int c = 0; c < 10; ++c) out[b * 10 + c] = lg[c] - lse;
  }
}

// ---------------------------------------------------------------------------
extern "C" void kernel_launch(void* const* d_in, const int* in_sizes, int n_in,
                              void* d_out, int out_size, void* d_ws, size_t ws_size,
                              hipStream_t stream) {
  (void)in_sizes; (void)n_in; (void)out_size; (void)ws_size;
  const float* x       = (const float*)d_in[0];
  const int*   ei      = (const int*)d_in[1];
  const float* W1      = (const float*)d_in[2];
  const float* b1      = (const float*)d_in[3];
  const float* p1_wrel = (const float*)d_in[4];
  const float* p1_wroot= (const float*)d_in[5];
  const float* p1_b    = (const float*)d_in[6];
  const float* W2      = (const float*)d_in[7];
  const float* b2      = (const float*)d_in[8];
  const float* p2_wrel = (const float*)d_in[9];
  const float* p2_wroot= (const float*)d_in[10];
  const float* p2_b    = (const float*)d_in[11];
  const float* W3      = (const float*)d_in[12];
  const float* b3      = (const float*)d_in[13];
  const float* l1w     = (const float*)d_in[14];
  const float* l1b     = (const float*)d_in[15];
  const float* l2w     = (const float*)d_in[16];
  const float* l2b     = (const float*)d_in[17];
  float* out = (float*)d_out;

  char* p = (char*)d_ws;
  auto alloc = [&](size_t bytes) {
    char* r = p;
    p += ((bytes + 255) & ~(size_t)255);
    return r;
  };
  unsigned short* h   = (unsigned short*)alloc((size_t)B * N * H * 2);   // bf16
  unsigned short* tmp = (unsigned short*)alloc((size_t)B * N * H * 2);   // bf16
  int*      offs   = (int*)alloc((size_t)B * (N + 1) * 4);
  int*      csr    = (int*)alloc((size_t)B * E * 4);
  unsigned* pbuf   = (unsigned*)alloc((size_t)B * E * 4);
  int*      bchist = (int*)alloc((size_t)B * CHUNKS * NBK * 4);
  int*      cursor = (int*)alloc((size_t)B * CHUNKS * NBK * 4);
  int*      bbase  = (int*)alloc((size_t)B * (NBK + 1) * 4);
  int*      ecnt   = (int*)alloc((size_t)B * N * 4);
  float* dinv   = (float*)alloc((size_t)B * N * 4);
  float* mask   = (float*)alloc((size_t)B * N * 4);
  float* rr     = (float*)alloc((size_t)B * N * 4);
  float* tt     = (float*)alloc((size_t)B * N * 4);
  float* score  = (float*)alloc((size_t)B * N * 4);
  float* fscale = (float*)alloc((size_t)B * N * 4);
  float* part   = (float*)alloc((size_t)B * 32 * H * 4);
  unsigned short* Wts = (unsigned short*)alloc(3 * 128 * 128 * 2);

  // CSR build (streaming counting sort) + weight prep
  hist_pass<<<B * CHUNKS, 256, 0, stream>>>(ei, bchist);
  bucket_scan<<<B, 256, 0, stream>>>(bchist, cursor, bbase);
  bin_scatter<<<B * CHUNKS, 256, 0, stream>>>(ei, cursor, pbuf);
  final_scatter<<<B * NBK, 256, 0, stream>>>(pbuf, bbase, csr, offs, dinv);
  prep_wt3<<<3, 256, 0, stream>>>(W1, W2, W3, Wts);

  // ---- layer 1 + pool 1 (all nodes live)
  gemm_mfma<false><<<(B * N) / 128, 256, 0, stream>>>(x, Wts, tmp, nullptr);
  gcn_agg6<true><<<B * N / 4, 256, 0, stream>>>((const unsigned*)tmp, dinv, offs,
                                                nullptr, csr, b1, (unsigned*)h,
                                                p1_wrel, p1_wroot, rr, tt);
  score_agg<<<B * N / 16, 256, 0, stream>>>(rr, tt, p1_b, nullptr, offs, nullptr,
                                            csr, score);
  topk_kernel<<<B, 1024, 0, stream>>>(score, nullptr, mask, fscale, K1);
  compact_pool<<<B * N / 4, 256, 0, stream>>>(mask, offs, nullptr, csr, ecnt, dinv);

  // ---- layer 2 + pool 2
  gemm_mfma<true><<<(B * N) / 128, 256, 0, stream>>>(h, Wts + 128 * 128, tmp, fscale);
  gcn_agg6<false><<<B * N / 4, 256, 0, stream>>>((const unsigned*)tmp, dinv, offs,
                                                 ecnt, csr, b2, (unsigned*)h,
                                                 p2_wrel, p2_wroot, rr, tt);
  score_agg<<<B * N / 16, 256, 0, stream>>>(rr, tt, p2_b, dinv, offs, ecnt, csr, score);
  topk_kernel<<<B, 1024, 0, stream>>>(score, mask, mask, fscale, K2);
  compact_pool<<<B * N / 4, 256, 0, stream>>>(mask, offs, ecnt, csr, ecnt, dinv);

  // ---- layer 3
  gemm_mfma<true><<<(B * N) / 128, 256, 0, stream>>>(h, Wts + 2 * 128 * 128, tmp, fscale);
  gcn_agg6<false><<<B * N / 4, 256, 0, stream>>>((const unsigned*)tmp, dinv, offs,
                                                 ecnt, csr, b3, (unsigned*)h,
                                                 nullptr, nullptr, nullptr, nullptr);

  // ---- readout + head
  readout<<<dim3(B, 32), 256, 0, stream>>>(h, part);
  head<<<B, 128, 0, stream>>>(part, l1w, l1b, l2w, l2b, out);
}

// Round 9
// 414.960 us; speedup vs baseline: 1.2942x; 1.0847x over previous
//
#include <hip/hip_runtime.h>
#include <hip/hip_bf16.h>
#include <math.h>

// Problem constants
constexpr int B  = 16;
constexpr int N  = 8192;     // 2^13
constexpr int E  = 131072;   // 2^17
constexpr int H  = 128;
constexpr int K1 = 4096;
constexpr int K2 = 2048;

constexpr int CHUNKS = 16;         // edge chunks per graph (8192 edges each)
constexpr int NBK    = 16;         // dst buckets (dst>>9, 512 nodes each)
constexpr int FCAP   = 12288;      // final_scatter LDS capacity

typedef __attribute__((ext_vector_type(8))) short short8;
typedef __attribute__((ext_vector_type(4))) float floatx4;

__device__ __forceinline__ unsigned short f2bf(float f) {
  unsigned u = __float_as_uint(f);
  return (unsigned short)((u + 0x7FFFu + ((u >> 16) & 1u)) >> 16);  // RNE
}
__device__ __forceinline__ float bf2f(unsigned short s) {
  return __uint_as_float(((unsigned)s) << 16);
}
__device__ __forceinline__ int rdlane_i(int v, int l) {
  return __builtin_amdgcn_readlane(v, l);
}
__device__ __forceinline__ float rdlane_f(float v, int l) {
  return __uint_as_float((unsigned)__builtin_amdgcn_readlane((int)__float_as_uint(v), l));
}
__device__ __forceinline__ unsigned cvt_pk_bf16(float a, float b) {
  unsigned r;
  asm("v_cvt_pk_bf16_f32 %0, %1, %2" : "=v"(r) : "v"(a), "v"(b));
  return r;
}

// ---------------------------------------------------------------------------
// CSR build (streaming counting sort) — unchanged from R5
// ---------------------------------------------------------------------------
__global__ __launch_bounds__(256) void hist_pass(const int* __restrict__ ei,
                                                 int* __restrict__ bchist) {
  int blk = blockIdx.x;                 // B*CHUNKS = 256
  int b = blk >> 4, c = blk & 15;
  __shared__ int h16[NBK];
  if (threadIdx.x < NBK) h16[threadIdx.x] = 0;
  __syncthreads();
  const int* dstp = ei + (size_t)b * 2 * E + E + c * 8192;
  for (int i = 0; i < 32; ++i) {
    int dst = dstp[i * 256 + threadIdx.x];
    atomicAdd(&h16[dst >> 9], 1);
  }
  __syncthreads();
  if (threadIdx.x < NBK) bchist[(blk << 4) + threadIdx.x] = h16[threadIdx.x];
}

__global__ __launch_bounds__(256) void bucket_scan(const int* __restrict__ bchist,
                                                   int* __restrict__ cursor,
                                                   int* __restrict__ bbase) {
  int b = blockIdx.x;                   // B = 16
  int tid = threadIdx.x;                // 256 = CHUNKS*NBK
  int c = tid >> 4, k = tid & 15;
  __shared__ int arr[CHUNKS][NBK];
  __shared__ int base[NBK + 1];
  arr[c][k] = bchist[((b * CHUNKS + c) << 4) + k];
  __syncthreads();
  if (tid == 0) {
    int run = 0;
    for (int kk = 0; kk < NBK; ++kk) {
      base[kk] = run;
      int t = 0;
      for (int cc = 0; cc < CHUNKS; ++cc) t += arr[cc][kk];
      run += t;
    }
    base[NBK] = run;
  }
  __syncthreads();
  int pre = 0;
  for (int cc = 0; cc < c; ++cc) pre += arr[cc][k];
  cursor[((b * CHUNKS + c) << 4) + k] = base[k] + pre;
  if (tid < NBK + 1) bbase[b * (NBK + 1) + tid] = base[tid];
}

__global__ __launch_bounds__(256) void bin_scatter(const int* __restrict__ ei,
                                                   const int* __restrict__ cursor,
                                                   unsigned* __restrict__ pbuf) {
  int blk = blockIdx.x;
  int b = blk >> 4, c = blk & 15;
  __shared__ int gcur[NBK], lcnt[NBK], lfill[NBK];
  __shared__ int lbase[NBK + 1];
  __shared__ unsigned sbuf[2048];
  int tid = threadIdx.x;
  if (tid < NBK) gcur[tid] = cursor[(blk << 4) + tid];
  const int* srcp = ei + (size_t)b * 2 * E + c * 8192;
  const int* dstp = srcp + E;
  unsigned* pb = pbuf + (size_t)b * E;

  for (int sc = 0; sc < 4; ++sc) {
    if (tid < NBK) { lcnt[tid] = 0; lfill[tid] = 0; }
    __syncthreads();
    int s8[8], d8[8];
#pragma unroll
    for (int q = 0; q < 8; ++q) {
      int i = sc * 2048 + q * 256 + tid;
      s8[q] = srcp[i]; d8[q] = dstp[i];
      atomicAdd(&lcnt[d8[q] >> 9], 1);
    }
    __syncthreads();
    if (tid == 0) {
      int run = 0;
      for (int k = 0; k < NBK; ++k) { lbase[k] = run; run += lcnt[k]; }
      lbase[NBK] = run;
    }
    __syncthreads();
#pragma unroll
    for (int q = 0; q < 8; ++q) {
      int k = d8[q] >> 9;
      int idx = atomicAdd(&lfill[k], 1);
      sbuf[lbase[k] + idx] = ((unsigned)(d8[q] & 511) << 13) | (unsigned)s8[q];
    }
    __syncthreads();
    for (int i = tid; i < 2048; i += 256) {
      int k = 0;
      while (lbase[k + 1] <= i) ++k;
      pb[gcur[k] + (i - lbase[k])] = sbuf[i];
    }
    __syncthreads();
    if (tid < NBK) gcur[tid] += lcnt[tid];
    __syncthreads();
  }
}

__global__ __launch_bounds__(256) void final_scatter(const unsigned* __restrict__ pbuf,
                                                     const int* __restrict__ bbase,
                                                     int* __restrict__ csr,
                                                     int* __restrict__ offs,
                                                     float* __restrict__ dinv1) {
  int blk = blockIdx.x;
  int b = blk >> 4, k = blk & 15;
  __shared__ int ncnt[512], nbase[512], nfill[512];
  __shared__ int sred[256];
  __shared__ unsigned sbuf[FCAP];
  int tid = threadIdx.x;
  int gbase = bbase[b * (NBK + 1) + k];
  int gend  = bbase[b * (NBK + 1) + k + 1];
  int cnt = gend - gbase;
  const unsigned* pb = pbuf + (size_t)b * E + gbase;

  for (int i = tid; i < 512; i += 256) { ncnt[i] = 0; nfill[i] = 0; }
  __syncthreads();
  for (int i = tid; i < cnt; i += 256) atomicAdd(&ncnt[pb[i] >> 13], 1);
  __syncthreads();
  int v0 = ncnt[2 * tid], v1 = ncnt[2 * tid + 1];
  int s = v0 + v1;
  sred[tid] = s;
  __syncthreads();
  for (int off = 1; off < 256; off <<= 1) {
    int x = (tid >= off) ? sred[tid - off] : 0;
    __syncthreads();
    sred[tid] += x;
    __syncthreads();
  }
  int ex = sred[tid] - s;
  nbase[2 * tid] = ex;
  nbase[2 * tid + 1] = ex + v0;
  __syncthreads();
  for (int i = tid; i < 512; i += 256) {
    int node = k * 512 + i;
    offs[b * (N + 1) + node] = gbase + nbase[i];
    dinv1[b * N + node] = rsqrtf((float)ncnt[i] + 1.0f);
  }
  if (k == 15 && tid == 0) offs[b * (N + 1) + N] = E;
  __syncthreads();
  for (int i = tid; i < cnt; i += 256) {
    unsigned pk = pb[i];
    int node = pk >> 13;
    int idx = atomicAdd(&nfill[node], 1);
    sbuf[nbase[node] + idx] = pk & 8191u;
  }
  __syncthreads();
  int* co = csr + (size_t)b * E + gbase;
  for (int i = tid; i < cnt; i += 256) co[i] = (int)sbuf[i];
}

// ---------------------------------------------------------------------------
// W[128][128] fp32 -> Wt[128][128] bf16 transposed, 3 weights in one launch
// ---------------------------------------------------------------------------
__global__ __launch_bounds__(256) void prep_wt3(const float* __restrict__ W1,
                                                const float* __restrict__ W2,
                                                const float* __restrict__ W3,
                                                unsigned short* __restrict__ Wt) {
  const float* W = (blockIdx.x == 0) ? W1 : (blockIdx.x == 1) ? W2 : W3;
  unsigned short* o = Wt + blockIdx.x * 128 * 128;
  for (int i = threadIdx.x; i < 128 * 128; i += 256) {
    int k = i >> 7, n = i & 127;
    o[n * 128 + k] = f2bf(W[i]);
  }
}

// ---------------------------------------------------------------------------
// MFMA GEMM: C[M,128](bf16) = diag(fscale*dscale) @ A[M,128] @ W.
// dscale = dinv of the CURRENT layer (pre-scales rows so the agg's edge sum
// needs no per-src weight at all). Wt staged in LDS with 16B-slot XOR swizzle
// (2-way bank conflict = free).
// ---------------------------------------------------------------------------
template <bool ABF16>
__global__ __launch_bounds__(256) void gemm_mfma(const void* __restrict__ Ap,
                                                 const unsigned short* __restrict__ Wt,
                                                 unsigned short* __restrict__ Cb,
                                                 const float* __restrict__ fscale,
                                                 const float* __restrict__ dscale) {
  __shared__ unsigned short Wsh[128 * 128];   // [col][k], slot s at row r -> s^(r&15)
  int tid  = threadIdx.x;
  int lane = tid & 63;
  int l15  = lane & 15, lg = lane >> 4;
  size_t rowbase = (size_t)blockIdx.x * 128 + (tid >> 6) * 32;

  // stage Wt: 2048 16B slots, 8 per thread
#pragma unroll
  for (int i = 0; i < 8; ++i) {
    int idx = tid + i * 256;
    int row = idx >> 4, s = idx & 15;
    short8 v = *(const short8*)(Wt + idx * 8);
    *(short8*)(Wsh + row * 128 + (s ^ (row & 15)) * 8) = v;
  }

  short8 afrag[2][4];
#pragma unroll
  for (int rg = 0; rg < 2; ++rg) {
    size_t row = rowbase + rg * 16 + l15;
#pragma unroll
    for (int c = 0; c < 4; ++c) {
      int k0 = c * 32 + lg * 8;
      if (ABF16) {
        afrag[rg][c] = *(const short8*)((const unsigned short*)Ap + row * 128 + k0);
      } else {
        const float* p = (const float*)Ap + row * 128 + k0;
        float4 v0 = *(const float4*)p;
        float4 v1 = *(const float4*)(p + 4);
        short8 a;
        a[0] = (short)f2bf(v0.x); a[1] = (short)f2bf(v0.y);
        a[2] = (short)f2bf(v0.z); a[3] = (short)f2bf(v0.w);
        a[4] = (short)f2bf(v1.x); a[5] = (short)f2bf(v1.y);
        a[6] = (short)f2bf(v1.z); a[7] = (short)f2bf(v1.w);
        afrag[rg][c] = a;
      }
    }
  }

  float fsr0[4] = {1.f, 1.f, 1.f, 1.f}, fsr1[4] = {1.f, 1.f, 1.f, 1.f};
  if (fscale != nullptr) {
    float4 t0 = *(const float4*)(fscale + rowbase + lg * 4);
    float4 t1 = *(const float4*)(fscale + rowbase + 16 + lg * 4);
    fsr0[0] = t0.x; fsr0[1] = t0.y; fsr0[2] = t0.z; fsr0[3] = t0.w;
    fsr1[0] = t1.x; fsr1[1] = t1.y; fsr1[2] = t1.z; fsr1[3] = t1.w;
  }
  if (dscale != nullptr) {
    float4 t0 = *(const float4*)(dscale + rowbase + lg * 4);
    float4 t1 = *(const float4*)(dscale + rowbase + 16 + lg * 4);
    fsr0[0] *= t0.x; fsr0[1] *= t0.y; fsr0[2] *= t0.z; fsr0[3] *= t0.w;
    fsr1[0] *= t1.x; fsr1[1] *= t1.y; fsr1[2] *= t1.z; fsr1[3] *= t1.w;
  }

  __syncthreads();

#pragma unroll
  for (int t = 0; t < 8; ++t) {
    int col = t * 16 + l15;
    short8 bfrag[4];
#pragma unroll
    for (int c = 0; c < 4; ++c)
      bfrag[c] = *(const short8*)(Wsh + col * 128 + ((c * 4 + lg) ^ (col & 15)) * 8);

    floatx4 acc0 = {0.f, 0.f, 0.f, 0.f};
    floatx4 acc1 = {0.f, 0.f, 0.f, 0.f};
#pragma unroll
    for (int c = 0; c < 4; ++c) {
      acc0 = __builtin_amdgcn_mfma_f32_16x16x32_bf16(afrag[0][c], bfrag[c], acc0, 0, 0, 0);
      acc1 = __builtin_amdgcn_mfma_f32_16x16x32_bf16(afrag[1][c], bfrag[c], acc1, 0, 0, 0);
    }
#pragma unroll
    for (int r = 0; r < 4; ++r) {
      size_t row0 = rowbase + lg * 4 + r;
      size_t row1 = rowbase + 16 + lg * 4 + r;
      Cb[row0 * 128 + col] = f2bf(acc0[r] * fsr0[r]);
      Cb[row1 * 128 + col] = f2bf(acc1[r] * fsr1[r]);
    }
  }
}

// ---------------------------------------------------------------------------
// GCN aggregation v7: R8's proven structure, but tmp rows are PRE-SCALED by
// dinv (folded into the GEMM epilogue), so the edge loop needs NO per-src
// weight: no dvb gather (kills the 2nd serial L2 hop per 64-edge block),
// one readlane per edge instead of two, ADD instead of FMA.
// ---------------------------------------------------------------------------
template <bool ALL_LIVE>
__global__ __launch_bounds__(256) void gcn_agg7(
    const unsigned* __restrict__ tmp, const float* __restrict__ dinv,
    const int* __restrict__ offs, const int* __restrict__ ecnt,
    const int* __restrict__ csr, const float* __restrict__ bias,
    unsigned* __restrict__ hout,
    const float* __restrict__ wrel, const float* __restrict__ wroot,
    float* __restrict__ rr, float* __restrict__ tt) {
  int blk = blockIdx.x;
  int xcd = blk & 7;
  int j   = blk >> 3;                      // 0..4095
  int b   = xcd * 2 + (j >> 11);           // 2 graphs per XCD
  int n   = (j & 2047) * 4 + (threadIdx.x >> 6);
  int wid = b * N + n;
  int lane = threadIdx.x & 63;

  float dv = rdlane_f(dinv[wid], 0);       // wave-uniform -> SGPR
  unsigned* hrow = hout + (size_t)wid * 64;

  if (!ALL_LIVE && dv <= 0.0f) {           // dead destination: zeros only
    hrow[lane] = 0u;
    if (rr != nullptr && lane == 0) { rr[wid] = 0.0f; tt[wid] = 0.0f; }
    return;
  }

  const unsigned* tmpb = tmp + (((size_t)b << 13) << 6);
  const int*   cs  = csr + (size_t)b * E;

  float2 accA, accB;
  {
    unsigned u = tmpb[((unsigned)n << 6) + lane];   // self term (pre-scaled)
    accA.x = __uint_as_float(u << 16);
    accA.y = __uint_as_float(u & 0xFFFF0000u);
    accB.x = 0.0f; accB.y = 0.0f;
  }

  int nbase = b * (N + 1) + n;
  int o0 = __builtin_amdgcn_readfirstlane(offs[nbase]);
  int d;
  if (ALL_LIVE) d = __builtin_amdgcn_readfirstlane(offs[nbase + 1]) - o0;
  else          d = __builtin_amdgcn_readfirstlane(ecnt[wid]);

  for (int base = 0; base < d; base += 64) {
    int nv = d - base; if (nv > 64) nv = 64;
    int sl = (lane < nv) ? cs[o0 + base + lane] : -1;

    for (int i0 = 0; i0 < nv; i0 += 16) {
      unsigned uu[16]; int sq[16];
#pragma unroll
      for (int q = 0; q < 16; ++q) {
        sq[q] = rdlane_i(sl, i0 + q);                // SGPR; -1 for pads
        const unsigned* rowp = tmpb + ((unsigned)(sq[q] < 0 ? 0 : sq[q]) << 6);
        uu[q] = (sq[q] < 0) ? 0u : rowp[lane];       // wave-uniform cond
      }
#pragma unroll
      for (int q = 0; q < 16; ++q) {
        float lo = __uint_as_float(uu[q] << 16);
        float hi = __uint_as_float(uu[q] & 0xFFFF0000u);
        if (q & 1) { accB.x += lo; accB.y += hi; }
        else       { accA.x += lo; accA.y += hi; }
      }
    }
  }

  float2 acc = {accA.x + accB.x, accA.y + accB.y};
  const float2 bb = *(const float2*)(bias + lane * 2);
  float2 outv;
  outv.x = fmaxf(dv * acc.x + bb.x, 0.0f);
  outv.y = fmaxf(dv * acc.y + bb.y, 0.0f);
  hrow[lane] = cvt_pk_bf16(outv.x, outv.y);

  if (rr != nullptr) {                        // fused pool dots r=h.wrel t=h.wroot
    const float2 wr = *(const float2*)(wrel + lane * 2);
    const float2 wo = *(const float2*)(wroot + lane * 2);
    float pr = outv.x * wr.x + outv.y * wr.y;
    float pt = outv.x * wo.x + outv.y * wo.y;
#pragma unroll
    for (int dd = 32; dd > 0; dd >>= 1) {
      pr += __shfl_down(pr, dd);
      pt += __shfl_down(pt, dd);
    }
    if (lane == 0) { rr[wid] = pr; tt[wid] = pt; }
  }
}

// ---------------------------------------------------------------------------
// compact_pool: ONE fused pass per pool (unchanged from R8).
// ---------------------------------------------------------------------------
__global__ __launch_bounds__(256) void compact_pool(
    const float* __restrict__ mask, const int* __restrict__ offs,
    const int* __restrict__ ecnt_in, int* __restrict__ csr,
    int* __restrict__ ecnt_out, float* __restrict__ dinv_out) {
  int wid = blockIdx.x * 4 + (threadIdx.x >> 6);
  int lane = threadIdx.x & 63;
  int b = wid >> 13, n = wid & (N - 1);
  float m = rdlane_f(mask[wid], 0);
  if (m <= 0.0f) {
    if (lane == 0) { ecnt_out[wid] = 0; dinv_out[wid] = 0.0f; }
    return;
  }
  int nb = b * (N + 1) + n;
  int o0 = __builtin_amdgcn_readfirstlane(offs[nb]);
  int din = (ecnt_in != nullptr)
                ? __builtin_amdgcn_readfirstlane(ecnt_in[wid])
                : __builtin_amdgcn_readfirstlane(offs[nb + 1]) - o0;
  int* cs = csr + (size_t)b * E;
  const float* mb = mask + b * N;
  int wpos = o0;
  for (int base = 0; base < din; base += 64) {
    int nv = din - base; if (nv > 64) nv = 64;
    int s = (lane < nv) ? cs[o0 + base + lane] : 0;
    bool alive = (lane < nv) && (mb[s] > 0.0f);
    unsigned long long bal = __ballot(alive);
    int idx = __popcll(bal & ((1ull << lane) - 1ull));
    if (alive) cs[wpos + idx] = s;
    wpos += __popcll(bal);
  }
  if (lane == 0) {
    int total = wpos - o0;
    ecnt_out[wid] = total;
    dinv_out[wid] = rsqrtf((float)total + 1.0f);
  }
}

// ---------------------------------------------------------------------------
// pool score: score[n] = live*(sum_in r[src] + t[n] + b); 16 lanes/node.
// ---------------------------------------------------------------------------
__global__ __launch_bounds__(256) void score_agg(const float* __restrict__ r,
                                                 const float* __restrict__ t,
                                                 const float* __restrict__ pb,
                                                 const float* __restrict__ livep,
                                                 const int* __restrict__ offs,
                                                 const int* __restrict__ ecnt,
                                                 const int* __restrict__ csr,
                                                 float* __restrict__ score) {
  int grp = threadIdx.x >> 4;
  int gl  = threadIdx.x & 15;
  int nid = blockIdx.x * 16 + grp;
  int b = nid >> 13, n = nid & (N - 1);
  bool live = (livep == nullptr) || (livep[nid] > 0.0f);
  float s = 0.0f;
  if (live) {
    int o0 = offs[b * (N + 1) + n];
    int d = (ecnt != nullptr) ? ecnt[nid] : offs[b * (N + 1) + n + 1] - o0;
    const int* cs = csr + (size_t)b * E;
    const float* rb = r + b * N;
    for (int base = 0; base < d; base += 16)
      if (base + gl < d) s += rb[cs[o0 + base + gl]];
  }
#pragma unroll
  for (int dd = 8; dd > 0; dd >>= 1) s += __shfl_xor(s, dd, 16);
  if (gl == 0) score[nid] = live ? (s + t[nid] + pb[0]) : 0.0f;
}

// ---------------------------------------------------------------------------
// top-k via radix select (unchanged)
// ---------------------------------------------------------------------------
__device__ __forceinline__ unsigned fkey(float s, float m) {
  if (m <= 0.0f) return 0u;
  unsigned u = __float_as_uint(s);
  return (u & 0x80000000u) ? ~u : (u | 0x80000000u);
}

__global__ __launch_bounds__(1024) void topk_kernel(const float* __restrict__ score,
                                                    const float* __restrict__ mkin,
                                                    float* __restrict__ mkout,
                                                    float* __restrict__ fscale,
                                                    int k) {
  int b = blockIdx.x, tid = threadIdx.x;
  const float* sc = score + b * N;
  float* mk = mkout + b * N;
  float* fs = fscale + b * N;
  __shared__ unsigned keyb[N];
  __shared__ int hist[256];
  __shared__ int sbuf[1024];
  __shared__ unsigned sh_prefix;
  __shared__ int sh_kneed;

  for (int i = tid; i < N; i += 1024) {
    float m = (mkin == nullptr) ? 1.0f : mkin[b * N + i];
    keyb[i] = fkey(sc[i], m);
  }
  __syncthreads();

  unsigned prefix = 0, hm = 0;
  int kneed = k;
  for (int shift = 24; shift >= 0; shift -= 8) {
    if (tid < 256) hist[tid] = 0;
    __syncthreads();
    for (int i = tid; i < N; i += 1024) {
      unsigned key = keyb[i];
      if ((key & hm) == prefix) atomicAdd(&hist[(key >> shift) & 255], 1);
    }
    __syncthreads();
    if (tid < 256) sbuf[tid] = hist[tid];
    __syncthreads();
    for (int off = 1; off < 256; off <<= 1) {
      int v = (tid < 256 && tid + off < 256) ? sbuf[tid + off] : 0;
      __syncthreads();
      if (tid < 256) sbuf[tid] += v;
      __syncthreads();
    }
    if (tid < 256) {
      int ge = sbuf[tid];
      int gt = (tid < 255) ? sbuf[tid + 1] : 0;
      if (ge >= kneed && gt < kneed) {
        sh_prefix = prefix | ((unsigned)tid << shift);
        sh_kneed = kneed - gt;
      }
    }
    __syncthreads();
    prefix = sh_prefix;
    kneed = sh_kneed;
    hm |= (0xFFu << shift);
    __syncthreads();
  }

  unsigned T = prefix;
  int base = tid * 8;
  unsigned keys[8];
  int eqf[8];
  int cnt = 0;
#pragma unroll
  for (int q = 0; q < 8; ++q) {
    keys[q] = keyb[base + q];
    eqf[q] = (keys[q] == T) ? 1 : 0;
    cnt += eqf[q];
  }
  sbuf[tid] = cnt; __syncthreads();
  for (int off = 1; off < 1024; off <<= 1) {
    int x = (tid >= off) ? sbuf[tid - off] : 0;
    __syncthreads();
    sbuf[tid] += x;
    __syncthreads();
  }
  int ex = sbuf[tid] - cnt;
#pragma unroll
  for (int q = 0; q < 8; ++q) {
    bool sel = (keys[q] > T) || (eqf[q] && (ex < kneed));
    ex += eqf[q];
    mk[base + q] = sel ? 1.0f : 0.0f;
    fs[base + q] = sel ? tanhf(sc[base + q]) : 0.0f;
  }
}

// ---------------------------------------------------------------------------
// readout partials (bf16 h) + head MLP + log_softmax
// ---------------------------------------------------------------------------
__global__ __launch_bounds__(256) void readout(const unsigned short* __restrict__ h,
                                               float* __restrict__ part) {
  int b = blockIdx.x, c = blockIdx.y;
  int tid = threadIdx.x;
  int f = tid & 127, half = tid >> 7;
  float acc = 0.0f;
  for (int n = c * 256 + half; n < (c + 1) * 256; n += 2)
    acc += bf2f(h[((size_t)b * N + n) * 128 + f]);
  __shared__ float red[256];
  red[tid] = acc; __syncthreads();
  if (half == 0) part[((size_t)b * 32 + c) * 128 + f] = red[f] + red[f + 128];
}

__global__ __launch_bounds__(128) void head(const float* __restrict__ part,
                                            const float* __restrict__ l1w,
                                            const float* __restrict__ l1b,
                                            const float* __restrict__ l2w,
                                            const float* __restrict__ l2b,
                                            float* __restrict__ out) {
  int b = blockIdx.x, f = threadIdx.x;
  float g = 0.0f;
  for (int c = 0; c < 32; ++c) g += part[((size_t)b * 32 + c) * 128 + f];
  g *= (1.0f / (float)K2);
  __shared__ float gs[128], hh[128], lg[10];
  gs[f] = g; __syncthreads();
  float a = l1b[f];
  for (int kk = 0; kk < 128; ++kk) a += gs[kk] * l1w[kk * 128 + f];
  hh[f] = fmaxf(a, 0.0f); __syncthreads();
  if (f < 10) {
    float l = l2b[f];
    for (int j = 0; j < 128; ++j) l += hh[j] * l2w[j * 10 + f];
    lg[f] = l;
  }
  __syncthreads();
  if (f == 0) {
    float m = lg[0];
    for (int c = 1; c < 10; ++c) m = fmaxf(m, lg[c]);
    float s = 0.0f;
    for (int c = 0; c < 10; ++c) s += expf(lg[c] - m);
    float lse = m + logf(s);
    for (int c = 0; c < 10; ++c) out[b * 10 + c] = lg[c] - lse;
  }
}

// ---------------------------------------------------------------------------
extern "C" void kernel_launch(void* const* d_in, const int* in_sizes, int n_in,
                              void* d_out, int out_size, void* d_ws, size_t ws_size,
                              hipStream_t stream) {
  (void)in_sizes; (void)n_in; (void)out_size; (void)ws_size;
  const float* x       = (const float*)d_in[0];
  const int*   ei      = (const int*)d_in[1];
  const float* W1      = (const float*)d_in[2];
  const float* b1      = (const float*)d_in[3];
  const float* p1_wrel = (const float*)d_in[4];
  const float* p1_wroot= (const float*)d_in[5];
  const float* p1_b    = (const float*)d_in[6];
  const float* W2      = (const float*)d_in[7];
  const float* b2      = (const float*)d_in[8];
  const float* p2_wrel = (const float*)d_in[9];
  const float* p2_wroot= (const float*)d_in[10];
  const float* p2_b    = (const float*)d_in[11];
  const float* W3      = (const float*)d_in[12];
  const float* b3      = (const float*)d_in[13];
  const float* l1w     = (const float*)d_in[14];
  const float* l1b     = (const float*)d_in[15];
  const float* l2w     = (const float*)d_in[16];
  const float* l2b     = (const float*)d_in[17];
  float* out = (float*)d_out;

  char* p = (char*)d_ws;
  auto alloc = [&](size_t bytes) {
    char* r = p;
    p += ((bytes + 255) & ~(size_t)255);
    return r;
  };
  unsigned short* h   = (unsigned short*)alloc((size_t)B * N * H * 2);   // bf16
  unsigned short* tmp = (unsigned short*)alloc((size_t)B * N * H * 2);   // bf16
  int*      offs   = (int*)alloc((size_t)B * (N + 1) * 4);
  int*      csr    = (int*)alloc((size_t)B * E * 4);
  unsigned* pbuf   = (unsigned*)alloc((size_t)B * E * 4);
  int*      bchist = (int*)alloc((size_t)B * CHUNKS * NBK * 4);
  int*      cursor = (int*)alloc((size_t)B * CHUNKS * NBK * 4);
  int*      bbase  = (int*)alloc((size_t)B * (NBK + 1) * 4);
  int*      ecnt   = (int*)alloc((size_t)B * N * 4);
  float* dinv   = (float*)alloc((size_t)B * N * 4);
  float* mask   = (float*)alloc((size_t)B * N * 4);
  float* rr     = (float*)alloc((size_t)B * N * 4);
  float* tt     = (float*)alloc((size_t)B * N * 4);
  float* score  = (float*)alloc((size_t)B * N * 4);
  float* fscale = (float*)alloc((size_t)B * N * 4);
  float* part   = (float*)alloc((size_t)B * 32 * H * 4);
  unsigned short* Wts = (unsigned short*)alloc(3 * 128 * 128 * 2);

  // CSR build (streaming counting sort) + weight prep
  hist_pass<<<B * CHUNKS, 256, 0, stream>>>(ei, bchist);
  bucket_scan<<<B, 256, 0, stream>>>(bchist, cursor, bbase);
  bin_scatter<<<B * CHUNKS, 256, 0, stream>>>(ei, cursor, pbuf);
  final_scatter<<<B * NBK, 256, 0, stream>>>(pbuf, bbase, csr, offs, dinv);
  prep_wt3<<<3, 256, 0, stream>>>(W1, W2, W3, Wts);

  // ---- layer 1 + pool 1 (all nodes live; dinv folded into GEMM epilogue)
  gemm_mfma<false><<<(B * N) / 128, 256, 0, stream>>>(x, Wts, tmp, nullptr, dinv);
  gcn_agg7<true><<<B * N / 4, 256, 0, stream>>>((const unsigned*)tmp, dinv, offs,
                                                nullptr, csr, b1, (unsigned*)h,
                                                p1_wrel, p1_wroot, rr, tt);
  score_agg<<<B * N / 16, 256, 0, stream>>>(rr, tt, p1_b, nullptr, offs, nullptr,
                                            csr, score);
  topk_kernel<<<B, 1024, 0, stream>>>(score, nullptr, mask, fscale, K1);
  compact_pool<<<B * N / 4, 256, 0, stream>>>(mask, offs, nullptr, csr, ecnt, dinv);

  // ---- layer 2 + pool 2
  gemm_mfma<true><<<(B * N) / 128, 256, 0, stream>>>(h, Wts + 128 * 128, tmp,
                                                     fscale, dinv);
  gcn_agg7<false><<<B * N / 4, 256, 0, stream>>>((const unsigned*)tmp, dinv, offs,
                                                 ecnt, csr, b2, (unsigned*)h,
                                                 p2_wrel, p2_wroot, rr, tt);
  score_agg<<<B * N / 16, 256, 0, stream>>>(rr, tt, p2_b, dinv, offs, ecnt, csr, score);
  topk_kernel<<<B, 1024, 0, stream>>>(score, mask, mask, fscale, K2);
  compact_pool<<<B * N / 4, 256, 0, stream>>>(mask, offs, ecnt, csr, ecnt, dinv);

  // ---- layer 3
  gemm_mfma<true><<<(B * N) / 128, 256, 0, stream>>>(h, Wts + 2 * 128 * 128, tmp,
                                                     fscale, dinv);
  gcn_agg7<false><<<B * N / 4, 256, 0, stream>>>((const unsigned*)tmp, dinv, offs,
                                                 ecnt, csr, b3, (unsigned*)h,
                                                 nullptr, nullptr, nullptr, nullptr);

  // ---- readout + head
  readout<<<dim3(B, 32), 256, 0, stream>>>(h, part);
  head<<<B, 128, 0, stream>>>(part, l1w, l1b, l2w, l2b, out);
}

// Round 10
// 392.440 us; speedup vs baseline: 1.3684x; 1.0574x over previous
//
#include <hip/hip_runtime.h>
#include <hip/hip_bf16.h>
#include <math.h>

// Problem constants
constexpr int B  = 16;
constexpr int N  = 8192;     // 2^13
constexpr int E  = 131072;   // 2^17
constexpr int H  = 128;
constexpr int K1 = 4096;
constexpr int K2 = 2048;

constexpr int CHUNKS = 16;         // edge chunks per graph (8192 edges each)
constexpr int NBK    = 16;         // dst buckets (dst>>9, 512 nodes each)
constexpr int FCAP   = 12288;      // final_scatter LDS capacity

typedef __attribute__((ext_vector_type(8))) short short8;
typedef __attribute__((ext_vector_type(4))) float floatx4;

__device__ __forceinline__ unsigned short f2bf(float f) {
  unsigned u = __float_as_uint(f);
  return (unsigned short)((u + 0x7FFFu + ((u >> 16) & 1u)) >> 16);  // RNE
}
__device__ __forceinline__ float bf2f(unsigned short s) {
  return __uint_as_float(((unsigned)s) << 16);
}
__device__ __forceinline__ int rdlane_i(int v, int l) {
  return __builtin_amdgcn_readlane(v, l);
}
__device__ __forceinline__ float rdlane_f(float v, int l) {
  return __uint_as_float((unsigned)__builtin_amdgcn_readlane((int)__float_as_uint(v), l));
}
__device__ __forceinline__ unsigned cvt_pk_bf16(float a, float b) {
  unsigned r;
  asm("v_cvt_pk_bf16_f32 %0, %1, %2" : "=v"(r) : "v"(a), "v"(b));
  return r;
}

// ---------------------------------------------------------------------------
// CSR build, pass 1: per-(graph,chunk) histogram over 16 dst-buckets.
// ---------------------------------------------------------------------------
__global__ __launch_bounds__(256) void hist_pass(const int* __restrict__ ei,
                                                 int* __restrict__ bchist) {
  int blk = blockIdx.x;                 // B*CHUNKS = 256
  int b = blk >> 4, c = blk & 15;
  __shared__ int h16[NBK];
  if (threadIdx.x < NBK) h16[threadIdx.x] = 0;
  __syncthreads();
  const int* dstp = ei + (size_t)b * 2 * E + E + c * 8192;
  for (int i = 0; i < 32; ++i) {
    int dst = dstp[i * 256 + threadIdx.x];
    atomicAdd(&h16[dst >> 9], 1);
  }
  __syncthreads();
  if (threadIdx.x < NBK) bchist[(blk << 4) + threadIdx.x] = h16[threadIdx.x];
}

// ---------------------------------------------------------------------------
// CSR build, pass 2 (+ fused weight prep in blocks 16..18)
// ---------------------------------------------------------------------------
__global__ __launch_bounds__(256) void bucket_scan(const int* __restrict__ bchist,
                                                   int* __restrict__ cursor,
                                                   int* __restrict__ bbase,
                                                   const float* __restrict__ W1,
                                                   const float* __restrict__ W2,
                                                   const float* __restrict__ W3,
                                                   unsigned short* __restrict__ Wt) {
  if (blockIdx.x >= 16) {               // weight prep (independent work)
    int w = blockIdx.x - 16;
    const float* W = (w == 0) ? W1 : (w == 1) ? W2 : W3;
    unsigned short* o = Wt + w * 128 * 128;
    for (int i = threadIdx.x; i < 128 * 128; i += 256) {
      int k = i >> 7, n = i & 127;
      o[n * 128 + k] = f2bf(W[i]);
    }
    return;
  }
  int b = blockIdx.x;
  int tid = threadIdx.x;                // 256 = CHUNKS*NBK
  int c = tid >> 4, k = tid & 15;
  __shared__ int arr[CHUNKS][NBK];
  __shared__ int base[NBK + 1];
  arr[c][k] = bchist[((b * CHUNKS + c) << 4) + k];
  __syncthreads();
  if (tid == 0) {
    int run = 0;
    for (int kk = 0; kk < NBK; ++kk) {
      base[kk] = run;
      int t = 0;
      for (int cc = 0; cc < CHUNKS; ++cc) t += arr[cc][kk];
      run += t;
    }
    base[NBK] = run;
  }
  __syncthreads();
  int pre = 0;
  for (int cc = 0; cc < c; ++cc) pre += arr[cc][k];
  cursor[((b * CHUNKS + c) << 4) + k] = base[k] + pre;
  if (tid < NBK + 1) bbase[b * (NBK + 1) + tid] = base[tid];
}

// ---------------------------------------------------------------------------
// CSR build, pass 3: bin by bucket. pk = k<<22 | (dst&511)<<13 | src, so the
// flush can recover the bucket without a serial lbase walk.
// ---------------------------------------------------------------------------
__global__ __launch_bounds__(256) void bin_scatter(const int* __restrict__ ei,
                                                   const int* __restrict__ cursor,
                                                   unsigned* __restrict__ pbuf) {
  int blk = blockIdx.x;
  int b = blk >> 4, c = blk & 15;
  __shared__ int gcur[NBK], lcnt[NBK], lfill[NBK];
  __shared__ int lbase[NBK + 1];
  __shared__ unsigned sbuf[2048];
  int tid = threadIdx.x;
  if (tid < NBK) gcur[tid] = cursor[(blk << 4) + tid];
  const int* srcp = ei + (size_t)b * 2 * E + c * 8192;
  const int* dstp = srcp + E;
  unsigned* pb = pbuf + (size_t)b * E;

  for (int sc = 0; sc < 4; ++sc) {
    if (tid < NBK) { lcnt[tid] = 0; lfill[tid] = 0; }
    __syncthreads();
    int s8[8], d8[8];
#pragma unroll
    for (int q = 0; q < 8; ++q) {
      int i = sc * 2048 + q * 256 + tid;
      s8[q] = srcp[i]; d8[q] = dstp[i];
      atomicAdd(&lcnt[d8[q] >> 9], 1);
    }
    __syncthreads();
    if (tid == 0) {
      int run = 0;
      for (int k = 0; k < NBK; ++k) { lbase[k] = run; run += lcnt[k]; }
      lbase[NBK] = run;
    }
    __syncthreads();
#pragma unroll
    for (int q = 0; q < 8; ++q) {
      int k = d8[q] >> 9;
      int idx = atomicAdd(&lfill[k], 1);
      sbuf[lbase[k] + idx] = ((unsigned)k << 22) |
                             ((unsigned)(d8[q] & 511) << 13) | (unsigned)s8[q];
    }
    __syncthreads();
    for (int i = tid; i < 2048; i += 256) {
      unsigned pk = sbuf[i];
      int k = (int)(pk >> 22);
      pb[gcur[k] + (i - lbase[k])] = pk;
    }
    __syncthreads();
    if (tid < NBK) gcur[tid] += lcnt[tid];
    __syncthreads();
  }
}

__global__ __launch_bounds__(256) void final_scatter(const unsigned* __restrict__ pbuf,
                                                     const int* __restrict__ bbase,
                                                     int* __restrict__ csr,
                                                     int* __restrict__ offs,
                                                     float* __restrict__ dinv1) {
  int blk = blockIdx.x;
  int b = blk >> 4, k = blk & 15;
  __shared__ int ncnt[512], nbase[512], nfill[512];
  __shared__ int sred[256];
  __shared__ unsigned sbuf[FCAP];
  int tid = threadIdx.x;
  int gbase = bbase[b * (NBK + 1) + k];
  int gend  = bbase[b * (NBK + 1) + k + 1];
  int cnt = gend - gbase;
  const unsigned* pb = pbuf + (size_t)b * E + gbase;

  for (int i = tid; i < 512; i += 256) { ncnt[i] = 0; nfill[i] = 0; }
  __syncthreads();
  for (int i = tid; i < cnt; i += 256) atomicAdd(&ncnt[(pb[i] >> 13) & 511], 1);
  __syncthreads();
  int v0 = ncnt[2 * tid], v1 = ncnt[2 * tid + 1];
  int s = v0 + v1;
  sred[tid] = s;
  __syncthreads();
  for (int off = 1; off < 256; off <<= 1) {
    int x = (tid >= off) ? sred[tid - off] : 0;
    __syncthreads();
    sred[tid] += x;
    __syncthreads();
  }
  int ex = sred[tid] - s;
  nbase[2 * tid] = ex;
  nbase[2 * tid + 1] = ex + v0;
  __syncthreads();
  for (int i = tid; i < 512; i += 256) {
    int node = k * 512 + i;
    offs[b * (N + 1) + node] = gbase + nbase[i];
    dinv1[b * N + node] = rsqrtf((float)ncnt[i] + 1.0f);
  }
  if (k == 15 && tid == 0) offs[b * (N + 1) + N] = E;
  __syncthreads();
  for (int i = tid; i < cnt; i += 256) {
    unsigned pk = pb[i];
    int node = (pk >> 13) & 511;
    int idx = atomicAdd(&nfill[node], 1);
    sbuf[nbase[node] + idx] = pk & 8191u;
  }
  __syncthreads();
  int* co = csr + (size_t)b * E + gbase;
  for (int i = tid; i < cnt; i += 256) co[i] = (int)sbuf[i];
}

// ---------------------------------------------------------------------------
// MFMA GEMM: C[M,128](bf16) = diag(fscale*dscale) @ A[M,128] @ W.
// Wt staged in LDS with 16B-slot XOR swizzle.
// ---------------------------------------------------------------------------
template <bool ABF16>
__global__ __launch_bounds__(256) void gemm_mfma(const void* __restrict__ Ap,
                                                 const unsigned short* __restrict__ Wt,
                                                 unsigned short* __restrict__ Cb,
                                                 const float* __restrict__ fscale,
                                                 const float* __restrict__ dscale) {
  __shared__ unsigned short Wsh[128 * 128];
  int tid  = threadIdx.x;
  int lane = tid & 63;
  int l15  = lane & 15, lg = lane >> 4;
  size_t rowbase = (size_t)blockIdx.x * 128 + (tid >> 6) * 32;

#pragma unroll
  for (int i = 0; i < 8; ++i) {
    int idx = tid + i * 256;
    int row = idx >> 4, s = idx & 15;
    short8 v = *(const short8*)(Wt + idx * 8);
    *(short8*)(Wsh + row * 128 + (s ^ (row & 15)) * 8) = v;
  }

  short8 afrag[2][4];
#pragma unroll
  for (int rg = 0; rg < 2; ++rg) {
    size_t row = rowbase + rg * 16 + l15;
#pragma unroll
    for (int c = 0; c < 4; ++c) {
      int k0 = c * 32 + lg * 8;
      if (ABF16) {
        afrag[rg][c] = *(const short8*)((const unsigned short*)Ap + row * 128 + k0);
      } else {
        const float* p = (const float*)Ap + row * 128 + k0;
        float4 v0 = *(const float4*)p;
        float4 v1 = *(const float4*)(p + 4);
        short8 a;
        a[0] = (short)f2bf(v0.x); a[1] = (short)f2bf(v0.y);
        a[2] = (short)f2bf(v0.z); a[3] = (short)f2bf(v0.w);
        a[4] = (short)f2bf(v1.x); a[5] = (short)f2bf(v1.y);
        a[6] = (short)f2bf(v1.z); a[7] = (short)f2bf(v1.w);
        afrag[rg][c] = a;
      }
    }
  }

  float fsr0[4] = {1.f, 1.f, 1.f, 1.f}, fsr1[4] = {1.f, 1.f, 1.f, 1.f};
  if (fscale != nullptr) {
    float4 t0 = *(const float4*)(fscale + rowbase + lg * 4);
    float4 t1 = *(const float4*)(fscale + rowbase + 16 + lg * 4);
    fsr0[0] = t0.x; fsr0[1] = t0.y; fsr0[2] = t0.z; fsr0[3] = t0.w;
    fsr1[0] = t1.x; fsr1[1] = t1.y; fsr1[2] = t1.z; fsr1[3] = t1.w;
  }
  if (dscale != nullptr) {
    float4 t0 = *(const float4*)(dscale + rowbase + lg * 4);
    float4 t1 = *(const float4*)(dscale + rowbase + 16 + lg * 4);
    fsr0[0] *= t0.x; fsr0[1] *= t0.y; fsr0[2] *= t0.z; fsr0[3] *= t0.w;
    fsr1[0] *= t1.x; fsr1[1] *= t1.y; fsr1[2] *= t1.z; fsr1[3] *= t1.w;
  }

  __syncthreads();

#pragma unroll
  for (int t = 0; t < 8; ++t) {
    int col = t * 16 + l15;
    short8 bfrag[4];
#pragma unroll
    for (int c = 0; c < 4; ++c)
      bfrag[c] = *(const short8*)(Wsh + col * 128 + ((c * 4 + lg) ^ (col & 15)) * 8);

    floatx4 acc0 = {0.f, 0.f, 0.f, 0.f};
    floatx4 acc1 = {0.f, 0.f, 0.f, 0.f};
#pragma unroll
    for (int c = 0; c < 4; ++c) {
      acc0 = __builtin_amdgcn_mfma_f32_16x16x32_bf16(afrag[0][c], bfrag[c], acc0, 0, 0, 0);
      acc1 = __builtin_amdgcn_mfma_f32_16x16x32_bf16(afrag[1][c], bfrag[c], acc1, 0, 0, 0);
    }
#pragma unroll
    for (int r = 0; r < 4; ++r) {
      size_t row0 = rowbase + lg * 4 + r;
      size_t row1 = rowbase + 16 + lg * 4 + r;
      Cb[row0 * 128 + col] = f2bf(acc0[r] * fsr0[r]);
      Cb[row1 * 128 + col] = f2bf(acc1[r] * fsr1[r]);
    }
  }
}

// ---------------------------------------------------------------------------
// GCN aggregation v8: wave per node, tmp rows pre-scaled by dinv (GEMM
// epilogue). Edge loop = full 16-batches of UNCONDITIONAL readlane+load
// (restores R8's load pipelining, lost to per-load branches in v7) plus one
// masked tail batch (pads load lane-0's valid row, value zeroed by cndmask).
// ---------------------------------------------------------------------------
template <bool ALL_LIVE>
__global__ __launch_bounds__(256) void gcn_agg8(
    const unsigned* __restrict__ tmp, const float* __restrict__ dinv,
    const int* __restrict__ offs, const int* __restrict__ ecnt,
    const int* __restrict__ csr, const float* __restrict__ bias,
    unsigned* __restrict__ hout,
    const float* __restrict__ wrel, const float* __restrict__ wroot,
    float* __restrict__ rr, float* __restrict__ tt) {
  int blk = blockIdx.x;
  int xcd = blk & 7;
  int j   = blk >> 3;                      // 0..4095
  int b   = xcd * 2 + (j >> 11);           // 2 graphs per XCD
  int n   = (j & 2047) * 4 + (threadIdx.x >> 6);
  int wid = b * N + n;
  int lane = threadIdx.x & 63;

  float dv = rdlane_f(dinv[wid], 0);
  unsigned* hrow = hout + (size_t)wid * 64;

  if (!ALL_LIVE && dv <= 0.0f) {
    hrow[lane] = 0u;
    if (rr != nullptr && lane == 0) { rr[wid] = 0.0f; tt[wid] = 0.0f; }
    return;
  }

  const unsigned* tmpb = tmp + (((size_t)b << 13) << 6);
  const int* cs = csr + (size_t)b * E;

  float2 accA, accB;
  {
    unsigned u = tmpb[((unsigned)n << 6) + lane];   // self term (pre-scaled)
    accA.x = __uint_as_float(u << 16);
    accA.y = __uint_as_float(u & 0xFFFF0000u);
    accB.x = 0.0f; accB.y = 0.0f;
  }

  int nbase = b * (N + 1) + n;
  int o0 = __builtin_amdgcn_readfirstlane(offs[nbase]);
  int d;
  if (ALL_LIVE) d = __builtin_amdgcn_readfirstlane(offs[nbase + 1]) - o0;
  else          d = __builtin_amdgcn_readfirstlane(ecnt[wid]);

  for (int base = 0; base < d; base += 64) {
    int nv = d - base; if (nv > 64) nv = 64;
    int sl = (lane < nv) ? cs[o0 + base + lane] : 0;

    int nfull = nv >> 4;
    for (int t = 0; t < nfull; ++t) {           // full batches: no masking
      int i0 = t << 4;
      unsigned uu[16];
#pragma unroll
      for (int q = 0; q < 16; ++q) {
        int sq = rdlane_i(sl, i0 + q);          // SGPR
        uu[q] = tmpb[((unsigned)sq << 6) + lane];
      }
#pragma unroll
      for (int q = 0; q < 16; ++q) {
        float lo = __uint_as_float(uu[q] << 16);
        float hi = __uint_as_float(uu[q] & 0xFFFF0000u);
        if (q & 1) { accB.x += lo; accB.y += hi; }
        else       { accA.x += lo; accA.y += hi; }
      }
    }
    int rem = nv & 15;
    if (rem) {                                   // one masked tail batch
      int i0 = nfull << 4;
      unsigned uu[16];
#pragma unroll
      for (int q = 0; q < 16; ++q) {
        int idx = i0 + q;
        int sq = rdlane_i(sl, idx < nv ? idx : 0);   // pad -> lane 0 (valid row)
        unsigned v = tmpb[((unsigned)sq << 6) + lane];
        uu[q] = (idx < nv) ? v : 0u;                  // zero pad values
      }
#pragma unroll
      for (int q = 0; q < 16; ++q) {
        float lo = __uint_as_float(uu[q] << 16);
        float hi = __uint_as_float(uu[q] & 0xFFFF0000u);
        if (q & 1) { accB.x += lo; accB.y += hi; }
        else       { accA.x += lo; accA.y += hi; }
      }
    }
  }

  float2 acc = {accA.x + accB.x, accA.y + accB.y};
  const float2 bb = *(const float2*)(bias + lane * 2);
  float2 outv;
  outv.x = fmaxf(dv * acc.x + bb.x, 0.0f);
  outv.y = fmaxf(dv * acc.y + bb.y, 0.0f);
  hrow[lane] = cvt_pk_bf16(outv.x, outv.y);

  if (rr != nullptr) {
    const float2 wr = *(const float2*)(wrel + lane * 2);
    const float2 wo = *(const float2*)(wroot + lane * 2);
    float pr = outv.x * wr.x + outv.y * wr.y;
    float pt = outv.x * wo.x + outv.y * wo.y;
#pragma unroll
    for (int dd = 32; dd > 0; dd >>= 1) {
      pr += __shfl_down(pr, dd);
      pt += __shfl_down(pt, dd);
    }
    if (lane == 0) { rr[wid] = pr; tt[wid] = pt; }
  }
}

// ---------------------------------------------------------------------------
// compact_pool (unchanged from R8/R9)
// ---------------------------------------------------------------------------
__global__ __launch_bounds__(256) void compact_pool(
    const float* __restrict__ mask, const int* __restrict__ offs,
    const int* __restrict__ ecnt_in, int* __restrict__ csr,
    int* __restrict__ ecnt_out, float* __restrict__ dinv_out) {
  int wid = blockIdx.x * 4 + (threadIdx.x >> 6);
  int lane = threadIdx.x & 63;
  int b = wid >> 13, n = wid & (N - 1);
  float m = rdlane_f(mask[wid], 0);
  if (m <= 0.0f) {
    if (lane == 0) { ecnt_out[wid] = 0; dinv_out[wid] = 0.0f; }
    return;
  }
  int nb = b * (N + 1) + n;
  int o0 = __builtin_amdgcn_readfirstlane(offs[nb]);
  int din = (ecnt_in != nullptr)
                ? __builtin_amdgcn_readfirstlane(ecnt_in[wid])
                : __builtin_amdgcn_readfirstlane(offs[nb + 1]) - o0;
  int* cs = csr + (size_t)b * E;
  const float* mb = mask + b * N;
  int wpos = o0;
  for (int base = 0; base < din; base += 64) {
    int nv = din - base; if (nv > 64) nv = 64;
    int s = (lane < nv) ? cs[o0 + base + lane] : 0;
    bool alive = (lane < nv) && (mb[s] > 0.0f);
    unsigned long long bal = __ballot(alive);
    int idx = __popcll(bal & ((1ull << lane) - 1ull));
    if (alive) cs[wpos + idx] = s;
    wpos += __popcll(bal);
  }
  if (lane == 0) {
    int total = wpos - o0;
    ecnt_out[wid] = total;
    dinv_out[wid] = rsqrtf((float)total + 1.0f);
  }
}

// ---------------------------------------------------------------------------
// pool score (unchanged)
// ---------------------------------------------------------------------------
__global__ __launch_bounds__(256) void score_agg(const float* __restrict__ r,
                                                 const float* __restrict__ t,
                                                 const float* __restrict__ pb,
                                                 const float* __restrict__ livep,
                                                 const int* __restrict__ offs,
                                                 const int* __restrict__ ecnt,
                                                 const int* __restrict__ csr,
                                                 float* __restrict__ score) {
  int grp = threadIdx.x >> 4;
  int gl  = threadIdx.x & 15;
  int nid = blockIdx.x * 16 + grp;
  int b = nid >> 13, n = nid & (N - 1);
  bool live = (livep == nullptr) || (livep[nid] > 0.0f);
  float s = 0.0f;
  if (live) {
    int o0 = offs[b * (N + 1) + n];
    int d = (ecnt != nullptr) ? ecnt[nid] : offs[b * (N + 1) + n + 1] - o0;
    const int* cs = csr + (size_t)b * E;
    const float* rb = r + b * N;
    for (int base = 0; base < d; base += 16)
      if (base + gl < d) s += rb[cs[o0 + base + gl]];
  }
#pragma unroll
  for (int dd = 8; dd > 0; dd >>= 1) s += __shfl_xor(s, dd, 16);
  if (gl == 0) score[nid] = live ? (s + t[nid] + pb[0]) : 0.0f;
}

// ---------------------------------------------------------------------------
// top-k via radix select — wave-level scans (2 barriers for tie-break, ~2
// per radix pass vs 16-20 block-wide barriers before).
// ---------------------------------------------------------------------------
__device__ __forceinline__ unsigned fkey(float s, float m) {
  if (m <= 0.0f) return 0u;
  unsigned u = __float_as_uint(s);
  return (u & 0x80000000u) ? ~u : (u | 0x80000000u);
}

__global__ __launch_bounds__(1024) void topk_kernel(const float* __restrict__ score,
                                                    const float* __restrict__ mkin,
                                                    float* __restrict__ mkout,
                                                    float* __restrict__ fscale,
                                                    int k) {
  int b = blockIdx.x, tid = threadIdx.x;
  const float* sc = score + b * N;
  float* mk = mkout + b * N;
  float* fs = fscale + b * N;
  __shared__ unsigned keyb[N];        // 32 KB
  __shared__ int hist[256];
  __shared__ unsigned sh_prefix;
  __shared__ int sh_kneed;
  __shared__ int wsum[16], wexc[16];

  for (int i = tid; i < N; i += 1024) {
    float m = (mkin == nullptr) ? 1.0f : mkin[b * N + i];
    keyb[i] = fkey(sc[i], m);
  }
  __syncthreads();

  unsigned prefix = 0, hm = 0;
  int kneed = k;
  for (int shift = 24; shift >= 0; shift -= 8) {
    if (tid < 256) hist[tid] = 0;
    __syncthreads();
    for (int i = tid; i < N; i += 1024) {
      unsigned key = keyb[i];
      if ((key & hm) == prefix) atomicAdd(&hist[(key >> shift) & 255], 1);
    }
    __syncthreads();
    if (tid < 64) {                    // single-wave bucket pick, 4 bins/lane
      int b4[4]; int s = 0;
#pragma unroll
      for (int j = 0; j < 4; ++j) { b4[j] = hist[tid * 4 + j]; s += b4[j]; }
      int suf = s;                     // suffix-inclusive over lanes
#pragma unroll
      for (int o = 1; o < 64; o <<= 1) {
        int v = __shfl_down(suf, o);
        if (tid + o < 64) suf += v;
      }
      int run = suf - s;               // sum over lanes > tid
      for (int j = 3; j >= 0; --j) {
        if (run < kneed && run + b4[j] >= kneed) {
          sh_prefix = prefix | ((unsigned)(tid * 4 + j) << shift);
          sh_kneed = kneed - run;
        }
        run += b4[j];
      }
    }
    __syncthreads();
    prefix = sh_prefix;
    kneed = sh_kneed;
    hm |= (0xFFu << shift);
  }

  unsigned T = prefix;                 // key of the k-th largest
  int base = tid * 8;
  unsigned keys[8];
  int eqf[8];
  int cnt = 0;
#pragma unroll
  for (int q = 0; q < 8; ++q) {
    keys[q] = keyb[base + q];
    eqf[q] = (keys[q] == T) ? 1 : 0;
    cnt += eqf[q];
  }
  // wave inclusive scan of cnt
  int inc = cnt;
  int wl = tid & 63;
#pragma unroll
  for (int o = 1; o < 64; o <<= 1) {
    int v = __shfl_up(inc, o);
    if (wl >= o) inc += v;
  }
  if (wl == 63) wsum[tid >> 6] = inc;
  __syncthreads();
  if (tid < 16) {                      // cross-wave exclusive scan (16 vals)
    int v = wsum[tid];
    int in = v;
#pragma unroll
    for (int o = 1; o < 16; o <<= 1) {
      int u = __shfl_up(in, o);
      if (tid >= o) in += u;
    }
    wexc[tid] = in - v;
  }
  __syncthreads();
  int ex = wexc[tid >> 6] + (inc - cnt);   // rank base among ties (index order)
#pragma unroll
  for (int q = 0; q < 8; ++q) {
    bool sel = (keys[q] > T) || (eqf[q] && (ex < kneed));
    ex += eqf[q];
    mk[base + q] = sel ? 1.0f : 0.0f;
    fs[base + q] = sel ? tanhf(sc[base + q]) : 0.0f;
  }
}

// ---------------------------------------------------------------------------
// readout partials (bf16 h) + head MLP + log_softmax
// ---------------------------------------------------------------------------
__global__ __launch_bounds__(256) void readout(const unsigned short* __restrict__ h,
                                               float* __restrict__ part) {
  int b = blockIdx.x, c = blockIdx.y;
  int tid = threadIdx.x;
  int f = tid & 127, half = tid >> 7;
  float acc = 0.0f;
  for (int n = c * 256 + half; n < (c + 1) * 256; n += 2)
    acc += bf2f(h[((size_t)b * N + n) * 128 + f]);
  __shared__ float red[256];
  red[tid] = acc; __syncthreads();
  if (half == 0) part[((size_t)b * 32 + c) * 128 + f] = red[f] + red[f + 128];
}

__global__ __launch_bounds__(128) void head(const float* __restrict__ part,
                                            const float* __restrict__ l1w,
                                            const float* __restrict__ l1b,
                                            const float* __restrict__ l2w,
                                            const float* __restrict__ l2b,
                                            float* __restrict__ out) {
  int b = blockIdx.x, f = threadIdx.x;
  float g = 0.0f;
  for (int c = 0; c < 32; ++c) g += part[((size_t)b * 32 + c) * 128 + f];
  g *= (1.0f / (float)K2);
  __shared__ float gs[128], hh[128], lg[10];
  gs[f] = g; __syncthreads();
  float a = l1b[f];
  for (int kk = 0; kk < 128; ++kk) a += gs[kk] * l1w[kk * 128 + f];
  hh[f] = fmaxf(a, 0.0f); __syncthreads();
  if (f < 10) {
    float l = l2b[f];
    for (int j = 0; j < 128; ++j) l += hh[j] * l2w[j * 10 + f];
    lg[f] = l;
  }
  __syncthreads();
  if (f == 0) {
    float m = lg[0];
    for (int c = 1; c < 10; ++c) m = fmaxf(m, lg[c]);
    float s = 0.0f;
    for (int c = 0; c < 10; ++c) s += expf(lg[c] - m);
    float lse = m + logf(s);
    for (int c = 0; c < 10; ++c) out[b * 10 + c] = lg[c] - lse;
  }
}

// ---------------------------------------------------------------------------
extern "C" void kernel_launch(void* const* d_in, const int* in_sizes, int n_in,
                              void* d_out, int out_size, void* d_ws, size_t ws_size,
                              hipStream_t stream) {
  (void)in_sizes; (void)n_in; (void)out_size; (void)ws_size;
  const float* x       = (const float*)d_in[0];
  const int*   ei      = (const int*)d_in[1];
  const float* W1      = (const float*)d_in[2];
  const float* b1      = (const float*)d_in[3];
  const float* p1_wrel = (const float*)d_in[4];
  const float* p1_wroot= (const float*)d_in[5];
  const float* p1_b    = (const float*)d_in[6];
  const float* W2      = (const float*)d_in[7];
  const float* b2      = (const float*)d_in[8];
  const float* p2_wrel = (const float*)d_in[9];
  const float* p2_wroot= (const float*)d_in[10];
  const float* p2_b    = (const float*)d_in[11];
  const float* W3      = (const float*)d_in[12];
  const float* b3      = (const float*)d_in[13];
  const float* l1w     = (const float*)d_in[14];
  const float* l1b     = (const float*)d_in[15];
  const float* l2w     = (const float*)d_in[16];
  const float* l2b     = (const float*)d_in[17];
  float* out = (float*)d_out;

  char* p = (char*)d_ws;
  auto alloc = [&](size_t bytes) {
    char* r = p;
    p += ((bytes + 255) & ~(size_t)255);
    return r;
  };
  unsigned short* h   = (unsigned short*)alloc((size_t)B * N * H * 2);   // bf16
  unsigned short* tmp = (unsigned short*)alloc((size_t)B * N * H * 2);   // bf16
  int*      offs   = (int*)alloc((size_t)B * (N + 1) * 4);
  int*      csr    = (int*)alloc((size_t)B * E * 4);
  unsigned* pbuf   = (unsigned*)alloc((size_t)B * E * 4);
  int*      bchist = (int*)alloc((size_t)B * CHUNKS * NBK * 4);
  int*      cursor = (int*)alloc((size_t)B * CHUNKS * NBK * 4);
  int*      bbase  = (int*)alloc((size_t)B * (NBK + 1) * 4);
  int*      ecnt   = (int*)alloc((size_t)B * N * 4);
  float* dinv   = (float*)alloc((size_t)B * N * 4);
  float* mask   = (float*)alloc((size_t)B * N * 4);
  float* rr     = (float*)alloc((size_t)B * N * 4);
  float* tt     = (float*)alloc((size_t)B * N * 4);
  float* score  = (float*)alloc((size_t)B * N * 4);
  float* fscale = (float*)alloc((size_t)B * N * 4);
  float* part   = (float*)alloc((size_t)B * 32 * H * 4);
  unsigned short* Wts = (unsigned short*)alloc(3 * 128 * 128 * 2);

  // CSR build (streaming counting sort); weight prep fused into bucket_scan
  hist_pass<<<B * CHUNKS, 256, 0, stream>>>(ei, bchist);
  bucket_scan<<<19, 256, 0, stream>>>(bchist, cursor, bbase, W1, W2, W3, Wts);
  bin_scatter<<<B * CHUNKS, 256, 0, stream>>>(ei, cursor, pbuf);
  final_scatter<<<B * NBK, 256, 0, stream>>>(pbuf, bbase, csr, offs, dinv);

  // ---- layer 1 + pool 1 (all nodes live; dinv folded into GEMM epilogue)
  gemm_mfma<false><<<(B * N) / 128, 256, 0, stream>>>(x, Wts, tmp, nullptr, dinv);
  gcn_agg8<true><<<B * N / 4, 256, 0, stream>>>((const unsigned*)tmp, dinv, offs,
                                                nullptr, csr, b1, (unsigned*)h,
                                                p1_wrel, p1_wroot, rr, tt);
  score_agg<<<B * N / 16, 256, 0, stream>>>(rr, tt, p1_b, nullptr, offs, nullptr,
                                            csr, score);
  topk_kernel<<<B, 1024, 0, stream>>>(score, nullptr, mask, fscale, K1);
  compact_pool<<<B * N / 4, 256, 0, stream>>>(mask, offs, nullptr, csr, ecnt, dinv);

  // ---- layer 2 + pool 2
  gemm_mfma<true><<<(B * N) / 128, 256, 0, stream>>>(h, Wts + 128 * 128, tmp,
                                                     fscale, dinv);
  gcn_agg8<false><<<B * N / 4, 256, 0, stream>>>((const unsigned*)tmp, dinv, offs,
                                                 ecnt, csr, b2, (unsigned*)h,
                                                 p2_wrel, p2_wroot, rr, tt);
  score_agg<<<B * N / 16, 256, 0, stream>>>(rr, tt, p2_b, dinv, offs, ecnt, csr, score);
  topk_kernel<<<B, 1024, 0, stream>>>(score, mask, mask, fscale, K2);
  compact_pool<<<B * N / 4, 256, 0, stream>>>(mask, offs, ecnt, csr, ecnt, dinv);

  // ---- layer 3
  gemm_mfma<true><<<(B * N) / 128, 256, 0, stream>>>(h, Wts + 2 * 128 * 128, tmp,
                                                     fscale, dinv);
  gcn_agg8<false><<<B * N / 4, 256, 0, stream>>>((const unsigned*)tmp, dinv, offs,
                                                 ecnt, csr, b3, (unsigned*)h,
                                                 nullptr, nullptr, nullptr, nullptr);

  // ---- readout + head
  readout<<<dim3(B, 32), 256, 0, stream>>>(h, part);
  head<<<B, 128, 0, stream>>>(part, l1w, l1b, l2w, l2b, out);
}

// Round 11
// 327.528 us; speedup vs baseline: 1.6397x; 1.1982x over previous
//
#include <hip/hip_runtime.h>
#include <hip/hip_bf16.h>
#include <math.h>

// Problem constants
constexpr int B  = 16;
constexpr int N  = 8192;     // 2^13
constexpr int E  = 131072;   // 2^17
constexpr int H  = 128;
constexpr int K1 = 4096;
constexpr int K2 = 2048;

constexpr int CHUNKS = 16;
constexpr int NBK    = 16;
constexpr int FCAP   = 12288;

typedef __attribute__((ext_vector_type(8))) short short8;
typedef __attribute__((ext_vector_type(4))) float floatx4;

__device__ __forceinline__ unsigned short f2bf(float f) {
  unsigned u = __float_as_uint(f);
  return (unsigned short)((u + 0x7FFFu + ((u >> 16) & 1u)) >> 16);  // RNE
}
__device__ __forceinline__ float bf2f(unsigned short s) {
  return __uint_as_float(((unsigned)s) << 16);
}
__device__ __forceinline__ int rdlane_i(int v, int l) {
  return __builtin_amdgcn_readlane(v, l);
}
__device__ __forceinline__ float rdlane_f(float v, int l) {
  return __uint_as_float((unsigned)__builtin_amdgcn_readlane((int)__float_as_uint(v), l));
}
__device__ __forceinline__ unsigned cvt_pk_bf16(float a, float b) {
  unsigned r;
  asm("v_cvt_pk_bf16_f32 %0, %1, %2" : "=v"(r) : "v"(a), "v"(b));
  return r;
}

// ---------------------------------------------------------------------------
// CSR build (streaming counting sort) — unchanged from R10
// ---------------------------------------------------------------------------
__global__ __launch_bounds__(256) void hist_pass(const int* __restrict__ ei,
                                                 int* __restrict__ bchist) {
  int blk = blockIdx.x;
  int b = blk >> 4, c = blk & 15;
  __shared__ int h16[NBK];
  if (threadIdx.x < NBK) h16[threadIdx.x] = 0;
  __syncthreads();
  const int* dstp = ei + (size_t)b * 2 * E + E + c * 8192;
  for (int i = 0; i < 32; ++i) {
    int dst = dstp[i * 256 + threadIdx.x];
    atomicAdd(&h16[dst >> 9], 1);
  }
  __syncthreads();
  if (threadIdx.x < NBK) bchist[(blk << 4) + threadIdx.x] = h16[threadIdx.x];
}

__global__ __launch_bounds__(256) void bucket_scan(const int* __restrict__ bchist,
                                                   int* __restrict__ cursor,
                                                   int* __restrict__ bbase,
                                                   const float* __restrict__ W1,
                                                   const float* __restrict__ W2,
                                                   const float* __restrict__ W3,
                                                   unsigned short* __restrict__ Wt) {
  if (blockIdx.x >= 16) {
    int w = blockIdx.x - 16;
    const float* W = (w == 0) ? W1 : (w == 1) ? W2 : W3;
    unsigned short* o = Wt + w * 128 * 128;
    for (int i = threadIdx.x; i < 128 * 128; i += 256) {
      int k = i >> 7, n = i & 127;
      o[n * 128 + k] = f2bf(W[i]);
    }
    return;
  }
  int b = blockIdx.x;
  int tid = threadIdx.x;
  int c = tid >> 4, k = tid & 15;
  __shared__ int arr[CHUNKS][NBK];
  __shared__ int base[NBK + 1];
  arr[c][k] = bchist[((b * CHUNKS + c) << 4) + k];
  __syncthreads();
  if (tid == 0) {
    int run = 0;
    for (int kk = 0; kk < NBK; ++kk) {
      base[kk] = run;
      int t = 0;
      for (int cc = 0; cc < CHUNKS; ++cc) t += arr[cc][kk];
      run += t;
    }
    base[NBK] = run;
  }
  __syncthreads();
  int pre = 0;
  for (int cc = 0; cc < c; ++cc) pre += arr[cc][k];
  cursor[((b * CHUNKS + c) << 4) + k] = base[k] + pre;
  if (tid < NBK + 1) bbase[b * (NBK + 1) + tid] = base[tid];
}

__global__ __launch_bounds__(256) void bin_scatter(const int* __restrict__ ei,
                                                   const int* __restrict__ cursor,
                                                   unsigned* __restrict__ pbuf) {
  int blk = blockIdx.x;
  int b = blk >> 4, c = blk & 15;
  __shared__ int gcur[NBK], lcnt[NBK], lfill[NBK];
  __shared__ int lbase[NBK + 1];
  __shared__ unsigned sbuf[2048];
  int tid = threadIdx.x;
  if (tid < NBK) gcur[tid] = cursor[(blk << 4) + tid];
  const int* srcp = ei + (size_t)b * 2 * E + c * 8192;
  const int* dstp = srcp + E;
  unsigned* pb = pbuf + (size_t)b * E;

  for (int sc = 0; sc < 4; ++sc) {
    if (tid < NBK) { lcnt[tid] = 0; lfill[tid] = 0; }
    __syncthreads();
    int s8[8], d8[8];
#pragma unroll
    for (int q = 0; q < 8; ++q) {
      int i = sc * 2048 + q * 256 + tid;
      s8[q] = srcp[i]; d8[q] = dstp[i];
      atomicAdd(&lcnt[d8[q] >> 9], 1);
    }
    __syncthreads();
    if (tid == 0) {
      int run = 0;
      for (int k = 0; k < NBK; ++k) { lbase[k] = run; run += lcnt[k]; }
      lbase[NBK] = run;
    }
    __syncthreads();
#pragma unroll
    for (int q = 0; q < 8; ++q) {
      int k = d8[q] >> 9;
      int idx = atomicAdd(&lfill[k], 1);
      sbuf[lbase[k] + idx] = ((unsigned)k << 22) |
                             ((unsigned)(d8[q] & 511) << 13) | (unsigned)s8[q];
    }
    __syncthreads();
    for (int i = tid; i < 2048; i += 256) {
      unsigned pk = sbuf[i];
      int k = (int)(pk >> 22);
      pb[gcur[k] + (i - lbase[k])] = pk;
    }
    __syncthreads();
    if (tid < NBK) gcur[tid] += lcnt[tid];
    __syncthreads();
  }
}

__global__ __launch_bounds__(256) void final_scatter(const unsigned* __restrict__ pbuf,
                                                     const int* __restrict__ bbase,
                                                     int* __restrict__ csr,
                                                     int* __restrict__ offs,
                                                     float* __restrict__ dinv1) {
  int blk = blockIdx.x;
  int b = blk >> 4, k = blk & 15;
  __shared__ int ncnt[512], nbase[512], nfill[512];
  __shared__ int sred[256];
  __shared__ unsigned sbuf[FCAP];
  int tid = threadIdx.x;
  int gbase = bbase[b * (NBK + 1) + k];
  int gend  = bbase[b * (NBK + 1) + k + 1];
  int cnt = gend - gbase;
  const unsigned* pb = pbuf + (size_t)b * E + gbase;

  for (int i = tid; i < 512; i += 256) { ncnt[i] = 0; nfill[i] = 0; }
  __syncthreads();
  for (int i = tid; i < cnt; i += 256) atomicAdd(&ncnt[(pb[i] >> 13) & 511], 1);
  __syncthreads();
  int v0 = ncnt[2 * tid], v1 = ncnt[2 * tid + 1];
  int s = v0 + v1;
  sred[tid] = s;
  __syncthreads();
  for (int off = 1; off < 256; off <<= 1) {
    int x = (tid >= off) ? sred[tid - off] : 0;
    __syncthreads();
    sred[tid] += x;
    __syncthreads();
  }
  int ex = sred[tid] - s;
  nbase[2 * tid] = ex;
  nbase[2 * tid + 1] = ex + v0;
  __syncthreads();
  for (int i = tid; i < 512; i += 256) {
    int node = k * 512 + i;
    offs[b * (N + 1) + node] = gbase + nbase[i];
    dinv1[b * N + node] = rsqrtf((float)ncnt[i] + 1.0f);
  }
  if (k == 15 && tid == 0) offs[b * (N + 1) + N] = E;
  __syncthreads();
  for (int i = tid; i < cnt; i += 256) {
    unsigned pk = pb[i];
    int node = (pk >> 13) & 511;
    int idx = atomicAdd(&nfill[node], 1);
    sbuf[nbase[node] + idx] = pk & 8191u;
  }
  __syncthreads();
  int* co = csr + (size_t)b * E + gbase;
  for (int i = tid; i < cnt; i += 256) co[i] = (int)sbuf[i];
}

// ---------------------------------------------------------------------------
// GEMM layer-1: full rows, fp32 A, dscale (=dinv1) in epilogue.
// ---------------------------------------------------------------------------
__global__ __launch_bounds__(256) void gemm_l1(const float* __restrict__ Ap,
                                               const unsigned short* __restrict__ Wt,
                                               unsigned short* __restrict__ Cb,
                                               const float* __restrict__ dscale) {
  __shared__ unsigned short Wsh[128 * 128];
  int tid  = threadIdx.x;
  int lane = tid & 63;
  int l15  = lane & 15, lg = lane >> 4;
  size_t rowbase = (size_t)blockIdx.x * 128 + (tid >> 6) * 32;

#pragma unroll
  for (int i = 0; i < 8; ++i) {
    int idx = tid + i * 256;
    int row = idx >> 4, s = idx & 15;
    short8 v = *(const short8*)(Wt + idx * 8);
    *(short8*)(Wsh + row * 128 + (s ^ (row & 15)) * 8) = v;
  }

  short8 afrag[2][4];
#pragma unroll
  for (int rg = 0; rg < 2; ++rg) {
    size_t row = rowbase + rg * 16 + l15;
#pragma unroll
    for (int c = 0; c < 4; ++c) {
      const float* p = Ap + row * 128 + c * 32 + lg * 8;
      float4 v0 = *(const float4*)p;
      float4 v1 = *(const float4*)(p + 4);
      short8 a;
      a[0] = (short)f2bf(v0.x); a[1] = (short)f2bf(v0.y);
      a[2] = (short)f2bf(v0.z); a[3] = (short)f2bf(v0.w);
      a[4] = (short)f2bf(v1.x); a[5] = (short)f2bf(v1.y);
      a[6] = (short)f2bf(v1.z); a[7] = (short)f2bf(v1.w);
      afrag[rg][c] = a;
    }
  }

  float fsr0[4], fsr1[4];
  {
    float4 t0 = *(const float4*)(dscale + rowbase + lg * 4);
    float4 t1 = *(const float4*)(dscale + rowbase + 16 + lg * 4);
    fsr0[0] = t0.x; fsr0[1] = t0.y; fsr0[2] = t0.z; fsr0[3] = t0.w;
    fsr1[0] = t1.x; fsr1[1] = t1.y; fsr1[2] = t1.z; fsr1[3] = t1.w;
  }

  __syncthreads();

#pragma unroll
  for (int t = 0; t < 8; ++t) {
    int col = t * 16 + l15;
    short8 bfrag[4];
#pragma unroll
    for (int c = 0; c < 4; ++c)
      bfrag[c] = *(const short8*)(Wsh + col * 128 + ((c * 4 + lg) ^ (col & 15)) * 8);

    floatx4 acc0 = {0.f, 0.f, 0.f, 0.f};
    floatx4 acc1 = {0.f, 0.f, 0.f, 0.f};
#pragma unroll
    for (int c = 0; c < 4; ++c) {
      acc0 = __builtin_amdgcn_mfma_f32_16x16x32_bf16(afrag[0][c], bfrag[c], acc0, 0, 0, 0);
      acc1 = __builtin_amdgcn_mfma_f32_16x16x32_bf16(afrag[1][c], bfrag[c], acc1, 0, 0, 0);
    }
#pragma unroll
    for (int r = 0; r < 4; ++r) {
      size_t row0 = rowbase + lg * 4 + r;
      size_t row1 = rowbase + 16 + lg * 4 + r;
      Cb[row0 * 128 + col] = f2bf(acc0[r] * fsr0[r]);
      Cb[row1 * 128 + col] = f2bf(acc1[r] * fsr1[r]);
    }
  }
}

// ---------------------------------------------------------------------------
// GEMM layers 2/3: LIVE rows only via per-graph index list. LGB = log2(K/128).
// C[idx] = diag(fscale*dscale)[idx] @ A[idx] @ W, bf16 A.
// ---------------------------------------------------------------------------
template <int LGB>
__global__ __launch_bounds__(256) void gemm_idx(const unsigned short* __restrict__ Ab,
                                                const unsigned short* __restrict__ Wt,
                                                unsigned short* __restrict__ Cb,
                                                const float* __restrict__ fscale,
                                                const float* __restrict__ dscale,
                                                const int* __restrict__ idxl) {
  __shared__ unsigned short Wsh[128 * 128];
  __shared__ int ridx[128];
  int tid  = threadIdx.x;
  int lane = tid & 63;
  int l15  = lane & 15, lg = lane >> 4;
  int b    = blockIdx.x >> LGB;
  int lblk = blockIdx.x & ((1 << LGB) - 1);
  int woff = (tid >> 6) * 32;

  if (tid < 128) ridx[tid] = idxl[b * N + lblk * 128 + tid];
#pragma unroll
  for (int i = 0; i < 8; ++i) {
    int idx = tid + i * 256;
    int row = idx >> 4, s = idx & 15;
    short8 v = *(const short8*)(Wt + idx * 8);
    *(short8*)(Wsh + row * 128 + (s ^ (row & 15)) * 8) = v;
  }
  __syncthreads();

  const unsigned short* Ag = Ab + (size_t)b * N * 128;
  unsigned short* Cg = Cb + (size_t)b * N * 128;
  const float* fsb = fscale + b * N;
  const float* dsb = dscale + b * N;

  short8 afrag[2][4];
#pragma unroll
  for (int rg = 0; rg < 2; ++rg) {
    int arow = ridx[woff + rg * 16 + l15];
#pragma unroll
    for (int c = 0; c < 4; ++c)
      afrag[rg][c] = *(const short8*)(Ag + (size_t)arow * 128 + c * 32 + lg * 8);
  }

  int orow[2][4]; float fsr[2][4];
#pragma unroll
  for (int rg = 0; rg < 2; ++rg)
#pragma unroll
    for (int r = 0; r < 4; ++r) {
      int o = ridx[woff + rg * 16 + lg * 4 + r];
      orow[rg][r] = o;
      fsr[rg][r] = fsb[o] * dsb[o];
    }

#pragma unroll
  for (int t = 0; t < 8; ++t) {
    int col = t * 16 + l15;
    short8 bfrag[4];
#pragma unroll
    for (int c = 0; c < 4; ++c)
      bfrag[c] = *(const short8*)(Wsh + col * 128 + ((c * 4 + lg) ^ (col & 15)) * 8);

    floatx4 acc0 = {0.f, 0.f, 0.f, 0.f};
    floatx4 acc1 = {0.f, 0.f, 0.f, 0.f};
#pragma unroll
    for (int c = 0; c < 4; ++c) {
      acc0 = __builtin_amdgcn_mfma_f32_16x16x32_bf16(afrag[0][c], bfrag[c], acc0, 0, 0, 0);
      acc1 = __builtin_amdgcn_mfma_f32_16x16x32_bf16(afrag[1][c], bfrag[c], acc1, 0, 0, 0);
    }
#pragma unroll
    for (int r = 0; r < 4; ++r) {
      Cg[(size_t)orow[0][r] * 128 + col] = f2bf(acc0[r] * fsr[0][r]);
      Cg[(size_t)orow[1][r] * 128 + col] = f2bf(acc1[r] * fsr[1][r]);
    }
  }
}

// ---------------------------------------------------------------------------
// GCN aggregation layer-1 (full, all live) — R10's proven agg8 structure.
// ---------------------------------------------------------------------------
__global__ __launch_bounds__(256) void gcn_agg_l1(
    const unsigned* __restrict__ tmp, const float* __restrict__ dinv,
    const int* __restrict__ offs, const int* __restrict__ csr,
    const float* __restrict__ bias, unsigned* __restrict__ hout,
    const float* __restrict__ wrel, const float* __restrict__ wroot,
    float* __restrict__ rr, float* __restrict__ tt) {
  int blk = blockIdx.x;
  int xcd = blk & 7;
  int j   = blk >> 3;
  int b   = xcd * 2 + (j >> 11);
  int n   = (j & 2047) * 4 + (threadIdx.x >> 6);
  int wid = b * N + n;
  int lane = threadIdx.x & 63;

  float dv = rdlane_f(dinv[wid], 0);
  unsigned* hrow = hout + (size_t)wid * 64;

  const unsigned* tmpb = tmp + (((size_t)b << 13) << 6);
  const int* cs = csr + (size_t)b * E;

  float2 accA, accB;
  {
    unsigned u = tmpb[((unsigned)n << 6) + lane];
    accA.x = __uint_as_float(u << 16);
    accA.y = __uint_as_float(u & 0xFFFF0000u);
    accB.x = 0.0f; accB.y = 0.0f;
  }

  int nbase = b * (N + 1) + n;
  int o0 = __builtin_amdgcn_readfirstlane(offs[nbase]);
  int d  = __builtin_amdgcn_readfirstlane(offs[nbase + 1]) - o0;

  for (int base = 0; base < d; base += 64) {
    int nv = d - base; if (nv > 64) nv = 64;
    int sl = (lane < nv) ? cs[o0 + base + lane] : 0;
    int nfull = nv >> 4;
    for (int t = 0; t < nfull; ++t) {
      int i0 = t << 4;
      unsigned uu[16];
#pragma unroll
      for (int q = 0; q < 16; ++q) {
        int sq = rdlane_i(sl, i0 + q);
        uu[q] = tmpb[((unsigned)sq << 6) + lane];
      }
#pragma unroll
      for (int q = 0; q < 16; ++q) {
        float lo = __uint_as_float(uu[q] << 16);
        float hi = __uint_as_float(uu[q] & 0xFFFF0000u);
        if (q & 1) { accB.x += lo; accB.y += hi; }
        else       { accA.x += lo; accA.y += hi; }
      }
    }
    int rem = nv & 15;
    if (rem) {
      int i0 = nfull << 4;
      unsigned uu[16];
#pragma unroll
      for (int q = 0; q < 16; ++q) {
        int idx = i0 + q;
        int sq = rdlane_i(sl, idx < nv ? idx : 0);
        unsigned v = tmpb[((unsigned)sq << 6) + lane];
        uu[q] = (idx < nv) ? v : 0u;
      }
#pragma unroll
      for (int q = 0; q < 16; ++q) {
        float lo = __uint_as_float(uu[q] << 16);
        float hi = __uint_as_float(uu[q] & 0xFFFF0000u);
        if (q & 1) { accB.x += lo; accB.y += hi; }
        else       { accA.x += lo; accA.y += hi; }
      }
    }
  }

  float2 acc = {accA.x + accB.x, accA.y + accB.y};
  const float2 bb = *(const float2*)(bias + lane * 2);
  float2 outv;
  outv.x = fmaxf(dv * acc.x + bb.x, 0.0f);
  outv.y = fmaxf(dv * acc.y + bb.y, 0.0f);
  hrow[lane] = cvt_pk_bf16(outv.x, outv.y);

  const float2 wr = *(const float2*)(wrel + lane * 2);
  const float2 wo = *(const float2*)(wroot + lane * 2);
  float pr = outv.x * wr.x + outv.y * wr.y;
  float pt = outv.x * wo.x + outv.y * wo.y;
#pragma unroll
  for (int dd = 32; dd > 0; dd >>= 1) {
    pr += __shfl_down(pr, dd);
    pt += __shfl_down(pt, dd);
  }
  if (lane == 0) { rr[wid] = pr; tt[wid] = pt; }
}

// ---------------------------------------------------------------------------
// GCN aggregation layers 2/3: iterate the LIVE index list. LOGPG =
// log2(KLIVE/4). FUSE_RO: skip h write, block-reduce outv and atomicAdd into
// the per-graph readout accumulator gacc[b][128].
// ---------------------------------------------------------------------------
template <int LOGPG, bool FUSE_RO>
__global__ __launch_bounds__(256) void gcn_agg_idx(
    const unsigned* __restrict__ tmp, const float* __restrict__ dinv,
    const int* __restrict__ offs, const int* __restrict__ ecnt,
    const int* __restrict__ csr, const float* __restrict__ bias,
    unsigned* __restrict__ hout, const float* __restrict__ wrel,
    const float* __restrict__ wroot, float* __restrict__ rr,
    float* __restrict__ tt, const int* __restrict__ idxl,
    float* __restrict__ gacc) {
  __shared__ float racc[128];
  int blk = blockIdx.x;
  int xcd = blk & 7;
  int j   = blk >> 3;
  int b   = xcd * 2 + (j >> LOGPG);
  int i   = (j & ((1 << LOGPG) - 1)) * 4 + (threadIdx.x >> 6);
  int lane = threadIdx.x & 63;

  if (FUSE_RO) {
    if (threadIdx.x < 128) racc[threadIdx.x] = 0.0f;
    __syncthreads();
  }

  int n = __builtin_amdgcn_readfirstlane(idxl[b * N + i]);   // live node id
  int wid = b * N + n;
  float dv = rdlane_f(dinv[wid], 0);

  const unsigned* tmpb = tmp + (((size_t)b << 13) << 6);
  const int* cs = csr + (size_t)b * E;

  float2 accA, accB;
  {
    unsigned u = tmpb[((unsigned)n << 6) + lane];
    accA.x = __uint_as_float(u << 16);
    accA.y = __uint_as_float(u & 0xFFFF0000u);
    accB.x = 0.0f; accB.y = 0.0f;
  }

  int o0 = __builtin_amdgcn_readfirstlane(offs[b * (N + 1) + n]);
  int d  = __builtin_amdgcn_readfirstlane(ecnt[wid]);

  for (int base = 0; base < d; base += 64) {
    int nv = d - base; if (nv > 64) nv = 64;
    int sl = (lane < nv) ? cs[o0 + base + lane] : 0;
    int nfull = nv >> 4;
    for (int t = 0; t < nfull; ++t) {
      int i0 = t << 4;
      unsigned uu[16];
#pragma unroll
      for (int q = 0; q < 16; ++q) {
        int sq = rdlane_i(sl, i0 + q);
        uu[q] = tmpb[((unsigned)sq << 6) + lane];
      }
#pragma unroll
      for (int q = 0; q < 16; ++q) {
        float lo = __uint_as_float(uu[q] << 16);
        float hi = __uint_as_float(uu[q] & 0xFFFF0000u);
        if (q & 1) { accB.x += lo; accB.y += hi; }
        else       { accA.x += lo; accA.y += hi; }
      }
    }
    int rem = nv & 15;
    if (rem) {
      int i0 = nfull << 4;
      unsigned uu[16];
#pragma unroll
      for (int q = 0; q < 16; ++q) {
        int idx = i0 + q;
        int sq = rdlane_i(sl, idx < nv ? idx : 0);
        unsigned v = tmpb[((unsigned)sq << 6) + lane];
        uu[q] = (idx < nv) ? v : 0u;
      }
#pragma unroll
      for (int q = 0; q < 16; ++q) {
        float lo = __uint_as_float(uu[q] << 16);
        float hi = __uint_as_float(uu[q] & 0xFFFF0000u);
        if (q & 1) { accB.x += lo; accB.y += hi; }
        else       { accA.x += lo; accA.y += hi; }
      }
    }
  }

  float2 acc = {accA.x + accB.x, accA.y + accB.y};
  const float2 bb = *(const float2*)(bias + lane * 2);
  float2 outv;
  outv.x = fmaxf(dv * acc.x + bb.x, 0.0f);
  outv.y = fmaxf(dv * acc.y + bb.y, 0.0f);

  if (!FUSE_RO) {
    unsigned* hrow = hout + (size_t)wid * 64;
    hrow[lane] = cvt_pk_bf16(outv.x, outv.y);
    const float2 wr = *(const float2*)(wrel + lane * 2);
    const float2 wo = *(const float2*)(wroot + lane * 2);
    float pr = outv.x * wr.x + outv.y * wr.y;
    float pt = outv.x * wo.x + outv.y * wo.y;
#pragma unroll
    for (int dd = 32; dd > 0; dd >>= 1) {
      pr += __shfl_down(pr, dd);
      pt += __shfl_down(pt, dd);
    }
    if (lane == 0) { rr[wid] = pr; tt[wid] = pt; }
  } else {
    atomicAdd(&racc[lane * 2],     outv.x);
    atomicAdd(&racc[lane * 2 + 1], outv.y);
    __syncthreads();
    if (threadIdx.x < 128) atomicAdd(&gacc[b * 128 + threadIdx.x], racc[threadIdx.x]);
  }
}

// ---------------------------------------------------------------------------
// compact (live nodes only, via index list). LOGK = log2(KLIVE).
// ---------------------------------------------------------------------------
template <int LOGK>
__global__ __launch_bounds__(256) void compact_idx(
    const int* __restrict__ idxl, const float* __restrict__ mask,
    const int* __restrict__ offs, const int* __restrict__ ecnt_in,
    int* __restrict__ csr, int* __restrict__ ecnt_out,
    float* __restrict__ dinv_out) {
  int ws = blockIdx.x * 4 + (threadIdx.x >> 6);
  int b = ws >> LOGK;
  int i = ws & ((1 << LOGK) - 1);
  int lane = threadIdx.x & 63;
  int n = __builtin_amdgcn_readfirstlane(idxl[b * N + i]);
  int wid = b * N + n;
  int nb = b * (N + 1) + n;
  int o0 = __builtin_amdgcn_readfirstlane(offs[nb]);
  int din = (ecnt_in != nullptr)
                ? __builtin_amdgcn_readfirstlane(ecnt_in[wid])
                : __builtin_amdgcn_readfirstlane(offs[nb + 1]) - o0;
  int* cs = csr + (size_t)b * E;
  const float* mb = mask + b * N;
  int wpos = o0;
  for (int base = 0; base < din; base += 64) {
    int nv = din - base; if (nv > 64) nv = 64;
    int s = (lane < nv) ? cs[o0 + base + lane] : 0;
    bool alive = (lane < nv) && (mb[s] > 0.0f);
    unsigned long long bal = __ballot(alive);
    int idx = __popcll(bal & ((1ull << lane) - 1ull));
    if (alive) cs[wpos + idx] = s;
    wpos += __popcll(bal);
  }
  if (lane == 0) {
    int total = wpos - o0;
    ecnt_out[wid] = total;
    dinv_out[wid] = rsqrtf((float)total + 1.0f);
  }
}

// ---------------------------------------------------------------------------
// pool score layer 1 (full, all live) and layer 2 (idx-restricted).
// ---------------------------------------------------------------------------
__global__ __launch_bounds__(256) void score_l1(const float* __restrict__ r,
                                                const float* __restrict__ t,
                                                const float* __restrict__ pb,
                                                const int* __restrict__ offs,
                                                const int* __restrict__ csr,
                                                float* __restrict__ score) {
  int grp = threadIdx.x >> 4;
  int gl  = threadIdx.x & 15;
  int nid = blockIdx.x * 16 + grp;
  int b = nid >> 13, n = nid & (N - 1);
  int o0 = offs[b * (N + 1) + n], o1 = offs[b * (N + 1) + n + 1];
  const int* cs = csr + (size_t)b * E;
  const float* rb = r + b * N;
  float s = 0.0f;
  for (int base = o0; base < o1; base += 16)
    if (base + gl < o1) s += rb[cs[base + gl]];
#pragma unroll
  for (int dd = 8; dd > 0; dd >>= 1) s += __shfl_xor(s, dd, 16);
  if (gl == 0) score[nid] = s + t[nid] + pb[0];
}

__global__ __launch_bounds__(256) void score_idx(const float* __restrict__ r,
                                                 const float* __restrict__ t,
                                                 const float* __restrict__ pb,
                                                 const int* __restrict__ offs,
                                                 const int* __restrict__ ecnt,
                                                 const int* __restrict__ csr,
                                                 float* __restrict__ score,
                                                 const int* __restrict__ idxl) {
  int grp = threadIdx.x >> 4;
  int gl  = threadIdx.x & 15;
  int ws  = blockIdx.x * 16 + grp;      // < B*K1
  int b = ws >> 12;
  int i = ws & (K1 - 1);
  int n = idxl[b * N + i];
  int nid = b * N + n;
  int o0 = offs[b * (N + 1) + n];
  int d  = ecnt[nid];
  const int* cs = csr + (size_t)b * E;
  const float* rb = r + b * N;
  float s = 0.0f;
  for (int base = 0; base < d; base += 16)
    if (base + gl < d) s += rb[cs[o0 + base + gl]];
#pragma unroll
  for (int dd = 8; dd > 0; dd >>= 1) s += __shfl_xor(s, dd, 16);
  if (gl == 0) score[nid] = s + t[nid] + pb[0];
}

// ---------------------------------------------------------------------------
// top-k via radix select (R10 wave-scan version) + compacted index emission.
// ---------------------------------------------------------------------------
__device__ __forceinline__ unsigned fkey(float s, float m) {
  if (m <= 0.0f) return 0u;
  unsigned u = __float_as_uint(s);
  return (u & 0x80000000u) ? ~u : (u | 0x80000000u);
}

__global__ __launch_bounds__(1024) void topk_kernel(const float* __restrict__ score,
                                                    const float* __restrict__ mkin,
                                                    float* __restrict__ mkout,
                                                    float* __restrict__ fscale,
                                                    int* __restrict__ idxo,
                                                    int k) {
  int b = blockIdx.x, tid = threadIdx.x;
  const float* sc = score + b * N;
  float* mk = mkout + b * N;
  float* fs = fscale + b * N;
  __shared__ unsigned keyb[N];
  __shared__ int hist[256];
  __shared__ unsigned sh_prefix;
  __shared__ int sh_kneed;
  __shared__ int wsum[16], wexc[16];

  for (int i = tid; i < N; i += 1024) {
    float m = (mkin == nullptr) ? 1.0f : mkin[b * N + i];
    keyb[i] = fkey(sc[i], m);
  }
  __syncthreads();

  unsigned prefix = 0, hm = 0;
  int kneed = k;
  for (int shift = 24; shift >= 0; shift -= 8) {
    if (tid < 256) hist[tid] = 0;
    __syncthreads();
    for (int i = tid; i < N; i += 1024) {
      unsigned key = keyb[i];
      if ((key & hm) == prefix) atomicAdd(&hist[(key >> shift) & 255], 1);
    }
    __syncthreads();
    if (tid < 64) {
      int b4[4]; int s = 0;
#pragma unroll
      for (int j = 0; j < 4; ++j) { b4[j] = hist[tid * 4 + j]; s += b4[j]; }
      int suf = s;
#pragma unroll
      for (int o = 1; o < 64; o <<= 1) {
        int v = __shfl_down(suf, o);
        if (tid + o < 64) suf += v;
      }
      int run = suf - s;
      for (int j = 3; j >= 0; --j) {
        if (run < kneed && run + b4[j] >= kneed) {
          sh_prefix = prefix | ((unsigned)(tid * 4 + j) << shift);
          sh_kneed = kneed - run;
        }
        run += b4[j];
      }
    }
    __syncthreads();
    prefix = sh_prefix;
    kneed = sh_kneed;
    hm |= (0xFFu << shift);
  }

  unsigned T = prefix;
  int base = tid * 8;
  unsigned keys[8];
  int eqf[8];
  int cnt = 0;
#pragma unroll
  for (int q = 0; q < 8; ++q) {
    keys[q] = keyb[base + q];
    eqf[q] = (keys[q] == T) ? 1 : 0;
    cnt += eqf[q];
  }
  int inc = cnt;
  int wl = tid & 63;
#pragma unroll
  for (int o = 1; o < 64; o <<= 1) {
    int v = __shfl_up(inc, o);
    if (wl >= o) inc += v;
  }
  if (wl == 63) wsum[tid >> 6] = inc;
  __syncthreads();
  if (tid < 16) {
    int v = wsum[tid];
    int in = v;
#pragma unroll
    for (int o = 1; o < 16; o <<= 1) {
      int u = __shfl_up(in, o);
      if (tid >= o) in += u;
    }
    wexc[tid] = in - v;
  }
  __syncthreads();
  int ex = wexc[tid >> 6] + (inc - cnt);
  int scnt = 0; bool selq[8];
#pragma unroll
  for (int q = 0; q < 8; ++q) {
    bool sel = (keys[q] > T) || (eqf[q] && (ex < kneed));
    ex += eqf[q];
    mk[base + q] = sel ? 1.0f : 0.0f;
    fs[base + q] = sel ? tanhf(sc[base + q]) : 0.0f;
    selq[q] = sel; scnt += sel;
  }
  // emit selected indices (index order)
  int inc2 = scnt;
#pragma unroll
  for (int o = 1; o < 64; o <<= 1) {
    int v = __shfl_up(inc2, o);
    if (wl >= o) inc2 += v;
  }
  __syncthreads();                       // all prior wexc reads done
  if (wl == 63) wsum[tid >> 6] = inc2;
  __syncthreads();
  if (tid < 16) {
    int v = wsum[tid];
    int in = v;
#pragma unroll
    for (int o = 1; o < 16; o <<= 1) {
      int u = __shfl_up(in, o);
      if (tid >= o) in += u;
    }
    wexc[tid] = in - v;
  }
  __syncthreads();
  int spos = wexc[tid >> 6] + (inc2 - scnt);
  int* io = idxo + b * N;
#pragma unroll
  for (int q = 0; q < 8; ++q)
    if (selq[q]) io[spos++] = base + q;
}

// ---------------------------------------------------------------------------
// head MLP + log_softmax (reads fused-readout accumulator gacc)
// ---------------------------------------------------------------------------
__global__ __launch_bounds__(128) void head(const float* __restrict__ gacc,
                                            const float* __restrict__ l1w,
                                            const float* __restrict__ l1b,
                                            const float* __restrict__ l2w,
                                            const float* __restrict__ l2b,
                                            float* __restrict__ out) {
  int b = blockIdx.x, f = threadIdx.x;
  float g = gacc[b * 128 + f] * (1.0f / (float)K2);
  __shared__ float gs[128], hh[128], lg[10];
  gs[f] = g; __syncthreads();
  float a = l1b[f];
  for (int kk = 0; kk < 128; ++kk) a += gs[kk] * l1w[kk * 128 + f];
  hh[f] = fmaxf(a, 0.0f); __syncthreads();
  if (f < 10) {
    float l = l2b[f];
    for (int j = 0; j < 128; ++j) l += hh[j] * l2w[j * 10 + f];
    lg[f] = l;
  }
  __syncthreads();
  if (f == 0) {
    float m = lg[0];
    for (int c = 1; c < 10; ++c) m = fmaxf(m, lg[c]);
    float s = 0.0f;
    for (int c = 0; c < 10; ++c) s += expf(lg[c] - m);
    float lse = m + logf(s);
    for (int c = 0; c < 10; ++c) out[b * 10 + c] = lg[c] - lse;
  }
}

// ---------------------------------------------------------------------------
extern "C" void kernel_launch(void* const* d_in, const int* in_sizes, int n_in,
                              void* d_out, int out_size, void* d_ws, size_t ws_size,
                              hipStream_t stream) {
  (void)in_sizes; (void)n_in; (void)out_size; (void)ws_size;
  const float* x       = (const float*)d_in[0];
  const int*   ei      = (const int*)d_in[1];
  const float* W1      = (const float*)d_in[2];
  const float* b1      = (const float*)d_in[3];
  const float* p1_wrel = (const float*)d_in[4];
  const float* p1_wroot= (const float*)d_in[5];
  const float* p1_b    = (const float*)d_in[6];
  const float* W2      = (const float*)d_in[7];
  const float* b2      = (const float*)d_in[8];
  const float* p2_wrel = (const float*)d_in[9];
  const float* p2_wroot= (const float*)d_in[10];
  const float* p2_b    = (const float*)d_in[11];
  const float* W3      = (const float*)d_in[12];
  const float* b3      = (const float*)d_in[13];
  const float* l1w     = (const float*)d_in[14];
  const float* l1b     = (const float*)d_in[15];
  const float* l2w     = (const float*)d_in[16];
  const float* l2b     = (const float*)d_in[17];
  float* out = (float*)d_out;

  char* p = (char*)d_ws;
  auto alloc = [&](size_t bytes) {
    char* r = p;
    p += ((bytes + 255) & ~(size_t)255);
    return r;
  };
  unsigned short* h   = (unsigned short*)alloc((size_t)B * N * H * 2);   // bf16
  unsigned short* tmp = (unsigned short*)alloc((size_t)B * N * H * 2);   // bf16
  int*      offs   = (int*)alloc((size_t)B * (N + 1) * 4);
  int*      csr    = (int*)alloc((size_t)B * E * 4);
  unsigned* pbuf   = (unsigned*)alloc((size_t)B * E * 4);
  int*      bchist = (int*)alloc((size_t)B * CHUNKS * NBK * 4);
  int*      cursor = (int*)alloc((size_t)B * CHUNKS * NBK * 4);
  int*      bbase  = (int*)alloc((size_t)B * (NBK + 1) * 4);
  int*      ecnt   = (int*)alloc((size_t)B * N * 4);
  int*      idx1   = (int*)alloc((size_t)B * N * 4);
  int*      idx2   = (int*)alloc((size_t)B * N * 4);
  float* dinv   = (float*)alloc((size_t)B * N * 4);
  float* mask   = (float*)alloc((size_t)B * N * 4);
  float* rr     = (float*)alloc((size_t)B * N * 4);
  float* tt     = (float*)alloc((size_t)B * N * 4);
  float* score  = (float*)alloc((size_t)B * N * 4);
  float* fscale = (float*)alloc((size_t)B * N * 4);
  float* gacc   = (float*)alloc((size_t)B * 128 * 4);
  unsigned short* Wts = (unsigned short*)alloc(3 * 128 * 128 * 2);

  // CSR build + weight prep + readout accumulator init
  hist_pass<<<B * CHUNKS, 256, 0, stream>>>(ei, bchist);
  bucket_scan<<<19, 256, 0, stream>>>(bchist, cursor, bbase, W1, W2, W3, Wts);
  bin_scatter<<<B * CHUNKS, 256, 0, stream>>>(ei, cursor, pbuf);
  final_scatter<<<B * NBK, 256, 0, stream>>>(pbuf, bbase, csr, offs, dinv);
  hipMemsetAsync(gacc, 0, (size_t)B * 128 * 4, stream);

  // ---- layer 1 + pool 1 (all nodes live)
  gemm_l1<<<(B * N) / 128, 256, 0, stream>>>(x, Wts, tmp, dinv);
  gcn_agg_l1<<<B * N / 4, 256, 0, stream>>>((const unsigned*)tmp, dinv, offs, csr, b1,
                                            (unsigned*)h, p1_wrel, p1_wroot, rr, tt);
  score_l1<<<B * N / 16, 256, 0, stream>>>(rr, tt, p1_b, offs, csr, score);
  topk_kernel<<<B, 1024, 0, stream>>>(score, nullptr, mask, fscale, idx1, K1);
  compact_idx<12><<<B * K1 / 4, 256, 0, stream>>>(idx1, mask, offs, nullptr, csr,
                                                  ecnt, dinv);

  // ---- layer 2 + pool 2 (live subgraph via idx1)
  gemm_idx<5><<<B * (K1 / 128), 256, 0, stream>>>(h, Wts + 128 * 128, tmp,
                                                  fscale, dinv, idx1);
  gcn_agg_idx<10, false><<<B * K1 / 4, 256, 0, stream>>>(
      (const unsigned*)tmp, dinv, offs, ecnt, csr, b2, (unsigned*)h,
      p2_wrel, p2_wroot, rr, tt, idx1, nullptr);
  score_idx<<<B * K1 / 16, 256, 0, stream>>>(rr, tt, p2_b, offs, ecnt, csr,
                                             score, idx1);
  topk_kernel<<<B, 1024, 0, stream>>>(score, mask, mask, fscale, idx2, K2);
  compact_idx<11><<<B * K2 / 4, 256, 0, stream>>>(idx2, mask, offs, ecnt, csr,
                                                  ecnt, dinv);

  // ---- layer 3 (live subgraph via idx2; fused readout)
  gemm_idx<4><<<B * (K2 / 128), 256, 0, stream>>>(h, Wts + 2 * 128 * 128, tmp,
                                                  fscale, dinv, idx2);
  gcn_agg_idx<9, true><<<B * K2 / 4, 256, 0, stream>>>(
      (const unsigned*)tmp, dinv, offs, ecnt, csr, b3, nullptr,
      nullptr, nullptr, nullptr, nullptr, idx2, gacc);

  // ---- head
  head<<<B, 128, 0, stream>>>(gacc, l1w, l1b, l2w, l2b, out);
}

// Round 12
// 324.655 us; speedup vs baseline: 1.6542x; 1.0089x over previous
//
#include <hip/hip_runtime.h>
#include <hip/hip_bf16.h>
#include <math.h>

// Problem constants
constexpr int B  = 16;
constexpr int N  = 8192;     // 2^13
constexpr int E  = 131072;   // 2^17
constexpr int H  = 128;
constexpr int K1 = 4096;
constexpr int K2 = 2048;

constexpr int CHUNKS = 16;
constexpr int NBK    = 16;
constexpr int FCAP   = 12288;

typedef __attribute__((ext_vector_type(8))) short short8;
typedef __attribute__((ext_vector_type(4))) float floatx4;

__device__ __forceinline__ unsigned short f2bf(float f) {
  unsigned u = __float_as_uint(f);
  return (unsigned short)((u + 0x7FFFu + ((u >> 16) & 1u)) >> 16);  // RNE
}
__device__ __forceinline__ float bf2f(unsigned short s) {
  return __uint_as_float(((unsigned)s) << 16);
}
__device__ __forceinline__ int rdlane_i(int v, int l) {
  return __builtin_amdgcn_readlane(v, l);
}
__device__ __forceinline__ float rdlane_f(float v, int l) {
  return __uint_as_float((unsigned)__builtin_amdgcn_readlane((int)__float_as_uint(v), l));
}
__device__ __forceinline__ unsigned cvt_pk_bf16(float a, float b) {
  unsigned r;
  asm("v_cvt_pk_bf16_f32 %0, %1, %2" : "=v"(r) : "v"(a), "v"(b));
  return r;
}

// ---------------------------------------------------------------------------
// CSR build (streaming counting sort)
// ---------------------------------------------------------------------------
__global__ __launch_bounds__(256) void hist_pass(const int* __restrict__ ei,
                                                 int* __restrict__ bchist) {
  int blk = blockIdx.x;
  int b = blk >> 4, c = blk & 15;
  __shared__ int h16[NBK];
  if (threadIdx.x < NBK) h16[threadIdx.x] = 0;
  __syncthreads();
  const int* dstp = ei + (size_t)b * 2 * E + E + c * 8192;
  for (int i = 0; i < 32; ++i) {
    int dst = dstp[i * 256 + threadIdx.x];
    atomicAdd(&h16[dst >> 9], 1);
  }
  __syncthreads();
  if (threadIdx.x < NBK) bchist[(blk << 4) + threadIdx.x] = h16[threadIdx.x];
}

__global__ __launch_bounds__(256) void bucket_scan(const int* __restrict__ bchist,
                                                   int* __restrict__ cursor,
                                                   int* __restrict__ bbase,
                                                   const float* __restrict__ W1,
                                                   const float* __restrict__ W2,
                                                   const float* __restrict__ W3,
                                                   unsigned short* __restrict__ Wt,
                                                   float* __restrict__ gacc) {
  if (blockIdx.x >= 16) {
    int w = blockIdx.x - 16;
    const float* W = (w == 0) ? W1 : (w == 1) ? W2 : W3;
    unsigned short* o = Wt + w * 128 * 128;
    for (int i = threadIdx.x; i < 128 * 128; i += 256) {
      int k = i >> 7, n = i & 127;
      o[n * 128 + k] = f2bf(W[i]);
    }
    if (w == 0) {                       // fold gacc zeroing in (saves a memset)
      for (int i = threadIdx.x; i < B * 128; i += 256) gacc[i] = 0.0f;
    }
    return;
  }
  int b = blockIdx.x;
  int tid = threadIdx.x;
  int c = tid >> 4, k = tid & 15;
  __shared__ int arr[CHUNKS][NBK];
  __shared__ int base[NBK + 1];
  arr[c][k] = bchist[((b * CHUNKS + c) << 4) + k];
  __syncthreads();
  if (tid == 0) {
    int run = 0;
    for (int kk = 0; kk < NBK; ++kk) {
      base[kk] = run;
      int t = 0;
      for (int cc = 0; cc < CHUNKS; ++cc) t += arr[cc][kk];
      run += t;
    }
    base[NBK] = run;
  }
  __syncthreads();
  int pre = 0;
  for (int cc = 0; cc < c; ++cc) pre += arr[cc][k];
  cursor[((b * CHUNKS + c) << 4) + k] = base[k] + pre;
  if (tid < NBK + 1) bbase[b * (NBK + 1) + tid] = base[tid];
}

__global__ __launch_bounds__(256) void bin_scatter(const int* __restrict__ ei,
                                                   const int* __restrict__ cursor,
                                                   unsigned* __restrict__ pbuf) {
  int blk = blockIdx.x;
  int b = blk >> 4, c = blk & 15;
  __shared__ int gcur[NBK], lcnt[NBK], lfill[NBK];
  __shared__ int lbase[NBK + 1];
  __shared__ unsigned sbuf[2048];
  int tid = threadIdx.x;
  if (tid < NBK) gcur[tid] = cursor[(blk << 4) + tid];
  const int* srcp = ei + (size_t)b * 2 * E + c * 8192;
  const int* dstp = srcp + E;
  unsigned* pb = pbuf + (size_t)b * E;

  for (int sc = 0; sc < 4; ++sc) {
    if (tid < NBK) { lcnt[tid] = 0; lfill[tid] = 0; }
    __syncthreads();
    int s8[8], d8[8];
#pragma unroll
    for (int q = 0; q < 8; ++q) {
      int i = sc * 2048 + q * 256 + tid;
      s8[q] = srcp[i]; d8[q] = dstp[i];
      atomicAdd(&lcnt[d8[q] >> 9], 1);
    }
    __syncthreads();
    if (tid == 0) {
      int run = 0;
      for (int k = 0; k < NBK; ++k) { lbase[k] = run; run += lcnt[k]; }
      lbase[NBK] = run;
    }
    __syncthreads();
#pragma unroll
    for (int q = 0; q < 8; ++q) {
      int k = d8[q] >> 9;
      int idx = atomicAdd(&lfill[k], 1);
      sbuf[lbase[k] + idx] = ((unsigned)k << 22) |
                             ((unsigned)(d8[q] & 511) << 13) | (unsigned)s8[q];
    }
    __syncthreads();
    for (int i = tid; i < 2048; i += 256) {
      unsigned pk = sbuf[i];
      int k = (int)(pk >> 22);
      pb[gcur[k] + (i - lbase[k])] = pk;
    }
    __syncthreads();
    if (tid < NBK) gcur[tid] += lcnt[tid];
    __syncthreads();
  }
}

__global__ __launch_bounds__(256) void final_scatter(const unsigned* __restrict__ pbuf,
                                                     const int* __restrict__ bbase,
                                                     int* __restrict__ csr,
                                                     int* __restrict__ offs,
                                                     float* __restrict__ dinv1) {
  int blk = blockIdx.x;
  int b = blk >> 4, k = blk & 15;
  __shared__ int ncnt[512], nbase[512], nfill[512];
  __shared__ int sred[256];
  __shared__ unsigned sbuf[FCAP];
  int tid = threadIdx.x;
  int gbase = bbase[b * (NBK + 1) + k];
  int gend  = bbase[b * (NBK + 1) + k + 1];
  int cnt = gend - gbase;
  const unsigned* pb = pbuf + (size_t)b * E + gbase;

  for (int i = tid; i < 512; i += 256) { ncnt[i] = 0; nfill[i] = 0; }
  __syncthreads();
  for (int i = tid; i < cnt; i += 256) atomicAdd(&ncnt[(pb[i] >> 13) & 511], 1);
  __syncthreads();
  int v0 = ncnt[2 * tid], v1 = ncnt[2 * tid + 1];
  int s = v0 + v1;
  sred[tid] = s;
  __syncthreads();
  for (int off = 1; off < 256; off <<= 1) {
    int x = (tid >= off) ? sred[tid - off] : 0;
    __syncthreads();
    sred[tid] += x;
    __syncthreads();
  }
  int ex = sred[tid] - s;
  nbase[2 * tid] = ex;
  nbase[2 * tid + 1] = ex + v0;
  __syncthreads();
  for (int i = tid; i < 512; i += 256) {
    int node = k * 512 + i;
    offs[b * (N + 1) + node] = gbase + nbase[i];
    dinv1[b * N + node] = rsqrtf((float)ncnt[i] + 1.0f);
  }
  if (k == 15 && tid == 0) offs[b * (N + 1) + N] = E;
  __syncthreads();
  for (int i = tid; i < cnt; i += 256) {
    unsigned pk = pb[i];
    int node = (pk >> 13) & 511;
    int idx = atomicAdd(&nfill[node], 1);
    sbuf[nbase[node] + idx] = pk & 8191u;
  }
  __syncthreads();
  int* co = csr + (size_t)b * E + gbase;
  for (int i = tid; i < cnt; i += 256) co[i] = (int)sbuf[i];
}

// ---------------------------------------------------------------------------
// GEMM layer-1: full rows, fp32 A, dscale (=dinv1) in epilogue.
// ---------------------------------------------------------------------------
__global__ __launch_bounds__(256) void gemm_l1(const float* __restrict__ Ap,
                                               const unsigned short* __restrict__ Wt,
                                               unsigned short* __restrict__ Cb,
                                               const float* __restrict__ dscale) {
  __shared__ unsigned short Wsh[128 * 128];
  int tid  = threadIdx.x;
  int lane = tid & 63;
  int l15  = lane & 15, lg = lane >> 4;
  size_t rowbase = (size_t)blockIdx.x * 128 + (tid >> 6) * 32;

#pragma unroll
  for (int i = 0; i < 8; ++i) {
    int idx = tid + i * 256;
    int row = idx >> 4, s = idx & 15;
    short8 v = *(const short8*)(Wt + idx * 8);
    *(short8*)(Wsh + row * 128 + (s ^ (row & 15)) * 8) = v;
  }

  short8 afrag[2][4];
#pragma unroll
  for (int rg = 0; rg < 2; ++rg) {
    size_t row = rowbase + rg * 16 + l15;
#pragma unroll
    for (int c = 0; c < 4; ++c) {
      const float* p = Ap + row * 128 + c * 32 + lg * 8;
      float4 v0 = *(const float4*)p;
      float4 v1 = *(const float4*)(p + 4);
      short8 a;
      a[0] = (short)f2bf(v0.x); a[1] = (short)f2bf(v0.y);
      a[2] = (short)f2bf(v0.z); a[3] = (short)f2bf(v0.w);
      a[4] = (short)f2bf(v1.x); a[5] = (short)f2bf(v1.y);
      a[6] = (short)f2bf(v1.z); a[7] = (short)f2bf(v1.w);
      afrag[rg][c] = a;
    }
  }

  float fsr0[4], fsr1[4];
  {
    float4 t0 = *(const float4*)(dscale + rowbase + lg * 4);
    float4 t1 = *(const float4*)(dscale + rowbase + 16 + lg * 4);
    fsr0[0] = t0.x; fsr0[1] = t0.y; fsr0[2] = t0.z; fsr0[3] = t0.w;
    fsr1[0] = t1.x; fsr1[1] = t1.y; fsr1[2] = t1.z; fsr1[3] = t1.w;
  }

  __syncthreads();

#pragma unroll
  for (int t = 0; t < 8; ++t) {
    int col = t * 16 + l15;
    short8 bfrag[4];
#pragma unroll
    for (int c = 0; c < 4; ++c)
      bfrag[c] = *(const short8*)(Wsh + col * 128 + ((c * 4 + lg) ^ (col & 15)) * 8);

    floatx4 acc0 = {0.f, 0.f, 0.f, 0.f};
    floatx4 acc1 = {0.f, 0.f, 0.f, 0.f};
#pragma unroll
    for (int c = 0; c < 4; ++c) {
      acc0 = __builtin_amdgcn_mfma_f32_16x16x32_bf16(afrag[0][c], bfrag[c], acc0, 0, 0, 0);
      acc1 = __builtin_amdgcn_mfma_f32_16x16x32_bf16(afrag[1][c], bfrag[c], acc1, 0, 0, 0);
    }
#pragma unroll
    for (int r = 0; r < 4; ++r) {
      size_t row0 = rowbase + lg * 4 + r;
      size_t row1 = rowbase + 16 + lg * 4 + r;
      Cb[row0 * 128 + col] = f2bf(acc0[r] * fsr0[r]);
      Cb[row1 * 128 + col] = f2bf(acc1[r] * fsr1[r]);
    }
  }
}

// ---------------------------------------------------------------------------
// GEMM layers 2/3: LIVE rows only via per-graph index list.
// ---------------------------------------------------------------------------
template <int LGB>
__global__ __launch_bounds__(256) void gemm_idx(const unsigned short* __restrict__ Ab,
                                                const unsigned short* __restrict__ Wt,
                                                unsigned short* __restrict__ Cb,
                                                const float* __restrict__ fscale,
                                                const float* __restrict__ dscale,
                                                const int* __restrict__ idxl) {
  __shared__ unsigned short Wsh[128 * 128];
  __shared__ int ridx[128];
  int tid  = threadIdx.x;
  int lane = tid & 63;
  int l15  = lane & 15, lg = lane >> 4;
  int b    = blockIdx.x >> LGB;
  int lblk = blockIdx.x & ((1 << LGB) - 1);
  int woff = (tid >> 6) * 32;

  if (tid < 128) ridx[tid] = idxl[b * N + lblk * 128 + tid];
#pragma unroll
  for (int i = 0; i < 8; ++i) {
    int idx = tid + i * 256;
    int row = idx >> 4, s = idx & 15;
    short8 v = *(const short8*)(Wt + idx * 8);
    *(short8*)(Wsh + row * 128 + (s ^ (row & 15)) * 8) = v;
  }
  __syncthreads();

  const unsigned short* Ag = Ab + (size_t)b * N * 128;
  unsigned short* Cg = Cb + (size_t)b * N * 128;
  const float* fsb = fscale + b * N;
  const float* dsb = dscale + b * N;

  short8 afrag[2][4];
#pragma unroll
  for (int rg = 0; rg < 2; ++rg) {
    int arow = ridx[woff + rg * 16 + l15];
#pragma unroll
    for (int c = 0; c < 4; ++c)
      afrag[rg][c] = *(const short8*)(Ag + (size_t)arow * 128 + c * 32 + lg * 8);
  }

  int orow[2][4]; float fsr[2][4];
#pragma unroll
  for (int rg = 0; rg < 2; ++rg)
#pragma unroll
    for (int r = 0; r < 4; ++r) {
      int o = ridx[woff + rg * 16 + lg * 4 + r];
      orow[rg][r] = o;
      fsr[rg][r] = fsb[o] * dsb[o];
    }

#pragma unroll
  for (int t = 0; t < 8; ++t) {
    int col = t * 16 + l15;
    short8 bfrag[4];
#pragma unroll
    for (int c = 0; c < 4; ++c)
      bfrag[c] = *(const short8*)(Wsh + col * 128 + ((c * 4 + lg) ^ (col & 15)) * 8);

    floatx4 acc0 = {0.f, 0.f, 0.f, 0.f};
    floatx4 acc1 = {0.f, 0.f, 0.f, 0.f};
#pragma unroll
    for (int c = 0; c < 4; ++c) {
      acc0 = __builtin_amdgcn_mfma_f32_16x16x32_bf16(afrag[0][c], bfrag[c], acc0, 0, 0, 0);
      acc1 = __builtin_amdgcn_mfma_f32_16x16x32_bf16(afrag[1][c], bfrag[c], acc1, 0, 0, 0);
    }
#pragma unroll
    for (int r = 0; r < 4; ++r) {
      Cg[(size_t)orow[0][r] * 128 + col] = f2bf(acc0[r] * fsr[0][r]);
      Cg[(size_t)orow[1][r] * 128 + col] = f2bf(acc1[r] * fsr[1][r]);
    }
  }
}

// ---------------------------------------------------------------------------
// GCN aggregation layer-1: ONE GRAPH PER XCD AT A TIME (temporal phasing —
// blocks dispatch roughly in order, so phase 0 = graphs 0-7, phase 1 = 8-15;
// per-XCD working set 2.5 MB -> L2-resident instead of 2 graphs = 5 MB).
// ---------------------------------------------------------------------------
__global__ __launch_bounds__(256) void gcn_agg_l1(
    const unsigned* __restrict__ tmp, const float* __restrict__ dinv,
    const int* __restrict__ offs, const int* __restrict__ csr,
    const float* __restrict__ bias, unsigned* __restrict__ hout,
    const float* __restrict__ wrel, const float* __restrict__ wroot,
    float* __restrict__ rr, float* __restrict__ tt) {
  int blk = blockIdx.x;
  int xcd = blk & 7;
  int j   = blk >> 3;
  int b   = xcd + 8 * (j >> 11);           // phase-mapped: 1 graph/XCD at a time
  int n   = (j & 2047) * 4 + (threadIdx.x >> 6);
  int wid = b * N + n;
  int lane = threadIdx.x & 63;

  float dv = rdlane_f(dinv[wid], 0);
  unsigned* hrow = hout + (size_t)wid * 64;

  const unsigned* tmpb = tmp + (((size_t)b << 13) << 6);
  const int* cs = csr + (size_t)b * E;

  float2 accA, accB;
  {
    unsigned u = tmpb[((unsigned)n << 6) + lane];
    accA.x = __uint_as_float(u << 16);
    accA.y = __uint_as_float(u & 0xFFFF0000u);
    accB.x = 0.0f; accB.y = 0.0f;
  }

  int nbase = b * (N + 1) + n;
  int o0 = __builtin_amdgcn_readfirstlane(offs[nbase]);
  int d  = __builtin_amdgcn_readfirstlane(offs[nbase + 1]) - o0;

  for (int base = 0; base < d; base += 64) {
    int nv = d - base; if (nv > 64) nv = 64;
    int sl = (lane < nv) ? cs[o0 + base + lane] : 0;
    int nfull = nv >> 4;
    for (int t = 0; t < nfull; ++t) {
      int i0 = t << 4;
      unsigned uu[16];
#pragma unroll
      for (int q = 0; q < 16; ++q) {
        int sq = rdlane_i(sl, i0 + q);
        uu[q] = tmpb[((unsigned)sq << 6) + lane];
      }
#pragma unroll
      for (int q = 0; q < 16; ++q) {
        float lo = __uint_as_float(uu[q] << 16);
        float hi = __uint_as_float(uu[q] & 0xFFFF0000u);
        if (q & 1) { accB.x += lo; accB.y += hi; }
        else       { accA.x += lo; accA.y += hi; }
      }
    }
    int rem = nv & 15;
    if (rem) {
      int i0 = nfull << 4;
      unsigned uu[16];
#pragma unroll
      for (int q = 0; q < 16; ++q) {
        int idx = i0 + q;
        int sq = rdlane_i(sl, idx < nv ? idx : 0);
        unsigned v = tmpb[((unsigned)sq << 6) + lane];
        uu[q] = (idx < nv) ? v : 0u;
      }
#pragma unroll
      for (int q = 0; q < 16; ++q) {
        float lo = __uint_as_float(uu[q] << 16);
        float hi = __uint_as_float(uu[q] & 0xFFFF0000u);
        if (q & 1) { accB.x += lo; accB.y += hi; }
        else       { accA.x += lo; accA.y += hi; }
      }
    }
  }

  float2 acc = {accA.x + accB.x, accA.y + accB.y};
  const float2 bb = *(const float2*)(bias + lane * 2);
  float2 outv;
  outv.x = fmaxf(dv * acc.x + bb.x, 0.0f);
  outv.y = fmaxf(dv * acc.y + bb.y, 0.0f);
  hrow[lane] = cvt_pk_bf16(outv.x, outv.y);

  const float2 wr = *(const float2*)(wrel + lane * 2);
  const float2 wo = *(const float2*)(wroot + lane * 2);
  float pr = outv.x * wr.x + outv.y * wr.y;
  float pt = outv.x * wo.x + outv.y * wo.y;
#pragma unroll
  for (int dd = 32; dd > 0; dd >>= 1) {
    pr += __shfl_down(pr, dd);
    pt += __shfl_down(pt, dd);
  }
  if (lane == 0) { rr[wid] = pr; tt[wid] = pt; }
}

// ---------------------------------------------------------------------------
// GCN aggregation layers 2/3 (live index list), phase-mapped XCD assignment.
// ---------------------------------------------------------------------------
template <int LOGPG, bool FUSE_RO>
__global__ __launch_bounds__(256) void gcn_agg_idx(
    const unsigned* __restrict__ tmp, const float* __restrict__ dinv,
    const int* __restrict__ offs, const int* __restrict__ ecnt,
    const int* __restrict__ csr, const float* __restrict__ bias,
    unsigned* __restrict__ hout, const float* __restrict__ wrel,
    const float* __restrict__ wroot, float* __restrict__ rr,
    float* __restrict__ tt, const int* __restrict__ idxl,
    float* __restrict__ gacc) {
  __shared__ float racc[128];
  int blk = blockIdx.x;
  int xcd = blk & 7;
  int j   = blk >> 3;
  int b   = xcd + 8 * (j >> LOGPG);        // phase-mapped
  int i   = (j & ((1 << LOGPG) - 1)) * 4 + (threadIdx.x >> 6);
  int lane = threadIdx.x & 63;

  if (FUSE_RO) {
    if (threadIdx.x < 128) racc[threadIdx.x] = 0.0f;
    __syncthreads();
  }

  int n = __builtin_amdgcn_readfirstlane(idxl[b * N + i]);
  int wid = b * N + n;
  float dv = rdlane_f(dinv[wid], 0);

  const unsigned* tmpb = tmp + (((size_t)b << 13) << 6);
  const int* cs = csr + (size_t)b * E;

  float2 accA, accB;
  {
    unsigned u = tmpb[((unsigned)n << 6) + lane];
    accA.x = __uint_as_float(u << 16);
    accA.y = __uint_as_float(u & 0xFFFF0000u);
    accB.x = 0.0f; accB.y = 0.0f;
  }

  int o0 = __builtin_amdgcn_readfirstlane(offs[b * (N + 1) + n]);
  int d  = __builtin_amdgcn_readfirstlane(ecnt[wid]);

  for (int base = 0; base < d; base += 64) {
    int nv = d - base; if (nv > 64) nv = 64;
    int sl = (lane < nv) ? cs[o0 + base + lane] : 0;
    int nfull = nv >> 4;
    for (int t = 0; t < nfull; ++t) {
      int i0 = t << 4;
      unsigned uu[16];
#pragma unroll
      for (int q = 0; q < 16; ++q) {
        int sq = rdlane_i(sl, i0 + q);
        uu[q] = tmpb[((unsigned)sq << 6) + lane];
      }
#pragma unroll
      for (int q = 0; q < 16; ++q) {
        float lo = __uint_as_float(uu[q] << 16);
        float hi = __uint_as_float(uu[q] & 0xFFFF0000u);
        if (q & 1) { accB.x += lo; accB.y += hi; }
        else       { accA.x += lo; accA.y += hi; }
      }
    }
    int rem = nv & 15;
    if (rem) {
      int i0 = nfull << 4;
      unsigned uu[16];
#pragma unroll
      for (int q = 0; q < 16; ++q) {
        int idx = i0 + q;
        int sq = rdlane_i(sl, idx < nv ? idx : 0);
        unsigned v = tmpb[((unsigned)sq << 6) + lane];
        uu[q] = (idx < nv) ? v : 0u;
      }
#pragma unroll
      for (int q = 0; q < 16; ++q) {
        float lo = __uint_as_float(uu[q] << 16);
        float hi = __uint_as_float(uu[q] & 0xFFFF0000u);
        if (q & 1) { accB.x += lo; accB.y += hi; }
        else       { accA.x += lo; accA.y += hi; }
      }
    }
  }

  float2 acc = {accA.x + accB.x, accA.y + accB.y};
  const float2 bb = *(const float2*)(bias + lane * 2);
  float2 outv;
  outv.x = fmaxf(dv * acc.x + bb.x, 0.0f);
  outv.y = fmaxf(dv * acc.y + bb.y, 0.0f);

  if (!FUSE_RO) {
    unsigned* hrow = hout + (size_t)wid * 64;
    hrow[lane] = cvt_pk_bf16(outv.x, outv.y);
    const float2 wr = *(const float2*)(wrel + lane * 2);
    const float2 wo = *(const float2*)(wroot + lane * 2);
    float pr = outv.x * wr.x + outv.y * wr.y;
    float pt = outv.x * wo.x + outv.y * wo.y;
#pragma unroll
    for (int dd = 32; dd > 0; dd >>= 1) {
      pr += __shfl_down(pr, dd);
      pt += __shfl_down(pt, dd);
    }
    if (lane == 0) { rr[wid] = pr; tt[wid] = pt; }
  } else {
    atomicAdd(&racc[lane * 2],     outv.x);
    atomicAdd(&racc[lane * 2 + 1], outv.y);
    __syncthreads();
    if (threadIdx.x < 128) atomicAdd(&gacc[b * 128 + threadIdx.x], racc[threadIdx.x]);
  }
}

// ---------------------------------------------------------------------------
// compact (live nodes only, via index list)
// ---------------------------------------------------------------------------
template <int LOGK>
__global__ __launch_bounds__(256) void compact_idx(
    const int* __restrict__ idxl, const float* __restrict__ mask,
    const int* __restrict__ offs, const int* __restrict__ ecnt_in,
    int* __restrict__ csr, int* __restrict__ ecnt_out,
    float* __restrict__ dinv_out) {
  int ws = blockIdx.x * 4 + (threadIdx.x >> 6);
  int b = ws >> LOGK;
  int i = ws & ((1 << LOGK) - 1);
  int lane = threadIdx.x & 63;
  int n = __builtin_amdgcn_readfirstlane(idxl[b * N + i]);
  int wid = b * N + n;
  int nb = b * (N + 1) + n;
  int o0 = __builtin_amdgcn_readfirstlane(offs[nb]);
  int din = (ecnt_in != nullptr)
                ? __builtin_amdgcn_readfirstlane(ecnt_in[wid])
                : __builtin_amdgcn_readfirstlane(offs[nb + 1]) - o0;
  int* cs = csr + (size_t)b * E;
  const float* mb = mask + b * N;
  int wpos = o0;
  for (int base = 0; base < din; base += 64) {
    int nv = din - base; if (nv > 64) nv = 64;
    int s = (lane < nv) ? cs[o0 + base + lane] : 0;
    bool alive = (lane < nv) && (mb[s] > 0.0f);
    unsigned long long bal = __ballot(alive);
    int idx = __popcll(bal & ((1ull << lane) - 1ull));
    if (alive) cs[wpos + idx] = s;
    wpos += __popcll(bal);
  }
  if (lane == 0) {
    int total = wpos - o0;
    ecnt_out[wid] = total;
    dinv_out[wid] = rsqrtf((float)total + 1.0f);
  }
}

// ---------------------------------------------------------------------------
// pool score layer 1 (full) and layer 2 (idx-restricted)
// ---------------------------------------------------------------------------
__global__ __launch_bounds__(256) void score_l1(const float* __restrict__ r,
                                                const float* __restrict__ t,
                                                const float* __restrict__ pb,
                                                const int* __restrict__ offs,
                                                const int* __restrict__ csr,
                                                float* __restrict__ score) {
  int grp = threadIdx.x >> 4;
  int gl  = threadIdx.x & 15;
  int nid = blockIdx.x * 16 + grp;
  int b = nid >> 13, n = nid & (N - 1);
  int o0 = offs[b * (N + 1) + n], o1 = offs[b * (N + 1) + n + 1];
  const int* cs = csr + (size_t)b * E;
  const float* rb = r + b * N;
  float s = 0.0f;
  for (int base = o0; base < o1; base += 16)
    if (base + gl < o1) s += rb[cs[base + gl]];
#pragma unroll
  for (int dd = 8; dd > 0; dd >>= 1) s += __shfl_xor(s, dd, 16);
  if (gl == 0) score[nid] = s + t[nid] + pb[0];
}

__global__ __launch_bounds__(256) void score_idx(const float* __restrict__ r,
                                                 const float* __restrict__ t,
                                                 const float* __restrict__ pb,
                                                 const int* __restrict__ offs,
                                                 const int* __restrict__ ecnt,
                                                 const int* __restrict__ csr,
                                                 float* __restrict__ score,
                                                 const int* __restrict__ idxl) {
  int grp = threadIdx.x >> 4;
  int gl  = threadIdx.x & 15;
  int ws  = blockIdx.x * 16 + grp;
  int b = ws >> 12;
  int i = ws & (K1 - 1);
  int n = idxl[b * N + i];
  int nid = b * N + n;
  int o0 = offs[b * (N + 1) + n];
  int d  = ecnt[nid];
  const int* cs = csr + (size_t)b * E;
  const float* rb = r + b * N;
  float s = 0.0f;
  for (int base = 0; base < d; base += 16)
    if (base + gl < d) s += rb[cs[o0 + base + gl]];
#pragma unroll
  for (int dd = 8; dd > 0; dd >>= 1) s += __shfl_xor(s, dd, 16);
  if (gl == 0) score[nid] = s + t[nid] + pb[0];
}

// ---------------------------------------------------------------------------
// top-k via radix select + compacted index emission
// ---------------------------------------------------------------------------
__device__ __forceinline__ unsigned fkey(float s, float m) {
  if (m <= 0.0f) return 0u;
  unsigned u = __float_as_uint(s);
  return (u & 0x80000000u) ? ~u : (u | 0x80000000u);
}

__global__ __launch_bounds__(1024) void topk_kernel(const float* __restrict__ score,
                                                    const float* __restrict__ mkin,
                                                    float* __restrict__ mkout,
                                                    float* __restrict__ fscale,
                                                    int* __restrict__ idxo,
                                                    int k) {
  int b = blockIdx.x, tid = threadIdx.x;
  const float* sc = score + b * N;
  float* mk = mkout + b * N;
  float* fs = fscale + b * N;
  __shared__ unsigned keyb[N];
  __shared__ int hist[256];
  __shared__ unsigned sh_prefix;
  __shared__ int sh_kneed;
  __shared__ int wsum[16], wexc[16];

  for (int i = tid; i < N; i += 1024) {
    float m = (mkin == nullptr) ? 1.0f : mkin[b * N + i];
    keyb[i] = fkey(sc[i], m);
  }
  __syncthreads();

  unsigned prefix = 0, hm = 0;
  int kneed = k;
  for (int shift = 24; shift >= 0; shift -= 8) {
    if (tid < 256) hist[tid] = 0;
    __syncthreads();
    for (int i = tid; i < N; i += 1024) {
      unsigned key = keyb[i];
      if ((key & hm) == prefix) atomicAdd(&hist[(key >> shift) & 255], 1);
    }
    __syncthreads();
    if (tid < 64) {
      int b4[4]; int s = 0;
#pragma unroll
      for (int j = 0; j < 4; ++j) { b4[j] = hist[tid * 4 + j]; s += b4[j]; }
      int suf = s;
#pragma unroll
      for (int o = 1; o < 64; o <<= 1) {
        int v = __shfl_down(suf, o);
        if (tid + o < 64) suf += v;
      }
      int run = suf - s;
      for (int j = 3; j >= 0; --j) {
        if (run < kneed && run + b4[j] >= kneed) {
          sh_prefix = prefix | ((unsigned)(tid * 4 + j) << shift);
          sh_kneed = kneed - run;
        }
        run += b4[j];
      }
    }
    __syncthreads();
    prefix = sh_prefix;
    kneed = sh_kneed;
    hm |= (0xFFu << shift);
  }

  unsigned T = prefix;
  int base = tid * 8;
  unsigned keys[8];
  int eqf[8];
  int cnt = 0;
#pragma unroll
  for (int q = 0; q < 8; ++q) {
    keys[q] = keyb[base + q];
    eqf[q] = (keys[q] == T) ? 1 : 0;
    cnt += eqf[q];
  }
  int inc = cnt;
  int wl = tid & 63;
#pragma unroll
  for (int o = 1; o < 64; o <<= 1) {
    int v = __shfl_up(inc, o);
    if (wl >= o) inc += v;
  }
  if (wl == 63) wsum[tid >> 6] = inc;
  __syncthreads();
  if (tid < 16) {
    int v = wsum[tid];
    int in = v;
#pragma unroll
    for (int o = 1; o < 16; o <<= 1) {
      int u = __shfl_up(in, o);
      if (tid >= o) in += u;
    }
    wexc[tid] = in - v;
  }
  __syncthreads();
  int ex = wexc[tid >> 6] + (inc - cnt);
  int scnt = 0; bool selq[8];
#pragma unroll
  for (int q = 0; q < 8; ++q) {
    bool sel = (keys[q] > T) || (eqf[q] && (ex < kneed));
    ex += eqf[q];
    mk[base + q] = sel ? 1.0f : 0.0f;
    fs[base + q] = sel ? tanhf(sc[base + q]) : 0.0f;
    selq[q] = sel; scnt += sel;
  }
  int inc2 = scnt;
#pragma unroll
  for (int o = 1; o < 64; o <<= 1) {
    int v = __shfl_up(inc2, o);
    if (wl >= o) inc2 += v;
  }
  __syncthreads();
  if (wl == 63) wsum[tid >> 6] = inc2;
  __syncthreads();
  if (tid < 16) {
    int v = wsum[tid];
    int in = v;
#pragma unroll
    for (int o = 1; o < 16; o <<= 1) {
      int u = __shfl_up(in, o);
      if (tid >= o) in += u;
    }
    wexc[tid] = in - v;
  }
  __syncthreads();
  int spos = wexc[tid >> 6] + (inc2 - scnt);
  int* io = idxo + b * N;
#pragma unroll
  for (int q = 0; q < 8; ++q)
    if (selq[q]) io[spos++] = base + q;
}

// ---------------------------------------------------------------------------
// head MLP + log_softmax
// ---------------------------------------------------------------------------
__global__ __launch_bounds__(128) void head(const float* __restrict__ gacc,
                                            const float* __restrict__ l1w,
                                            const float* __restrict__ l1b,
                                            const float* __restrict__ l2w,
                                            const float* __restrict__ l2b,
                                            float* __restrict__ out) {
  int b = blockIdx.x, f = threadIdx.x;
  float g = gacc[b * 128 + f] * (1.0f / (float)K2);
  __shared__ float gs[128], hh[128], lg[10];
  gs[f] = g; __syncthreads();
  float a = l1b[f];
  for (int kk = 0; kk < 128; ++kk) a += gs[kk] * l1w[kk * 128 + f];
  hh[f] = fmaxf(a, 0.0f); __syncthreads();
  if (f < 10) {
    float l = l2b[f];
    for (int j = 0; j < 128; ++j) l += hh[j] * l2w[j * 10 + f];
    lg[f] = l;
  }
  __syncthreads();
  if (f == 0) {
    float m = lg[0];
    for (int c = 1; c < 10; ++c) m = fmaxf(m, lg[c]);
    float s = 0.0f;
    for (int c = 0; c < 10; ++c) s += expf(lg[c] - m);
    float lse = m + logf(s);
    for (int c = 0; c < 10; ++c) out[b * 10 + c] = lg[c] - lse;
  }
}

// ---------------------------------------------------------------------------
extern "C" void kernel_launch(void* const* d_in, const int* in_sizes, int n_in,
                              void* d_out, int out_size, void* d_ws, size_t ws_size,
                              hipStream_t stream) {
  (void)in_sizes; (void)n_in; (void)out_size; (void)ws_size;
  const float* x       = (const float*)d_in[0];
  const int*   ei      = (const int*)d_in[1];
  const float* W1      = (const float*)d_in[2];
  const float* b1      = (const float*)d_in[3];
  const float* p1_wrel = (const float*)d_in[4];
  const float* p1_wroot= (const float*)d_in[5];
  const float* p1_b    = (const float*)d_in[6];
  const float* W2      = (const float*)d_in[7];
  const float* b2      = (const float*)d_in[8];
  const float* p2_wrel = (const float*)d_in[9];
  const float* p2_wroot= (const float*)d_in[10];
  const float* p2_b    = (const float*)d_in[11];
  const float* W3      = (const float*)d_in[12];
  const float* b3      = (const float*)d_in[13];
  const float* l1w     = (const float*)d_in[14];
  const float* l1b     = (const float*)d_in[15];
  const float* l2w     = (const float*)d_in[16];
  const float* l2b     = (const float*)d_in[17];
  float* out = (float*)d_out;

  char* p = (char*)d_ws;
  auto alloc = [&](size_t bytes) {
    char* r = p;
    p += ((bytes + 255) & ~(size_t)255);
    return r;
  };
  unsigned short* h   = (unsigned short*)alloc((size_t)B * N * H * 2);   // bf16
  unsigned short* tmp = (unsigned short*)alloc((size_t)B * N * H * 2);   // bf16
  int*      offs   = (int*)alloc((size_t)B * (N + 1) * 4);
  int*      csr    = (int*)alloc((size_t)B * E * 4);
  unsigned* pbuf   = (unsigned*)alloc((size_t)B * E * 4);
  int*      bchist = (int*)alloc((size_t)B * CHUNKS * NBK * 4);
  int*      cursor = (int*)alloc((size_t)B * CHUNKS * NBK * 4);
  int*      bbase  = (int*)alloc((size_t)B * (NBK + 1) * 4);
  int*      ecnt   = (int*)alloc((size_t)B * N * 4);
  int*      idx1   = (int*)alloc((size_t)B * N * 4);
  int*      idx2   = (int*)alloc((size_t)B * N * 4);
  float* dinv   = (float*)alloc((size_t)B * N * 4);
  float* mask   = (float*)alloc((size_t)B * N * 4);
  float* rr     = (float*)alloc((size_t)B * N * 4);
  float* tt     = (float*)alloc((size_t)B * N * 4);
  float* score  = (float*)alloc((size_t)B * N * 4);
  float* fscale = (float*)alloc((size_t)B * N * 4);
  float* gacc   = (float*)alloc((size_t)B * 128 * 4);
  unsigned short* Wts = (unsigned short*)alloc(3 * 128 * 128 * 2);

  // CSR build + weight prep + gacc zeroing (fused)
  hist_pass<<<B * CHUNKS, 256, 0, stream>>>(ei, bchist);
  bucket_scan<<<19, 256, 0, stream>>>(bchist, cursor, bbase, W1, W2, W3, Wts, gacc);
  bin_scatter<<<B * CHUNKS, 256, 0, stream>>>(ei, cursor, pbuf);
  final_scatter<<<B * NBK, 256, 0, stream>>>(pbuf, bbase, csr, offs, dinv);

  // ---- layer 1 + pool 1 (all nodes live)
  gemm_l1<<<(B * N) / 128, 256, 0, stream>>>(x, Wts, tmp, dinv);
  gcn_agg_l1<<<B * N / 4, 256, 0, stream>>>((const unsigned*)tmp, dinv, offs, csr, b1,
                                            (unsigned*)h, p1_wrel, p1_wroot, rr, tt);
  score_l1<<<B * N / 16, 256, 0, stream>>>(rr, tt, p1_b, offs, csr, score);
  topk_kernel<<<B, 1024, 0, stream>>>(score, nullptr, mask, fscale, idx1, K1);
  compact_idx<12><<<B * K1 / 4, 256, 0, stream>>>(idx1, mask, offs, nullptr, csr,
                                                  ecnt, dinv);

  // ---- layer 2 + pool 2 (live subgraph via idx1)
  gemm_idx<5><<<B * (K1 / 128), 256, 0, stream>>>(h, Wts + 128 * 128, tmp,
                                                  fscale, dinv, idx1);
  gcn_agg_idx<10, false><<<B * K1 / 4, 256, 0, stream>>>(
      (const unsigned*)tmp, dinv, offs, ecnt, csr, b2, (unsigned*)h,
      p2_wrel, p2_wroot, rr, tt, idx1, nullptr);
  score_idx<<<B * K1 / 16, 256, 0, stream>>>(rr, tt, p2_b, offs, ecnt, csr,
                                             score, idx1);
  topk_kernel<<<B, 1024, 0, stream>>>(score, mask, mask, fscale, idx2, K2);
  compact_idx<11><<<B * K2 / 4, 256, 0, stream>>>(idx2, mask, offs, ecnt, csr,
                                                  ecnt, dinv);

  // ---- layer 3 (live subgraph via idx2; fused readout)
  gemm_idx<4><<<B * (K2 / 128), 256, 0, stream>>>(h, Wts + 2 * 128 * 128, tmp,
                                                  fscale, dinv, idx2);
  gcn_agg_idx<9, true><<<B * K2 / 4, 256, 0, stream>>>(
      (const unsigned*)tmp, dinv, offs, ecnt, csr, b3, nullptr,
      nullptr, nullptr, nullptr, nullptr, idx2, gacc);

  // ---- head
  head<<<B, 128, 0, stream>>>(gacc, l1w, l1b, l2w, l2b, out);
}